// Round 3
// baseline (21269.667 us; speedup 1.0000x reference)
//
#include <hip/hip_runtime.h>
#include <math.h>

// ---------------- constants ----------------
#define B_    16
#define N_    2048
#define INDIM 64
#define DIM_  512
#define HEADS 8
#define DEPTH 4
#define KLIN  256
#define NCLS  2
#define DH    64
#define EPSF  1e-5f
#define CB    4                    // batches per attention chunk
#define CHROWS (CB * N_)           // 8192 rows per attention chunk
#define FROWS 4096                 // rows per FFN chunk

// ---------------- wave reductions ----------------
__device__ __forceinline__ float wave_sum(float v) {
  #pragma unroll
  for (int o = 32; o > 0; o >>= 1) v += __shfl_xor(v, o);
  return v;
}
__device__ __forceinline__ float wave_max(float v) {
  #pragma unroll
  for (int o = 32; o > 0; o >>= 1) v = fmaxf(v, __shfl_xor(v, o));
  return v;
}

// ---------------- LayerNorm: one wave per 512-wide row ----------------
__global__ __launch_bounds__(256) void ln_k(const float* __restrict__ h,
                                            const float* __restrict__ s,
                                            const float* __restrict__ b,
                                            float* __restrict__ z) {
  int lane = threadIdx.x & 63;
  long long row = ((long long)blockIdx.x << 2) + (threadIdx.x >> 6);
  const float* hr = h + row * DIM_ + lane * 8;
  float4 a = *(const float4*)hr;
  float4 c = *(const float4*)(hr + 4);
  float sum = a.x + a.y + a.z + a.w + c.x + c.y + c.z + c.w;
  sum = wave_sum(sum);
  float mu = sum * (1.f / DIM_);
  float d[8] = {a.x - mu, a.y - mu, a.z - mu, a.w - mu,
                c.x - mu, c.y - mu, c.z - mu, c.w - mu};
  float vs = 0.f;
  #pragma unroll
  for (int i = 0; i < 8; ++i) vs += d[i] * d[i];
  vs = wave_sum(vs);
  float rstd = rsqrtf(vs * (1.f / DIM_) + EPSF);
  const float* sp = s + lane * 8;
  const float* bp = b + lane * 8;
  float4 s0 = *(const float4*)sp, s1 = *(const float4*)(sp + 4);
  float4 b0 = *(const float4*)bp, b1 = *(const float4*)(bp + 4);
  float4 o0, o1;
  o0.x = d[0] * rstd * s0.x + b0.x; o0.y = d[1] * rstd * s0.y + b0.y;
  o0.z = d[2] * rstd * s0.z + b0.z; o0.w = d[3] * rstd * s0.w + b0.w;
  o1.x = d[4] * rstd * s1.x + b1.x; o1.y = d[5] * rstd * s1.y + b1.y;
  o1.z = d[6] * rstd * s1.z + b1.z; o1.w = d[7] * rstd * s1.w + b1.w;
  float* zr = z + row * DIM_ + lane * 8;
  *(float4*)zr = o0;
  *(float4*)(zr + 4) = o1;
}

// ---------------- generic fp32 GEMM, 64x64 tile, 4x4/thread ----------------
__device__ __forceinline__ float gelu_tanh(float x) {
  float x3 = x * x * x;
  float t = tanhf(0.7978845608028654f * (x + 0.044715f * x3));
  return 0.5f * x * (1.f + t);
}

__global__ __launch_bounds__(256) void gemm_f32(
    const float* __restrict__ A, const float* __restrict__ B,
    const float* __restrict__ bias, const float* __restrict__ resid,
    float* __restrict__ C, int M, int N, int K, int lda, int ldb, int ldc,
    long long sAb, long long sBb, long long sCb,
    int opA, int opB, int epi, float alpha, int resMod) {
  int zz = blockIdx.z;
  A += (long long)zz * sAb;
  B += (long long)zz * sBb;
  C += (long long)zz * sCb;

  int bm = blockIdx.y * 64, bn = blockIdx.x * 64;
  __shared__ float As[16][68];
  __shared__ float Bs[16][68];
  int tid = threadIdx.x;
  int tx = tid & 15, ty = tid >> 4;
  float acc[4][4] = {};

  for (int k0 = 0; k0 < K; k0 += 16) {
    if (opA == 0) {
      int m = tid >> 2, kq = (tid & 3) * 4;
      float4 v = *(const float4*)(A + (long long)(bm + m) * lda + k0 + kq);
      As[kq + 0][m] = v.x; As[kq + 1][m] = v.y;
      As[kq + 2][m] = v.z; As[kq + 3][m] = v.w;
    } else {
      int kk = tid >> 4, mq = (tid & 15) * 4;
      float4 v = *(const float4*)(A + (long long)(k0 + kk) * lda + bm + mq);
      *(float4*)&As[kk][mq] = v;
    }
    {
      int kk = tid >> 4, nq = (tid & 15) * 4;
      float4 v = *(const float4*)(B + (long long)(k0 + kk) * ldb + bn + nq);
      *(float4*)&Bs[kk][nq] = v;
    }
    __syncthreads();
    #pragma unroll
    for (int kk = 0; kk < 16; ++kk) {
      float4 a4 = *(const float4*)&As[kk][ty * 4];
      float4 b4 = *(const float4*)&Bs[kk][tx * 4];
      float ar[4] = {a4.x, a4.y, a4.z, a4.w};
      float br[4] = {b4.x, b4.y, b4.z, b4.w};
      #pragma unroll
      for (int i = 0; i < 4; ++i)
        #pragma unroll
        for (int j = 0; j < 4; ++j)
          acc[i][j] = fmaf(ar[i], br[j], acc[i][j]);
    }
    __syncthreads();
  }

  int nbase = bn + tx * 4;
  float4 bb = make_float4(0.f, 0.f, 0.f, 0.f);
  if (epi >= 1) bb = *(const float4*)(bias + nbase);
  #pragma unroll
  for (int i = 0; i < 4; ++i) {
    int m = bm + ty * 4 + i;
    float vv[4];
    #pragma unroll
    for (int j = 0; j < 4; ++j) vv[j] = acc[i][j] * alpha;
    if (epi == 1) {
      vv[0] += bb.x; vv[1] += bb.y; vv[2] += bb.z; vv[3] += bb.w;
    } else if (epi == 2) {
      int rm = resMod ? (m % resMod) : m;
      float4 rr = *(const float4*)(resid + (long long)rm * ldc + nbase);
      vv[0] += bb.x + rr.x; vv[1] += bb.y + rr.y;
      vv[2] += bb.z + rr.z; vv[3] += bb.w + rr.w;
    } else if (epi == 3) {
      vv[0] = gelu_tanh(vv[0] + bb.x); vv[1] = gelu_tanh(vv[1] + bb.y);
      vv[2] = gelu_tanh(vv[2] + bb.z); vv[3] = gelu_tanh(vv[3] + bb.w);
    }
    *(float4*)(C + (long long)m * ldc + nbase) =
        make_float4(vv[0], vv[1], vv[2], vv[3]);
  }
}

// ---------------- fused Linformer attention (flash-style) ----------------
// grid: (N/64 tiles, HEADS, CB batches). q is read AND overwritten in-place
// (each block touches only its own [64-row, head] slice; staged to LDS first).
// kp/vp: [CB, KLIN, DIM_] chunk-local.
__global__ __launch_bounds__(256) void attn_k(float* __restrict__ q,
                                              const float* __restrict__ kp,
                                              const float* __restrict__ vp,
                                              float scale) {
  int n0 = blockIdx.x * 64, hh = blockIdx.y, b = blockIdx.z;
  int t = threadIdx.x, tx = t & 15, ty = t >> 4;

  __shared__ float qt[64][68];
  __shared__ float kt[64][68];   // also reused as P-buffer
  __shared__ float vt[64][68];

  float* qptr = q + (long long)b * N_ * DIM_ + hh * DH;
  const float* kptr = kp + (long long)b * KLIN * DIM_ + hh * DH;
  const float* vptr = vp + (long long)b * KLIN * DIM_ + hh * DH;

  // stage q tile (pre-scaled)
  #pragma unroll
  for (int rep = 0; rep < 4; ++rep) {
    int r = (t >> 4) + rep * 16, d4 = tx * 4;
    float4 v = *(const float4*)(qptr + (long long)(n0 + r) * DIM_ + d4);
    qt[r][d4] = v.x * scale; qt[r][d4 + 1] = v.y * scale;
    qt[r][d4 + 2] = v.z * scale; qt[r][d4 + 3] = v.w * scale;
  }

  float out[4][4] = {};
  float mrow[4] = {-INFINITY, -INFINITY, -INFINITY, -INFINITY};
  float lrow[4] = {};

  for (int jc = 0; jc < KLIN / 64; ++jc) {
    __syncthreads();
    // stage kp/vp chunk [64 k-rows x 64 dh]
    #pragma unroll
    for (int rep = 0; rep < 4; ++rep) {
      int r = (t >> 4) + rep * 16, d4 = tx * 4;
      long long off = (long long)(jc * 64 + r) * DIM_ + d4;
      *(float4*)&kt[r][d4] = *(const float4*)(kptr + off);
      *(float4*)&vt[r][d4] = *(const float4*)(vptr + off);
    }
    __syncthreads();

    // S = qt @ kt^T  (rows ty*4+i, cols tx*4+j)
    float s[4][4] = {};
    #pragma unroll
    for (int d = 0; d < 64; d += 4) {
      float qa[4][4], kb[4][4];
      #pragma unroll
      for (int i = 0; i < 4; ++i)
        *(float4*)qa[i] = *(const float4*)&qt[ty * 4 + i][d];
      #pragma unroll
      for (int j = 0; j < 4; ++j)
        *(float4*)kb[j] = *(const float4*)&kt[tx * 4 + j][d];
      #pragma unroll
      for (int i = 0; i < 4; ++i)
        #pragma unroll
        for (int j = 0; j < 4; ++j)
          s[i][j] += qa[i][0] * kb[j][0] + qa[i][1] * kb[j][1] +
                     qa[i][2] * kb[j][2] + qa[i][3] * kb[j][3];
    }

    // online softmax update (row group = 16 lanes sharing ty)
    float al[4];
    #pragma unroll
    for (int i = 0; i < 4; ++i) {
      float cm = fmaxf(fmaxf(s[i][0], s[i][1]), fmaxf(s[i][2], s[i][3]));
      #pragma unroll
      for (int o = 1; o < 16; o <<= 1) cm = fmaxf(cm, __shfl_xor(cm, o));
      float mo = mrow[i], mn = fmaxf(mo, cm);
      al[i] = __expf(mo - mn);
      float rs = 0.f;
      #pragma unroll
      for (int j = 0; j < 4; ++j) { s[i][j] = __expf(s[i][j] - mn); rs += s[i][j]; }
      #pragma unroll
      for (int o = 1; o < 16; o <<= 1) rs += __shfl_xor(rs, o);
      lrow[i] = lrow[i] * al[i] + rs;
      mrow[i] = mn;
      #pragma unroll
      for (int j = 0; j < 4; ++j) out[i][j] *= al[i];
    }

    __syncthreads();  // kt S-reads done; reuse kt as P-buffer
    #pragma unroll
    for (int i = 0; i < 4; ++i)
      #pragma unroll
      for (int j = 0; j < 4; ++j) kt[ty * 4 + i][tx * 4 + j] = s[i][j];
    __syncthreads();

    // out += P @ vt
    #pragma unroll
    for (int kk = 0; kk < 64; kk += 4) {
      float pa[4][4], vb[4][4];
      #pragma unroll
      for (int i = 0; i < 4; ++i)
        *(float4*)pa[i] = *(const float4*)&kt[ty * 4 + i][kk];
      #pragma unroll
      for (int r = 0; r < 4; ++r)
        *(float4*)vb[r] = *(const float4*)&vt[kk + r][tx * 4];
      #pragma unroll
      for (int i = 0; i < 4; ++i)
        #pragma unroll
        for (int j = 0; j < 4; ++j)
          out[i][j] += pa[i][0] * vb[0][j] + pa[i][1] * vb[1][j] +
                       pa[i][2] * vb[2][j] + pa[i][3] * vb[3][j];
    }
  }

  // finalize + in-place write
  #pragma unroll
  for (int i = 0; i < 4; ++i) {
    float inv = 1.f / lrow[i];
    float4 o = make_float4(out[i][0] * inv, out[i][1] * inv, out[i][2] * inv,
                           out[i][3] * inv);
    *(float4*)(qptr + (long long)(n0 + ty * 4 + i) * DIM_ + tx * 4) = o;
  }
}

// ---------------- mean pool over N ----------------
__global__ __launch_bounds__(256) void pool_k(const float* __restrict__ h,
                                              float* __restrict__ pooled) {
  int b = blockIdx.y, dc = blockIdx.x * 64;
  int dd = threadIdx.x & 63, ng = threadIdx.x >> 6;
  float s = 0.f;
  for (int n = ng; n < N_; n += 4)
    s += h[((long long)b * N_ + n) * DIM_ + dc + dd];
  __shared__ float red[4][64];
  red[ng][dd] = s;
  __syncthreads();
  if (ng == 0)
    pooled[b * DIM_ + dc + dd] =
        (red[0][dd] + red[1][dd] + red[2][dd] + red[3][dd]) * (1.f / N_);
}

// ---------------- final FC [16,512]@[512,2] ----------------
__global__ __launch_bounds__(64) void fc_k(const float* __restrict__ pooled,
                                           const float* __restrict__ fc_w,
                                           const float* __restrict__ fc_b,
                                           float* __restrict__ out) {
  int t = threadIdx.x;
  if (t < B_ * NCLS) {
    int b = t >> 1, c = t & 1;
    float s = fc_b[c];
    for (int d = 0; d < DIM_; ++d) s += pooled[b * DIM_ + d] * fc_w[d * NCLS + c];
    out[t] = s;
  }
}

// ---------------- host side ----------------
static inline void launch_gemm(hipStream_t st, const float* A, const float* B,
                               const float* bias, const float* resid, float* C,
                               int M, int N, int K, int lda, int ldb, int ldc,
                               long long sAb, long long sBb, long long sCb,
                               int opA, int opB, int epi, float alpha,
                               int resMod, int batch) {
  dim3 g(N / 64, M / 64, batch), blk(256);
  hipLaunchKernelGGL(gemm_f32, g, blk, 0, st, A, B, bias, resid, C, M, N, K,
                     lda, ldb, ldc, sAb, sBb, sCb, opA, opB, epi, alpha,
                     resMod);
}

extern "C" void kernel_launch(void* const* d_in, const int* in_sizes, int n_in,
                              void* d_out, int out_size, void* d_ws,
                              size_t ws_size, hipStream_t stream) {
  const float* x     = (const float*)d_in[0];
  const float* emb_w = (const float*)d_in[1];
  const float* emb_b = (const float*)d_in[2];
  const float* pos   = (const float*)d_in[3];
  const float* ln1_s = (const float*)d_in[4];
  const float* ln1_b = (const float*)d_in[5];
  const float* wq    = (const float*)d_in[6];
  const float* wk    = (const float*)d_in[7];
  const float* wv    = (const float*)d_in[8];
  const float* pk    = (const float*)d_in[9];
  const float* pv    = (const float*)d_in[10];
  const float* wo    = (const float*)d_in[11];
  const float* wo_b  = (const float*)d_in[12];
  const float* ln2_s = (const float*)d_in[13];
  const float* ln2_b = (const float*)d_in[14];
  const float* w1    = (const float*)d_in[15];
  const float* b1    = (const float*)d_in[16];
  const float* w2    = (const float*)d_in[17];
  const float* b2    = (const float*)d_in[18];
  const float* fc_w  = (const float*)d_in[19];
  const float* fc_b  = (const float*)d_in[20];
  float* out = (float*)d_out;

  // ---- workspace: h slab (64MB) + arena (64MB) + kp/vp/pooled (~2.1MB) ----
  const long long SZ  = (long long)B_ * N_ * DIM_;    // 16.78M floats
  const long long CHW = (long long)CB * N_ * DIM_;    // 4.19M floats
  float* wsf  = (float*)d_ws;
  float* h     = wsf;
  float* arena = wsf + SZ;
  float* zc = arena;            // attn: LN1 chunk   | ffn: LN2 chunk (FROWS*DIM)
  float* qc = arena + CHW;      // attn: q / attn_out| ffn: ffnmid (FROWS*4*DIM)
  float* kc = arena + 2 * CHW;
  float* vc = arena + 3 * CHW;
  float* kpb = wsf + 2 * SZ;                      // [CB,KLIN,DIM] 2MB
  float* vpb = kpb + (long long)CB * KLIN * DIM_;
  float* pooled = vpb + (long long)CB * KLIN * DIM_;

  const int M = B_ * N_;       // 32768
  const float scale = 0.125f;  // DH^-0.5

  // embedding: h = x@emb_w + emb_b + pos (pos broadcast over batch)
  launch_gemm(stream, x, emb_w, emb_b, pos, h, M, DIM_, INDIM, INDIM, DIM_,
              DIM_, 0, 0, 0, 0, 0, 2, 1.f, N_, 1);

  for (int i = 0; i < DEPTH; ++i) {
    const float* wq_i = wq + (long long)i * DIM_ * DIM_;
    const float* wk_i = wk + (long long)i * DIM_ * DIM_;
    const float* wv_i = wv + (long long)i * DIM_ * DIM_;
    const float* pk_i = pk + (long long)i * N_ * KLIN;
    const float* pv_i = pv + (long long)i * N_ * KLIN;
    const float* wo_i = wo + (long long)i * DIM_ * DIM_;
    const float* w1_i = w1 + (long long)i * DIM_ * 4 * DIM_;
    const float* w2_i = w2 + (long long)i * 4 * DIM_ * DIM_;

    // ---- attention, chunked over CB=4 batches ----
    for (int c = 0; c < B_ / CB; ++c) {
      float* hc = h + (long long)c * CHW;
      hipLaunchKernelGGL(ln_k, dim3(CHROWS / 4), dim3(256), 0, stream, hc,
                         ln1_s + i * DIM_, ln1_b + i * DIM_, zc);
      launch_gemm(stream, zc, wq_i, nullptr, nullptr, qc, CHROWS, DIM_, DIM_,
                  DIM_, DIM_, DIM_, 0, 0, 0, 0, 0, 0, 1.f, 0, 1);
      launch_gemm(stream, zc, wk_i, nullptr, nullptr, kc, CHROWS, DIM_, DIM_,
                  DIM_, DIM_, DIM_, 0, 0, 0, 0, 0, 0, 1.f, 0, 1);
      launch_gemm(stream, zc, wv_i, nullptr, nullptr, vc, CHROWS, DIM_, DIM_,
                  DIM_, DIM_, DIM_, 0, 0, 0, 0, 0, 0, 1.f, 0, 1);
      // kpb[b] = pk^T @ kc[b] : M=256,N=512,K=2048, batch=CB
      launch_gemm(stream, pk_i, kc, nullptr, nullptr, kpb, KLIN, DIM_, N_,
                  KLIN, DIM_, DIM_, 0, (long long)N_ * DIM_,
                  (long long)KLIN * DIM_, 1, 0, 0, 1.f, 0, CB);
      launch_gemm(stream, pv_i, vc, nullptr, nullptr, vpb, KLIN, DIM_, N_,
                  KLIN, DIM_, DIM_, 0, (long long)N_ * DIM_,
                  (long long)KLIN * DIM_, 1, 0, 0, 1.f, 0, CB);
      // fused attention: qc <- attn_out (in place)
      hipLaunchKernelGGL(attn_k, dim3(N_ / 64, HEADS, CB), dim3(256), 0,
                         stream, qc, kpb, vpb, scale);
      // h_chunk += attn_out @ wo + wo_b
      launch_gemm(stream, qc, wo_i, wo_b + i * DIM_, hc, hc, CHROWS, DIM_,
                  DIM_, DIM_, DIM_, DIM_, 0, 0, 0, 0, 0, 2, 1.f, 0, 1);
    }

    // ---- FFN, chunked over FROWS rows ----
    for (int r0 = 0; r0 < M; r0 += FROWS) {
      float* hr = h + (long long)r0 * DIM_;
      hipLaunchKernelGGL(ln_k, dim3(FROWS / 4), dim3(256), 0, stream, hr,
                         ln2_s + i * DIM_, ln2_b + i * DIM_, zc);
      // ffnmid (in qc..) = gelu(zc @ w1 + b1): [FROWS, 2048]
      launch_gemm(stream, zc, w1_i, b1 + (long long)i * 4 * DIM_, nullptr, qc,
                  FROWS, 4 * DIM_, DIM_, DIM_, 4 * DIM_, 4 * DIM_, 0, 0, 0, 0,
                  0, 3, 1.f, 0, 1);
      // h_chunk += ffnmid @ w2 + b2
      launch_gemm(stream, qc, w2_i, b2 + (long long)i * DIM_, hr, hr, FROWS,
                  DIM_, 4 * DIM_, 4 * DIM_, DIM_, DIM_, 0, 0, 0, 0, 0, 2, 1.f,
                  0, 1);
    }
  }

  hipLaunchKernelGGL(pool_k, dim3(DIM_ / 64, B_), dim3(256), 0, stream, h,
                     pooled);
  hipLaunchKernelGGL(fc_k, dim3(1), dim3(64), 0, stream, pooled, fc_w, fc_b,
                     out);
}

// Round 4
// 11296.594 us; speedup vs baseline: 1.8828x; 1.8828x over previous
//
#include <hip/hip_runtime.h>
#include <math.h>

// ---------------- constants ----------------
#define B_    16
#define N_    2048
#define INDIM 64
#define DIM_  512
#define HEADS 8
#define DEPTH 4
#define KLIN  256
#define NCLS  2
#define DH    64
#define EPSF  1e-5f
#define CB    4                    // batches per attention chunk
#define CHROWS (CB * N_)           // 8192 rows per attention chunk
#define FROWS 4096                 // rows per FFN chunk

typedef __attribute__((ext_vector_type(8))) short short8v;
typedef __attribute__((ext_vector_type(4))) short short4v;
typedef __attribute__((ext_vector_type(4))) float f32x4;

// fp32 -> bf16 round-to-nearest-even (inputs are finite; no NaN guard)
__device__ __forceinline__ short f2bf(float f) {
  unsigned u = __float_as_uint(f);
  u += 0x7FFFu + ((u >> 16) & 1u);
  return (short)(u >> 16);
}

// ---------------- wave reductions ----------------
__device__ __forceinline__ float wave_sum(float v) {
  #pragma unroll
  for (int o = 32; o > 0; o >>= 1) v += __shfl_xor(v, o);
  return v;
}

// ---------------- LayerNorm: one wave per 512-wide row ----------------
__global__ __launch_bounds__(256) void ln_k(const float* __restrict__ h,
                                            const float* __restrict__ s,
                                            const float* __restrict__ b,
                                            float* __restrict__ z) {
  int lane = threadIdx.x & 63;
  long long row = ((long long)blockIdx.x << 2) + (threadIdx.x >> 6);
  const float* hr = h + row * DIM_ + lane * 8;
  float4 a = *(const float4*)hr;
  float4 c = *(const float4*)(hr + 4);
  float sum = a.x + a.y + a.z + a.w + c.x + c.y + c.z + c.w;
  sum = wave_sum(sum);
  float mu = sum * (1.f / DIM_);
  float d[8] = {a.x - mu, a.y - mu, a.z - mu, a.w - mu,
                c.x - mu, c.y - mu, c.z - mu, c.w - mu};
  float vs = 0.f;
  #pragma unroll
  for (int i = 0; i < 8; ++i) vs += d[i] * d[i];
  vs = wave_sum(vs);
  float rstd = rsqrtf(vs * (1.f / DIM_) + EPSF);
  const float* sp = s + lane * 8;
  const float* bp = b + lane * 8;
  float4 s0 = *(const float4*)sp, s1 = *(const float4*)(sp + 4);
  float4 b0 = *(const float4*)bp, b1 = *(const float4*)(bp + 4);
  float4 o0, o1;
  o0.x = d[0] * rstd * s0.x + b0.x; o0.y = d[1] * rstd * s0.y + b0.y;
  o0.z = d[2] * rstd * s0.z + b0.z; o0.w = d[3] * rstd * s0.w + b0.w;
  o1.x = d[4] * rstd * s1.x + b1.x; o1.y = d[5] * rstd * s1.y + b1.y;
  o1.z = d[6] * rstd * s1.z + b1.z; o1.w = d[7] * rstd * s1.w + b1.w;
  float* zr = z + row * DIM_ + lane * 8;
  *(float4*)zr = o0;
  *(float4*)(zr + 4) = o1;
}

__device__ __forceinline__ float gelu_tanh(float x) {
  float x3 = x * x * x;
  float t = tanhf(0.7978845608028654f * (x + 0.044715f * x3));
  return 0.5f * x * (1.f + t);
}

// ---------------- bf16 MFMA GEMM ----------------
// C[m,n] = alpha * sum_k A(m,k)*B[k,n] + epilogue. BN=128 fixed, BK=32.
// OPA: 0 -> A[m*lda+k]; 1 -> A[k*lda+m] (transpose-staged).
// epi: 0 none; 1 +bias[n]; 2 +bias[n]+resid[(m%resMod)*ldc+n]; 3 gelu(+bias)
template <int BM, int WM, int WN, int OPA>
__global__ __launch_bounds__(256) void gemm_mfma(
    const float* __restrict__ A, const float* __restrict__ B,
    const float* __restrict__ bias, const float* __restrict__ resid,
    float* __restrict__ C, int M, int N, int K, int lda, int ldb, int ldc,
    long long sAb, long long sBb, long long sCb, int epi, float alpha,
    int resMod) {
  constexpr int BN = 128;
  constexpr int WAVES_N = BN / WN;
  constexpr int MT = WM / 16, NT = WN / 16;
  static_assert((BM / WM) * WAVES_N == 4, "4 waves");

  int zz = blockIdx.z;
  A += (long long)zz * sAb;
  B += (long long)zz * sBb;
  C += (long long)zz * sCb;
  int bm = blockIdx.y * BM, bn = blockIdx.x * BN;
  int t = threadIdx.x;

  // rows padded to 40 shorts (20 words): conflict-free b128 frag reads
  __shared__ __align__(16) short Alds[BM][40];
  __shared__ __align__(16) short Blds[BN][40];

  int lane = t & 63, wid = t >> 6;
  int lr = lane & 15, q = lane >> 4;
  int wm = (wid / WAVES_N) * WM, wn = (wid % WAVES_N) * WN;

  f32x4 acc[MT][NT] = {};

  for (int k0 = 0; k0 < K; k0 += 32) {
    // ---- stage A ----
    if (OPA == 0) {
      #pragma unroll
      for (int rep = 0; rep < BM / 32; ++rep) {
        int r = (t >> 3) + rep * 32;
        int c = (t & 7) * 4;
        float4 v = *(const float4*)(A + (long long)(bm + r) * lda + k0 + c);
        short4v s = {f2bf(v.x), f2bf(v.y), f2bf(v.z), f2bf(v.w)};
        *(short4v*)&Alds[r][c] = s;
      }
    } else {
      constexpr int MBLK = BM / 4;
      if (t < 8 * MBLK) {
        int mb = t % MBLK, kb = t / MBLK;
        float4 v0 = *(const float4*)(A + (long long)(k0 + kb * 4 + 0) * lda + bm + mb * 4);
        float4 v1 = *(const float4*)(A + (long long)(k0 + kb * 4 + 1) * lda + bm + mb * 4);
        float4 v2 = *(const float4*)(A + (long long)(k0 + kb * 4 + 2) * lda + bm + mb * 4);
        float4 v3 = *(const float4*)(A + (long long)(k0 + kb * 4 + 3) * lda + bm + mb * 4);
        short4v s0 = {f2bf(v0.x), f2bf(v1.x), f2bf(v2.x), f2bf(v3.x)};
        short4v s1 = {f2bf(v0.y), f2bf(v1.y), f2bf(v2.y), f2bf(v3.y)};
        short4v s2 = {f2bf(v0.z), f2bf(v1.z), f2bf(v2.z), f2bf(v3.z)};
        short4v s3 = {f2bf(v0.w), f2bf(v1.w), f2bf(v2.w), f2bf(v3.w)};
        *(short4v*)&Alds[mb * 4 + 0][kb * 4] = s0;
        *(short4v*)&Alds[mb * 4 + 1][kb * 4] = s1;
        *(short4v*)&Alds[mb * 4 + 2][kb * 4] = s2;
        *(short4v*)&Alds[mb * 4 + 3][kb * 4] = s3;
      }
    }
    // ---- stage B (transpose [k][n] -> [n][k]) ----
    {
      int nb = t & 31, kb = t >> 5;
      float4 v0 = *(const float4*)(B + (long long)(k0 + kb * 4 + 0) * ldb + bn + nb * 4);
      float4 v1 = *(const float4*)(B + (long long)(k0 + kb * 4 + 1) * ldb + bn + nb * 4);
      float4 v2 = *(const float4*)(B + (long long)(k0 + kb * 4 + 2) * ldb + bn + nb * 4);
      float4 v3 = *(const float4*)(B + (long long)(k0 + kb * 4 + 3) * ldb + bn + nb * 4);
      short4v s0 = {f2bf(v0.x), f2bf(v1.x), f2bf(v2.x), f2bf(v3.x)};
      short4v s1 = {f2bf(v0.y), f2bf(v1.y), f2bf(v2.y), f2bf(v3.y)};
      short4v s2 = {f2bf(v0.z), f2bf(v1.z), f2bf(v2.z), f2bf(v3.z)};
      short4v s3 = {f2bf(v0.w), f2bf(v1.w), f2bf(v2.w), f2bf(v3.w)};
      *(short4v*)&Blds[nb * 4 + 0][kb * 4] = s0;
      *(short4v*)&Blds[nb * 4 + 1][kb * 4] = s1;
      *(short4v*)&Blds[nb * 4 + 2][kb * 4] = s2;
      *(short4v*)&Blds[nb * 4 + 3][kb * 4] = s3;
    }
    __syncthreads();

    short8v af[MT], bfv[NT];
    #pragma unroll
    for (int mi = 0; mi < MT; ++mi)
      af[mi] = *(const short8v*)&Alds[wm + mi * 16 + lr][q * 8];
    #pragma unroll
    for (int ni = 0; ni < NT; ++ni)
      bfv[ni] = *(const short8v*)&Blds[wn + ni * 16 + lr][q * 8];
    #pragma unroll
    for (int mi = 0; mi < MT; ++mi)
      #pragma unroll
      for (int ni = 0; ni < NT; ++ni)
        acc[mi][ni] = __builtin_amdgcn_mfma_f32_16x16x32_bf16(
            af[mi], bfv[ni], acc[mi][ni], 0, 0, 0);
    __syncthreads();
  }

  // ---- epilogue ----
  #pragma unroll
  for (int ni = 0; ni < NT; ++ni) {
    int col = bn + wn + ni * 16 + lr;
    float bval = (epi >= 1) ? bias[col] : 0.f;
    #pragma unroll
    for (int mi = 0; mi < MT; ++mi) {
      #pragma unroll
      for (int r = 0; r < 4; ++r) {
        int m = bm + wm + mi * 16 + q * 4 + r;
        float val = acc[mi][ni][r] * alpha;
        if (epi == 1) {
          val += bval;
        } else if (epi == 2) {
          int rm = resMod ? (m % resMod) : m;
          val += bval + resid[(long long)rm * ldc + col];
        } else if (epi == 3) {
          val = gelu_tanh(val + bval);
        }
        C[(long long)m * ldc + col] = val;
      }
    }
  }
}

// ---------------- fused Linformer attention (flash-style, fp32) ----------
__global__ __launch_bounds__(256) void attn_k(float* __restrict__ q,
                                              const float* __restrict__ kp,
                                              const float* __restrict__ vp,
                                              float scale) {
  int n0 = blockIdx.x * 64, hh = blockIdx.y, b = blockIdx.z;
  int t = threadIdx.x, tx = t & 15, ty = t >> 4;

  __shared__ float qt[64][68];
  __shared__ float kt[64][68];   // also reused as P-buffer
  __shared__ float vt[64][68];

  float* qptr = q + (long long)b * N_ * DIM_ + hh * DH;
  const float* kptr = kp + (long long)b * KLIN * DIM_ + hh * DH;
  const float* vptr = vp + (long long)b * KLIN * DIM_ + hh * DH;

  #pragma unroll
  for (int rep = 0; rep < 4; ++rep) {
    int r = (t >> 4) + rep * 16, d4 = tx * 4;
    float4 v = *(const float4*)(qptr + (long long)(n0 + r) * DIM_ + d4);
    qt[r][d4] = v.x * scale; qt[r][d4 + 1] = v.y * scale;
    qt[r][d4 + 2] = v.z * scale; qt[r][d4 + 3] = v.w * scale;
  }

  float out[4][4] = {};
  float mrow[4] = {-INFINITY, -INFINITY, -INFINITY, -INFINITY};
  float lrow[4] = {};

  for (int jc = 0; jc < KLIN / 64; ++jc) {
    __syncthreads();
    #pragma unroll
    for (int rep = 0; rep < 4; ++rep) {
      int r = (t >> 4) + rep * 16, d4 = tx * 4;
      long long off = (long long)(jc * 64 + r) * DIM_ + d4;
      *(float4*)&kt[r][d4] = *(const float4*)(kptr + off);
      *(float4*)&vt[r][d4] = *(const float4*)(vptr + off);
    }
    __syncthreads();

    float s[4][4] = {};
    #pragma unroll
    for (int d = 0; d < 64; d += 4) {
      float qa[4][4], kb[4][4];
      #pragma unroll
      for (int i = 0; i < 4; ++i)
        *(float4*)qa[i] = *(const float4*)&qt[ty * 4 + i][d];
      #pragma unroll
      for (int j = 0; j < 4; ++j)
        *(float4*)kb[j] = *(const float4*)&kt[tx * 4 + j][d];
      #pragma unroll
      for (int i = 0; i < 4; ++i)
        #pragma unroll
        for (int j = 0; j < 4; ++j)
          s[i][j] += qa[i][0] * kb[j][0] + qa[i][1] * kb[j][1] +
                     qa[i][2] * kb[j][2] + qa[i][3] * kb[j][3];
    }

    float al[4];
    #pragma unroll
    for (int i = 0; i < 4; ++i) {
      float cm = fmaxf(fmaxf(s[i][0], s[i][1]), fmaxf(s[i][2], s[i][3]));
      #pragma unroll
      for (int o = 1; o < 16; o <<= 1) cm = fmaxf(cm, __shfl_xor(cm, o));
      float mo = mrow[i], mn = fmaxf(mo, cm);
      al[i] = __expf(mo - mn);
      float rs = 0.f;
      #pragma unroll
      for (int j = 0; j < 4; ++j) { s[i][j] = __expf(s[i][j] - mn); rs += s[i][j]; }
      #pragma unroll
      for (int o = 1; o < 16; o <<= 1) rs += __shfl_xor(rs, o);
      lrow[i] = lrow[i] * al[i] + rs;
      mrow[i] = mn;
      #pragma unroll
      for (int j = 0; j < 4; ++j) out[i][j] *= al[i];
    }

    __syncthreads();
    #pragma unroll
    for (int i = 0; i < 4; ++i)
      #pragma unroll
      for (int j = 0; j < 4; ++j) kt[ty * 4 + i][tx * 4 + j] = s[i][j];
    __syncthreads();

    #pragma unroll
    for (int kk = 0; kk < 64; kk += 4) {
      float pa[4][4], vb[4][4];
      #pragma unroll
      for (int i = 0; i < 4; ++i)
        *(float4*)pa[i] = *(const float4*)&kt[ty * 4 + i][kk];
      #pragma unroll
      for (int r = 0; r < 4; ++r)
        *(float4*)vb[r] = *(const float4*)&vt[kk + r][tx * 4];
      #pragma unroll
      for (int i = 0; i < 4; ++i)
        #pragma unroll
        for (int j = 0; j < 4; ++j)
          out[i][j] += pa[i][0] * vb[0][j] + pa[i][1] * vb[1][j] +
                       pa[i][2] * vb[2][j] + pa[i][3] * vb[3][j];
    }
  }

  #pragma unroll
  for (int i = 0; i < 4; ++i) {
    float inv = 1.f / lrow[i];
    float4 o = make_float4(out[i][0] * inv, out[i][1] * inv, out[i][2] * inv,
                           out[i][3] * inv);
    *(float4*)(qptr + (long long)(n0 + ty * 4 + i) * DIM_ + tx * 4) = o;
  }
}

// ---------------- mean pool over N ----------------
__global__ __launch_bounds__(256) void pool_k(const float* __restrict__ h,
                                              float* __restrict__ pooled) {
  int b = blockIdx.y, dc = blockIdx.x * 64;
  int dd = threadIdx.x & 63, ng = threadIdx.x >> 6;
  float s = 0.f;
  for (int n = ng; n < N_; n += 4)
    s += h[((long long)b * N_ + n) * DIM_ + dc + dd];
  __shared__ float red[4][64];
  red[ng][dd] = s;
  __syncthreads();
  if (ng == 0)
    pooled[b * DIM_ + dc + dd] =
        (red[0][dd] + red[1][dd] + red[2][dd] + red[3][dd]) * (1.f / N_);
}

// ---------------- final FC [16,512]@[512,2] ----------------
__global__ __launch_bounds__(64) void fc_k(const float* __restrict__ pooled,
                                           const float* __restrict__ fc_w,
                                           const float* __restrict__ fc_b,
                                           float* __restrict__ out) {
  int t = threadIdx.x;
  if (t < B_ * NCLS) {
    int b = t >> 1, c = t & 1;
    float s = fc_b[c];
    for (int d = 0; d < DIM_; ++d) s += pooled[b * DIM_ + d] * fc_w[d * NCLS + c];
    out[t] = s;
  }
}

// ---------------- host-side wrappers ----------------
static inline void gemm128(hipStream_t st, const float* A, const float* B,
                           const float* bias, const float* resid, float* C,
                           int M, int N, int K, int lda, int ldb, int ldc,
                           long long sAb, long long sBb, long long sCb,
                           int epi, float alpha, int resMod, int batch) {
  dim3 g(N / 128, M / 128, batch);
  hipLaunchKernelGGL((gemm_mfma<128, 64, 64, 0>), g, dim3(256), 0, st, A, B,
                     bias, resid, C, M, N, K, lda, ldb, ldc, sAb, sBb, sCb,
                     epi, alpha, resMod);
}
static inline void gemm64(hipStream_t st, const float* A, const float* B,
                          const float* bias, const float* resid, float* C,
                          int M, int N, int K, int lda, int ldb, int ldc,
                          long long sAb, long long sBb, long long sCb,
                          int epi, float alpha, int resMod, int batch) {
  dim3 g(N / 128, M / 64, batch);
  hipLaunchKernelGGL((gemm_mfma<64, 64, 32, 0>), g, dim3(256), 0, st, A, B,
                     bias, resid, C, M, N, K, lda, ldb, ldc, sAb, sBb, sCb,
                     epi, alpha, resMod);
}
static inline void gemm64t(hipStream_t st, const float* A, const float* B,
                           const float* bias, const float* resid, float* C,
                           int M, int N, int K, int lda, int ldb, int ldc,
                           long long sAb, long long sBb, long long sCb,
                           int epi, float alpha, int resMod, int batch) {
  dim3 g(N / 128, M / 64, batch);
  hipLaunchKernelGGL((gemm_mfma<64, 64, 32, 1>), g, dim3(256), 0, st, A, B,
                     bias, resid, C, M, N, K, lda, ldb, ldc, sAb, sBb, sCb,
                     epi, alpha, resMod);
}

extern "C" void kernel_launch(void* const* d_in, const int* in_sizes, int n_in,
                              void* d_out, int out_size, void* d_ws,
                              size_t ws_size, hipStream_t stream) {
  const float* x     = (const float*)d_in[0];
  const float* emb_w = (const float*)d_in[1];
  const float* emb_b = (const float*)d_in[2];
  const float* pos   = (const float*)d_in[3];
  const float* ln1_s = (const float*)d_in[4];
  const float* ln1_b = (const float*)d_in[5];
  const float* wq    = (const float*)d_in[6];
  const float* wk    = (const float*)d_in[7];
  const float* wv    = (const float*)d_in[8];
  const float* pk    = (const float*)d_in[9];
  const float* pv    = (const float*)d_in[10];
  const float* wo    = (const float*)d_in[11];
  const float* wo_b  = (const float*)d_in[12];
  const float* ln2_s = (const float*)d_in[13];
  const float* ln2_b = (const float*)d_in[14];
  const float* w1    = (const float*)d_in[15];
  const float* b1    = (const float*)d_in[16];
  const float* w2    = (const float*)d_in[17];
  const float* b2    = (const float*)d_in[18];
  const float* fc_w  = (const float*)d_in[19];
  const float* fc_b  = (const float*)d_in[20];
  float* out = (float*)d_out;

  // ---- workspace: h slab (64MB) + arena (64MB) + kp/vp/pooled (~2.1MB) ----
  const long long SZ  = (long long)B_ * N_ * DIM_;
  const long long CHW = (long long)CB * N_ * DIM_;
  float* wsf  = (float*)d_ws;
  float* h     = wsf;
  float* arena = wsf + SZ;
  float* zc = arena;
  float* qc = arena + CHW;
  float* kc = arena + 2 * CHW;
  float* vc = arena + 3 * CHW;
  float* kpb = wsf + 2 * SZ;
  float* vpb = kpb + (long long)CB * KLIN * DIM_;
  float* pooled = vpb + (long long)CB * KLIN * DIM_;

  const int M = B_ * N_;
  const float scale = 0.125f;

  // embedding: h = x@emb_w + emb_b + pos (pos broadcast over batch)
  gemm128(stream, x, emb_w, emb_b, pos, h, M, DIM_, INDIM, INDIM, DIM_, DIM_,
          0, 0, 0, 2, 1.f, N_, 1);

  for (int i = 0; i < DEPTH; ++i) {
    const float* wq_i = wq + (long long)i * DIM_ * DIM_;
    const float* wk_i = wk + (long long)i * DIM_ * DIM_;
    const float* wv_i = wv + (long long)i * DIM_ * DIM_;
    const float* pk_i = pk + (long long)i * N_ * KLIN;
    const float* pv_i = pv + (long long)i * N_ * KLIN;
    const float* wo_i = wo + (long long)i * DIM_ * DIM_;
    const float* w1_i = w1 + (long long)i * DIM_ * 4 * DIM_;
    const float* w2_i = w2 + (long long)i * 4 * DIM_ * DIM_;

    // ---- attention, chunked over CB=4 batches ----
    for (int c = 0; c < B_ / CB; ++c) {
      float* hc = h + (long long)c * CHW;
      hipLaunchKernelGGL(ln_k, dim3(CHROWS / 4), dim3(256), 0, stream, hc,
                         ln1_s + i * DIM_, ln1_b + i * DIM_, zc);
      gemm128(stream, zc, wq_i, nullptr, nullptr, qc, CHROWS, DIM_, DIM_,
              DIM_, DIM_, DIM_, 0, 0, 0, 0, 1.f, 0, 1);
      gemm128(stream, zc, wk_i, nullptr, nullptr, kc, CHROWS, DIM_, DIM_,
              DIM_, DIM_, DIM_, 0, 0, 0, 0, 1.f, 0, 1);
      gemm128(stream, zc, wv_i, nullptr, nullptr, vc, CHROWS, DIM_, DIM_,
              DIM_, DIM_, DIM_, 0, 0, 0, 0, 1.f, 0, 1);
      // kpb[b] = pk^T @ kc[b] : M=256,N=512,K=2048, batch=CB (A transposed)
      gemm64t(stream, pk_i, kc, nullptr, nullptr, kpb, KLIN, DIM_, N_, KLIN,
              DIM_, DIM_, 0, (long long)N_ * DIM_, (long long)KLIN * DIM_, 0,
              1.f, 0, CB);
      gemm64t(stream, pv_i, vc, nullptr, nullptr, vpb, KLIN, DIM_, N_, KLIN,
              DIM_, DIM_, 0, (long long)N_ * DIM_, (long long)KLIN * DIM_, 0,
              1.f, 0, CB);
      // fused attention: qc <- attn_out (in place)
      hipLaunchKernelGGL(attn_k, dim3(N_ / 64, HEADS, CB), dim3(256), 0,
                         stream, qc, kpb, vpb, scale);
      // h_chunk += attn_out @ wo + wo_b
      gemm128(stream, qc, wo_i, wo_b + i * DIM_, hc, hc, CHROWS, DIM_, DIM_,
              DIM_, DIM_, DIM_, 0, 0, 0, 2, 1.f, 0, 1);
    }

    // ---- FFN, chunked over FROWS rows ----
    for (int r0 = 0; r0 < M; r0 += FROWS) {
      float* hr = h + (long long)r0 * DIM_;
      hipLaunchKernelGGL(ln_k, dim3(FROWS / 4), dim3(256), 0, stream, hr,
                         ln2_s + i * DIM_, ln2_b + i * DIM_, zc);
      // ffnmid (qc) = gelu(zc @ w1 + b1): [FROWS, 2048]
      gemm128(stream, zc, w1_i, b1 + (long long)i * 4 * DIM_, nullptr, qc,
              FROWS, 4 * DIM_, DIM_, DIM_, 4 * DIM_, 4 * DIM_, 0, 0, 0, 3,
              1.f, 0, 1);
      // h_chunk += ffnmid @ w2 + b2  (64-row tiles -> 256 blocks)
      gemm64(stream, qc, w2_i, b2 + (long long)i * DIM_, hr, hr, FROWS, DIM_,
             4 * DIM_, 4 * DIM_, DIM_, DIM_, 0, 0, 0, 2, 1.f, 0, 1);
    }
  }

  hipLaunchKernelGGL(pool_k, dim3(DIM_ / 64, B_), dim3(256), 0, stream, h,
                     pooled);
  hipLaunchKernelGGL(fc_k, dim3(1), dim3(64), 0, stream, pooled, fc_w, fc_b,
                     out);
}

// Round 5
// 7344.526 us; speedup vs baseline: 2.8960x; 1.5381x over previous
//
#include <hip/hip_runtime.h>
#include <math.h>

// ---------------- constants ----------------
#define B_    16
#define N_    2048
#define INDIM 64
#define DIM_  512
#define HEADS 8
#define DEPTH 4
#define KLIN  256
#define NCLS  2
#define DH    64
#define EPSF  1e-5f
#define CB    4                    // batches per attention chunk
#define CHROWS (CB * N_)           // 8192 rows per attention chunk
#define FROWS 4096                 // rows per FFN chunk

typedef __attribute__((ext_vector_type(8))) short short8v;
typedef __attribute__((ext_vector_type(4))) short short4v;
typedef __attribute__((ext_vector_type(4))) float f32x4;

// fp32 -> bf16 round-to-nearest-even (inputs are finite; no NaN guard)
__device__ __forceinline__ short f2bf(float f) {
  unsigned u = __float_as_uint(f);
  u += 0x7FFFu + ((u >> 16) & 1u);
  return (short)(u >> 16);
}

// ---------------- wave reductions ----------------
__device__ __forceinline__ float wave_sum(float v) {
  #pragma unroll
  for (int o = 32; o > 0; o >>= 1) v += __shfl_xor(v, o);
  return v;
}

// ---------------- LayerNorm: one wave per 512-wide row ----------------
__global__ __launch_bounds__(256) void ln_k(const float* __restrict__ h,
                                            const float* __restrict__ s,
                                            const float* __restrict__ b,
                                            float* __restrict__ z) {
  int lane = threadIdx.x & 63;
  long long row = ((long long)blockIdx.x << 2) + (threadIdx.x >> 6);
  const float* hr = h + row * DIM_ + lane * 8;
  float4 a = *(const float4*)hr;
  float4 c = *(const float4*)(hr + 4);
  float sum = a.x + a.y + a.z + a.w + c.x + c.y + c.z + c.w;
  sum = wave_sum(sum);
  float mu = sum * (1.f / DIM_);
  float d[8] = {a.x - mu, a.y - mu, a.z - mu, a.w - mu,
                c.x - mu, c.y - mu, c.z - mu, c.w - mu};
  float vs = 0.f;
  #pragma unroll
  for (int i = 0; i < 8; ++i) vs += d[i] * d[i];
  vs = wave_sum(vs);
  float rstd = rsqrtf(vs * (1.f / DIM_) + EPSF);
  const float* sp = s + lane * 8;
  const float* bp = b + lane * 8;
  float4 s0 = *(const float4*)sp, s1 = *(const float4*)(sp + 4);
  float4 b0 = *(const float4*)bp, b1 = *(const float4*)(bp + 4);
  float4 o0, o1;
  o0.x = d[0] * rstd * s0.x + b0.x; o0.y = d[1] * rstd * s0.y + b0.y;
  o0.z = d[2] * rstd * s0.z + b0.z; o0.w = d[3] * rstd * s0.w + b0.w;
  o1.x = d[4] * rstd * s1.x + b1.x; o1.y = d[5] * rstd * s1.y + b1.y;
  o1.z = d[6] * rstd * s1.z + b1.z; o1.w = d[7] * rstd * s1.w + b1.w;
  float* zr = z + row * DIM_ + lane * 8;
  *(float4*)zr = o0;
  *(float4*)(zr + 4) = o1;
}

__device__ __forceinline__ float gelu_tanh(float x) {
  float x3 = x * x * x;
  float t = tanhf(0.7978845608028654f * (x + 0.044715f * x3));
  return 0.5f * x * (1.f + t);
}

// ---------------- bf16 MFMA GEMM ----------------
// C[m,n] = alpha * sum_k A(m,k)*B[k,n] + epilogue. BN=128 fixed, BK=32.
// OPA: 0 -> A[m*lda+k]; 1 -> A[k*lda+m] (transpose-staged).
// DUAL: 0 none; 1 -> use A2 for output rows >= KLIN (A-side stack pk|pv);
//       2 -> use B2 for output rows >= KLIN (B-side stack wk|wv).
// epi: 0 none; 1 +bias[n]; 2 +bias[n]+resid[(m%resMod)*ldc+n]; 3 gelu(+bias)
template <int BM, int WM, int WN, int OPA, int DUAL>
__global__ __launch_bounds__(256) void gemm_mfma(
    const float* __restrict__ A, const float* __restrict__ A2,
    const float* __restrict__ B, const float* __restrict__ B2,
    const float* __restrict__ bias, const float* __restrict__ resid,
    float* __restrict__ C, int M, int N, int K, int lda, int ldb, int ldc,
    long long sAb, long long sBb, long long sCb, int epi, float alpha,
    int resMod) {
  constexpr int BN = 128;
  constexpr int WAVES_N = BN / WN;
  constexpr int MT = WM / 16, NT = WN / 16;
  static_assert((BM / WM) * WAVES_N == 4, "4 waves");

  int zz = blockIdx.z;
  A += (long long)zz * sAb;
  B += (long long)zz * sBb;
  C += (long long)zz * sCb;
  int bm = blockIdx.y * BM, bn = blockIdx.x * BN;
  int t = threadIdx.x;

  const float* Ause = A;
  int bmA = bm;
  if (DUAL == 1 && bm >= KLIN) { Ause = A2; bmA = bm - KLIN; }
  const float* Buse = B;
  if (DUAL == 2 && bm >= KLIN) { Buse = B2; }

  // rows padded to 40 shorts (20 words): conflict-free b128 frag reads
  __shared__ __align__(16) short Alds[BM][40];
  __shared__ __align__(16) short Blds[BN][40];

  int lane = t & 63, wid = t >> 6;
  int lr = lane & 15, q = lane >> 4;
  int wm = (wid / WAVES_N) * WM, wn = (wid % WAVES_N) * WN;

  f32x4 acc[MT][NT] = {};

  for (int k0 = 0; k0 < K; k0 += 32) {
    // ---- stage A ----
    if (OPA == 0) {
      #pragma unroll
      for (int rep = 0; rep < BM / 32; ++rep) {
        int r = (t >> 3) + rep * 32;
        int c = (t & 7) * 4;
        float4 v = *(const float4*)(Ause + (long long)(bmA + r) * lda + k0 + c);
        short4v s = {f2bf(v.x), f2bf(v.y), f2bf(v.z), f2bf(v.w)};
        *(short4v*)&Alds[r][c] = s;
      }
    } else {
      constexpr int MBLK = BM / 4;
      if (t < 8 * MBLK) {
        int mb = t % MBLK, kb = t / MBLK;
        float4 v0 = *(const float4*)(Ause + (long long)(k0 + kb * 4 + 0) * lda + bmA + mb * 4);
        float4 v1 = *(const float4*)(Ause + (long long)(k0 + kb * 4 + 1) * lda + bmA + mb * 4);
        float4 v2 = *(const float4*)(Ause + (long long)(k0 + kb * 4 + 2) * lda + bmA + mb * 4);
        float4 v3 = *(const float4*)(Ause + (long long)(k0 + kb * 4 + 3) * lda + bmA + mb * 4);
        short4v s0 = {f2bf(v0.x), f2bf(v1.x), f2bf(v2.x), f2bf(v3.x)};
        short4v s1 = {f2bf(v0.y), f2bf(v1.y), f2bf(v2.y), f2bf(v3.y)};
        short4v s2 = {f2bf(v0.z), f2bf(v1.z), f2bf(v2.z), f2bf(v3.z)};
        short4v s3 = {f2bf(v0.w), f2bf(v1.w), f2bf(v2.w), f2bf(v3.w)};
        *(short4v*)&Alds[mb * 4 + 0][kb * 4] = s0;
        *(short4v*)&Alds[mb * 4 + 1][kb * 4] = s1;
        *(short4v*)&Alds[mb * 4 + 2][kb * 4] = s2;
        *(short4v*)&Alds[mb * 4 + 3][kb * 4] = s3;
      }
    }
    // ---- stage B (transpose [k][n] -> [n][k]) ----
    {
      int nb = t & 31, kb = t >> 5;
      float4 v0 = *(const float4*)(Buse + (long long)(k0 + kb * 4 + 0) * ldb + bn + nb * 4);
      float4 v1 = *(const float4*)(Buse + (long long)(k0 + kb * 4 + 1) * ldb + bn + nb * 4);
      float4 v2 = *(const float4*)(Buse + (long long)(k0 + kb * 4 + 2) * ldb + bn + nb * 4);
      float4 v3 = *(const float4*)(Buse + (long long)(k0 + kb * 4 + 3) * ldb + bn + nb * 4);
      short4v s0 = {f2bf(v0.x), f2bf(v1.x), f2bf(v2.x), f2bf(v3.x)};
      short4v s1 = {f2bf(v0.y), f2bf(v1.y), f2bf(v2.y), f2bf(v3.y)};
      short4v s2 = {f2bf(v0.z), f2bf(v1.z), f2bf(v2.z), f2bf(v3.z)};
      short4v s3 = {f2bf(v0.w), f2bf(v1.w), f2bf(v2.w), f2bf(v3.w)};
      *(short4v*)&Blds[nb * 4 + 0][kb * 4] = s0;
      *(short4v*)&Blds[nb * 4 + 1][kb * 4] = s1;
      *(short4v*)&Blds[nb * 4 + 2][kb * 4] = s2;
      *(short4v*)&Blds[nb * 4 + 3][kb * 4] = s3;
    }
    __syncthreads();

    short8v af[MT], bfv[NT];
    #pragma unroll
    for (int mi = 0; mi < MT; ++mi)
      af[mi] = *(const short8v*)&Alds[wm + mi * 16 + lr][q * 8];
    #pragma unroll
    for (int ni = 0; ni < NT; ++ni)
      bfv[ni] = *(const short8v*)&Blds[wn + ni * 16 + lr][q * 8];
    #pragma unroll
    for (int mi = 0; mi < MT; ++mi)
      #pragma unroll
      for (int ni = 0; ni < NT; ++ni)
        acc[mi][ni] = __builtin_amdgcn_mfma_f32_16x16x32_bf16(
            af[mi], bfv[ni], acc[mi][ni], 0, 0, 0);
    __syncthreads();
  }

  // ---- epilogue ----
  #pragma unroll
  for (int ni = 0; ni < NT; ++ni) {
    int col = bn + wn + ni * 16 + lr;
    float bval = (epi >= 1) ? bias[col] : 0.f;
    #pragma unroll
    for (int mi = 0; mi < MT; ++mi) {
      #pragma unroll
      for (int r = 0; r < 4; ++r) {
        int m = bm + wm + mi * 16 + q * 4 + r;
        float val = acc[mi][ni][r] * alpha;
        if (epi == 1) {
          val += bval;
        } else if (epi == 2) {
          int rm = resMod ? (m % resMod) : m;
          val += bval + resid[(long long)rm * ldc + col];
        } else if (epi == 3) {
          val = gelu_tanh(val + bval);
        }
        C[(long long)m * ldc + col] = val;
      }
    }
  }
}

// ---------------- fused Linformer attention, bf16 MFMA ----------------
// grid: (N/64, HEADS, CB). qc is read AND overwritten in-place (each block
// owns its [64-row, head] slice). kvp: [CB, 2*KLIN, DIM]: rows 0..255 = kp,
// rows 256..511 = vp (per batch). All 256 keys handled per block (no online
// softmax). 4 waves; wave w owns Q rows 16w..16w+15.
__global__ __launch_bounds__(256) void attn_k(float* __restrict__ qc,
                                              const float* __restrict__ kvp,
                                              float scale) {
  int n0 = blockIdx.x * 64, hh = blockIdx.y, b = blockIdx.z;
  int t = threadIdx.x;
  int lane = t & 63, w = t >> 6;
  int lr = lane & 15, qd = lane >> 4;

  __shared__ __align__(16) short Qlds[64][72];
  __shared__ __align__(16) short Kbuf[256 * 72];   // Klds, then aliased as Plds
  __shared__ __align__(16) short Vt[64][264];      // V transposed [dh][key]
  auto Klds = (short(*)[72])Kbuf;
  auto Plds = (short(*)[264])Kbuf;

  float* qptr = qc + (long long)b * N_ * DIM_ + hh * DH;
  const float* kptr = kvp + (long long)b * 2 * KLIN * DIM_ + hh * DH;
  const float* vptr = kptr + (long long)KLIN * DIM_;

  // ---- stage Q (pre-scaled) ----
  #pragma unroll
  for (int rep = 0; rep < 4; ++rep) {
    int r = rep * 16 + (t >> 4), f4 = (t & 15) * 4;
    float4 v = *(const float4*)(qptr + (long long)(n0 + r) * DIM_ + f4);
    short4v s = {f2bf(v.x * scale), f2bf(v.y * scale), f2bf(v.z * scale),
                 f2bf(v.w * scale)};
    *(short4v*)&Qlds[r][f4] = s;
  }
  // ---- stage K [key][dh] ----
  #pragma unroll
  for (int rep = 0; rep < 16; ++rep) {
    int r = rep * 16 + (t >> 4), f4 = (t & 15) * 4;
    float4 v = *(const float4*)(kptr + (long long)r * DIM_ + f4);
    short4v s = {f2bf(v.x), f2bf(v.y), f2bf(v.z), f2bf(v.w)};
    *(short4v*)&Klds[r][f4] = s;
  }
  // ---- stage V transposed: Vt[dh][key] ----
  #pragma unroll
  for (int rep = 0; rep < 4; ++rep) {
    int key0 = rep * 64 + (t >> 4) * 4;
    int dh0 = (t & 15) * 4;
    float4 v0 = *(const float4*)(vptr + (long long)(key0 + 0) * DIM_ + dh0);
    float4 v1 = *(const float4*)(vptr + (long long)(key0 + 1) * DIM_ + dh0);
    float4 v2 = *(const float4*)(vptr + (long long)(key0 + 2) * DIM_ + dh0);
    float4 v3 = *(const float4*)(vptr + (long long)(key0 + 3) * DIM_ + dh0);
    short4v s0 = {f2bf(v0.x), f2bf(v1.x), f2bf(v2.x), f2bf(v3.x)};
    short4v s1 = {f2bf(v0.y), f2bf(v1.y), f2bf(v2.y), f2bf(v3.y)};
    short4v s2 = {f2bf(v0.z), f2bf(v1.z), f2bf(v2.z), f2bf(v3.z)};
    short4v s3 = {f2bf(v0.w), f2bf(v1.w), f2bf(v2.w), f2bf(v3.w)};
    *(short4v*)&Vt[dh0 + 0][key0] = s0;
    *(short4v*)&Vt[dh0 + 1][key0] = s1;
    *(short4v*)&Vt[dh0 + 2][key0] = s2;
    *(short4v*)&Vt[dh0 + 3][key0] = s3;
  }
  __syncthreads();

  // ---- S = Q @ K^T : wave w -> rows 16w..+15, all 256 cols ----
  short8v a0 = *(const short8v*)&Qlds[16 * w + lr][qd * 8];
  short8v a1 = *(const short8v*)&Qlds[16 * w + lr][32 + qd * 8];
  f32x4 sacc[16];
  #pragma unroll
  for (int nt = 0; nt < 16; ++nt) {
    short8v b0 = *(const short8v*)&Klds[nt * 16 + lr][qd * 8];
    short8v b1 = *(const short8v*)&Klds[nt * 16 + lr][32 + qd * 8];
    f32x4 acc = {};
    acc = __builtin_amdgcn_mfma_f32_16x16x32_bf16(a0, b0, acc, 0, 0, 0);
    acc = __builtin_amdgcn_mfma_f32_16x16x32_bf16(a1, b1, acc, 0, 0, 0);
    sacc[nt] = acc;
  }

  // ---- softmax over 256 cols, fully in-register ----
  // lane holds cols {lr + 16nt}, rows 16w + qd*4 + r. Col-reduce = own 16
  // values + shuffle across the quad's 16 lanes (xor 1,2,4,8).
  float l[4];
  #pragma unroll
  for (int r = 0; r < 4; ++r) {
    float m = -1e30f;
    #pragma unroll
    for (int nt = 0; nt < 16; ++nt) m = fmaxf(m, sacc[nt][r]);
    #pragma unroll
    for (int o = 1; o < 16; o <<= 1) m = fmaxf(m, __shfl_xor(m, o));
    float rs = 0.f;
    #pragma unroll
    for (int nt = 0; nt < 16; ++nt) {
      float e = __expf(sacc[nt][r] - m);
      sacc[nt][r] = e;
      rs += e;
    }
    #pragma unroll
    for (int o = 1; o < 16; o <<= 1) rs += __shfl_xor(rs, o);
    l[r] = rs;
  }

  __syncthreads();  // all Klds B-frag reads done; reuse as Plds
  #pragma unroll
  for (int nt = 0; nt < 16; ++nt)
    #pragma unroll
    for (int r = 0; r < 4; ++r)
      Plds[16 * w + qd * 4 + r][nt * 16 + lr] = f2bf(sacc[nt][r]);
  __syncthreads();

  // ---- out = P @ V : rows 16w..+15, dh 0..63 ----
  f32x4 out[4] = {};
  #pragma unroll
  for (int k0 = 0; k0 < 8; ++k0) {
    short8v ap = *(const short8v*)&Plds[16 * w + lr][k0 * 32 + qd * 8];
    #pragma unroll
    for (int n2 = 0; n2 < 4; ++n2) {
      short8v bv = *(const short8v*)&Vt[n2 * 16 + lr][k0 * 32 + qd * 8];
      out[n2] = __builtin_amdgcn_mfma_f32_16x16x32_bf16(ap, bv, out[n2], 0, 0, 0);
    }
  }

  #pragma unroll
  for (int r = 0; r < 4; ++r) {
    float inv = 1.f / l[r];
    long long rowoff = (long long)(n0 + 16 * w + qd * 4 + r) * DIM_;
    #pragma unroll
    for (int n2 = 0; n2 < 4; ++n2)
      qptr[rowoff + n2 * 16 + lr] = out[n2][r] * inv;
  }
}

// ---------------- mean pool over N ----------------
__global__ __launch_bounds__(256) void pool_k(const float* __restrict__ h,
                                              float* __restrict__ pooled) {
  int b = blockIdx.y, dc = blockIdx.x * 64;
  int dd = threadIdx.x & 63, ng = threadIdx.x >> 6;
  float s = 0.f;
  for (int n = ng; n < N_; n += 4)
    s += h[((long long)b * N_ + n) * DIM_ + dc + dd];
  __shared__ float red[4][64];
  red[ng][dd] = s;
  __syncthreads();
  if (ng == 0)
    pooled[b * DIM_ + dc + dd] =
        (red[0][dd] + red[1][dd] + red[2][dd] + red[3][dd]) * (1.f / N_);
}

// ---------------- final FC [16,512]@[512,2] ----------------
__global__ __launch_bounds__(64) void fc_k(const float* __restrict__ pooled,
                                           const float* __restrict__ fc_w,
                                           const float* __restrict__ fc_b,
                                           float* __restrict__ out) {
  int t = threadIdx.x;
  if (t < B_ * NCLS) {
    int b = t >> 1, c = t & 1;
    float s = fc_b[c];
    for (int d = 0; d < DIM_; ++d) s += pooled[b * DIM_ + d] * fc_w[d * NCLS + c];
    out[t] = s;
  }
}

// ---------------- host-side wrappers ----------------
static inline void gemm128(hipStream_t st, const float* A, const float* B,
                           const float* bias, const float* resid, float* C,
                           int M, int N, int K, int lda, int ldb, int ldc,
                           long long sAb, long long sBb, long long sCb,
                           int epi, float alpha, int resMod, int batch) {
  dim3 g(N / 128, M / 128, batch);
  hipLaunchKernelGGL((gemm_mfma<128, 64, 64, 0, 0>), g, dim3(256), 0, st, A,
                     nullptr, B, nullptr, bias, resid, C, M, N, K, lda, ldb,
                     ldc, sAb, sBb, sCb, epi, alpha, resMod);
}
static inline void gemm64(hipStream_t st, const float* A, const float* B,
                          const float* bias, const float* resid, float* C,
                          int M, int N, int K, int lda, int ldb, int ldc,
                          long long sAb, long long sBb, long long sCb,
                          int epi, float alpha, int resMod, int batch) {
  dim3 g(N / 128, M / 64, batch);
  hipLaunchKernelGGL((gemm_mfma<64, 64, 32, 0, 0>), g, dim3(256), 0, st, A,
                     nullptr, B, nullptr, bias, resid, C, M, N, K, lda, ldb,
                     ldc, sAb, sBb, sCb, epi, alpha, resMod);
}
// zp = [pk | pv]^T @ zc : A-side dual, transpose-staged
static inline void gemm_projA(hipStream_t st, const float* pkA,
                              const float* pvA, const float* Bz, float* C,
                              int K, long long sBb, long long sCb, int batch) {
  dim3 g(512 / 128, 512 / 64, batch);
  hipLaunchKernelGGL((gemm_mfma<64, 64, 32, 1, 1>), g, dim3(256), 0, st, pkA,
                     pvA, Bz, nullptr, nullptr, nullptr, C, 512, DIM_, K, KLIN,
                     DIM_, DIM_, 0, sBb, sCb, 0, 1.f, 0);
}
// kvp = zp @ [wk | wv] : B-side dual
static inline void gemm_kv(hipStream_t st, const float* Azp, const float* wkB,
                           const float* wvB, float* C, long long sAb,
                           long long sCb, int batch) {
  dim3 g(512 / 128, 512 / 64, batch);
  hipLaunchKernelGGL((gemm_mfma<64, 64, 32, 0, 2>), g, dim3(256), 0, st, Azp,
                     nullptr, wkB, wvB, nullptr, nullptr, C, 512, DIM_, DIM_,
                     DIM_, DIM_, DIM_, sAb, 0, sCb, 0, 1.f, 0);
}

extern "C" void kernel_launch(void* const* d_in, const int* in_sizes, int n_in,
                              void* d_out, int out_size, void* d_ws,
                              size_t ws_size, hipStream_t stream) {
  const float* x     = (const float*)d_in[0];
  const float* emb_w = (const float*)d_in[1];
  const float* emb_b = (const float*)d_in[2];
  const float* pos   = (const float*)d_in[3];
  const float* ln1_s = (const float*)d_in[4];
  const float* ln1_b = (const float*)d_in[5];
  const float* wq    = (const float*)d_in[6];
  const float* wk    = (const float*)d_in[7];
  const float* wv    = (const float*)d_in[8];
  const float* pk    = (const float*)d_in[9];
  const float* pv    = (const float*)d_in[10];
  const float* wo    = (const float*)d_in[11];
  const float* wo_b  = (const float*)d_in[12];
  const float* ln2_s = (const float*)d_in[13];
  const float* ln2_b = (const float*)d_in[14];
  const float* w1    = (const float*)d_in[15];
  const float* b1    = (const float*)d_in[16];
  const float* w2    = (const float*)d_in[17];
  const float* b2    = (const float*)d_in[18];
  const float* fc_w  = (const float*)d_in[19];
  const float* fc_b  = (const float*)d_in[20];
  float* out = (float*)d_out;

  // ---- workspace: h slab (64MB) + arena (<=50MB used) + tiny ----
  const long long SZ  = (long long)B_ * N_ * DIM_;
  const long long CHW = (long long)CB * N_ * DIM_;
  const long long KVW = (long long)2 * KLIN * DIM_;  // 262144 per batch
  float* wsf  = (float*)d_ws;
  float* h     = wsf;
  float* arena = wsf + SZ;
  float* zc  = arena;                 // attn: CHW | ffn: FROWS*DIM
  float* qc  = arena + CHW;           // attn: CHW | ffn: ffnmid FROWS*4*DIM
  float* zp  = arena + 2 * CHW;       // [CB, 2*KLIN, DIM] ~1.05M floats
  float* kvp = zp + CB * KVW;         // [CB, 2*KLIN, DIM]
  float* pooled = kvp + CB * KVW;

  const int M = B_ * N_;
  const float scale = 0.125f;

  // embedding: h = x@emb_w + emb_b + pos (pos broadcast over batch)
  gemm128(stream, x, emb_w, emb_b, pos, h, M, DIM_, INDIM, INDIM, DIM_, DIM_,
          0, 0, 0, 2, 1.f, N_, 1);

  for (int i = 0; i < DEPTH; ++i) {
    const float* wq_i = wq + (long long)i * DIM_ * DIM_;
    const float* wk_i = wk + (long long)i * DIM_ * DIM_;
    const float* wv_i = wv + (long long)i * DIM_ * DIM_;
    const float* pk_i = pk + (long long)i * N_ * KLIN;
    const float* pv_i = pv + (long long)i * N_ * KLIN;
    const float* wo_i = wo + (long long)i * DIM_ * DIM_;
    const float* w1_i = w1 + (long long)i * DIM_ * 4 * DIM_;
    const float* w2_i = w2 + (long long)i * 4 * DIM_ * DIM_;

    // ---- attention, chunked over CB=4 batches ----
    for (int c = 0; c < B_ / CB; ++c) {
      float* hc = h + (long long)c * CHW;
      hipLaunchKernelGGL(ln_k, dim3(CHROWS / 4), dim3(256), 0, stream, hc,
                         ln1_s + i * DIM_, ln1_b + i * DIM_, zc);
      // qc = zc @ wq
      gemm128(stream, zc, wq_i, nullptr, nullptr, qc, CHROWS, DIM_, DIM_,
              DIM_, DIM_, DIM_, 0, 0, 0, 0, 1.f, 0, 1);
      // zp[b] = [pk|pv]^T @ zc[b]  (M=512, K=2048)
      gemm_projA(stream, pk_i, pv_i, zc, zp, N_, (long long)N_ * DIM_, KVW, CB);
      // kvp[b] = zp[b] @ [wk|wv]   (rows 0..255 -> kp, 256..511 -> vp)
      gemm_kv(stream, zp, wk_i, wv_i, kvp, KVW, KVW, CB);
      // fused attention: qc <- attn_out (in place)
      hipLaunchKernelGGL(attn_k, dim3(N_ / 64, HEADS, CB), dim3(256), 0,
                         stream, qc, kvp, scale);
      // h_chunk += attn_out @ wo + wo_b
      gemm128(stream, qc, wo_i, wo_b + i * DIM_, hc, hc, CHROWS, DIM_, DIM_,
              DIM_, DIM_, DIM_, 0, 0, 0, 2, 1.f, 0, 1);
    }

    // ---- FFN, chunked over FROWS rows ----
    for (int r0 = 0; r0 < M; r0 += FROWS) {
      float* hr = h + (long long)r0 * DIM_;
      hipLaunchKernelGGL(ln_k, dim3(FROWS / 4), dim3(256), 0, stream, hr,
                         ln2_s + i * DIM_, ln2_b + i * DIM_, zc);
      // ffnmid (qc) = gelu(zc @ w1 + b1): [FROWS, 2048]
      gemm128(stream, zc, w1_i, b1 + (long long)i * 4 * DIM_, nullptr, qc,
              FROWS, 4 * DIM_, DIM_, DIM_, 4 * DIM_, 4 * DIM_, 0, 0, 0, 3,
              1.f, 0, 1);
      // h_chunk += ffnmid @ w2 + b2  (64-row tiles -> 256 blocks)
      gemm64(stream, qc, w2_i, b2 + (long long)i * DIM_, hr, hr, FROWS, DIM_,
             4 * DIM_, 4 * DIM_, DIM_, DIM_, 0, 0, 0, 2, 1.f, 0, 1);
    }
  }

  hipLaunchKernelGGL(pool_k, dim3(DIM_ / 64, B_), dim3(256), 0, stream, h,
                     pooled);
  hipLaunchKernelGGL(fc_k, dim3(1), dim3(64), 0, stream, pooled, fc_w, fc_b,
                     out);
}

// Round 6
// 4161.621 us; speedup vs baseline: 5.1109x; 1.7648x over previous
//
#include <hip/hip_runtime.h>
#include <math.h>

// ---------------- constants ----------------
#define B_    16
#define N_    2048
#define INDIM 64
#define DIM_  512
#define HEADS 8
#define DEPTH 4
#define KLIN  256
#define NCLS  2
#define DH    64
#define EPSF  1e-5f
#define ACB   8                    // batches per attention chunk
#define ACROWS (ACB * N_)          // 16384 rows
#define FROWS 8192                 // rows per FFN chunk

typedef __attribute__((ext_vector_type(8))) short short8v;
typedef __attribute__((ext_vector_type(4))) short short4v;
typedef __attribute__((ext_vector_type(4))) float f32x4;

// fp32 -> bf16 round-to-nearest-even (finite inputs)
__device__ __forceinline__ short f2bf(float f) {
  unsigned u = __float_as_uint(f);
  u += 0x7FFFu + ((u >> 16) & 1u);
  return (short)(u >> 16);
}

__device__ __forceinline__ float wave_sum(float v) {
  #pragma unroll
  for (int o = 32; o > 0; o >>= 1) v += __shfl_xor(v, o);
  return v;
}

__device__ __forceinline__ float gelu_tanh(float x) {
  float x3 = x * x * x;
  float t = tanhf(0.7978845608028654f * (x + 0.044715f * x3));
  return 0.5f * x * (1.f + t);
}

// ---------------- converts (once per launch) ----------------
// transpose-convert: src fp32 [R][C] -> dst bf16 [C][R], batched over z
__global__ __launch_bounds__(256) void tconv_k(const float* __restrict__ src,
                                               short* __restrict__ dst, int R,
                                               int C, long long sSrc,
                                               long long sDst) {
  __shared__ float tile[32][33];
  int c0 = blockIdx.x * 32, r0 = blockIdx.y * 32;
  src += (long long)blockIdx.z * sSrc;
  dst += (long long)blockIdx.z * sDst;
  int tx = threadIdx.x & 31, ty = threadIdx.x >> 5;
  #pragma unroll
  for (int rr = 0; rr < 4; ++rr)
    tile[ty + rr * 8][tx] = src[(long long)(r0 + ty + rr * 8) * C + c0 + tx];
  __syncthreads();
  #pragma unroll
  for (int rr = 0; rr < 4; ++rr) {
    int c = ty + rr * 8;
    dst[(long long)(c0 + c) * R + r0 + tx] = f2bf(tile[tx][c]);
  }
}

// straight copy-convert fp32 -> bf16, n8 = elements/8
__global__ __launch_bounds__(256) void cconv_k(const float* __restrict__ src,
                                               short* __restrict__ dst,
                                               int n8) {
  int i = blockIdx.x * 256 + threadIdx.x;
  if (i < n8) {
    const float* s = src + (long long)i * 8;
    float4 a = *(const float4*)s, c = *(const float4*)(s + 4);
    short8v o = {f2bf(a.x), f2bf(a.y), f2bf(a.z), f2bf(a.w),
                 f2bf(c.x), f2bf(c.y), f2bf(c.z), f2bf(c.w)};
    *(short8v*)(dst + (long long)i * 8) = o;
  }
}

// ---------------- LayerNorm: fp32 in, bf16 out ----------------
__global__ __launch_bounds__(256) void ln_k(const float* __restrict__ h,
                                            const float* __restrict__ s,
                                            const float* __restrict__ b,
                                            short* __restrict__ z) {
  int lane = threadIdx.x & 63;
  long long row = ((long long)blockIdx.x << 2) + (threadIdx.x >> 6);
  const float* hr = h + row * DIM_ + lane * 8;
  float4 a = *(const float4*)hr;
  float4 c = *(const float4*)(hr + 4);
  float sum = a.x + a.y + a.z + a.w + c.x + c.y + c.z + c.w;
  sum = wave_sum(sum);
  float mu = sum * (1.f / DIM_);
  float d[8] = {a.x - mu, a.y - mu, a.z - mu, a.w - mu,
                c.x - mu, c.y - mu, c.z - mu, c.w - mu};
  float vs = 0.f;
  #pragma unroll
  for (int i = 0; i < 8; ++i) vs += d[i] * d[i];
  vs = wave_sum(vs);
  float rstd = rsqrtf(vs * (1.f / DIM_) + EPSF);
  const float* sp = s + lane * 8;
  const float* bp = b + lane * 8;
  float4 s0 = *(const float4*)sp, s1 = *(const float4*)(sp + 4);
  float4 b0 = *(const float4*)bp, b1 = *(const float4*)(bp + 4);
  float o[8];
  o[0] = d[0] * rstd * s0.x + b0.x; o[1] = d[1] * rstd * s0.y + b0.y;
  o[2] = d[2] * rstd * s0.z + b0.z; o[3] = d[3] * rstd * s0.w + b0.w;
  o[4] = d[4] * rstd * s1.x + b1.x; o[5] = d[5] * rstd * s1.y + b1.y;
  o[6] = d[6] * rstd * s1.z + b1.z; o[7] = d[7] * rstd * s1.w + b1.w;
  short8v ov = {f2bf(o[0]), f2bf(o[1]), f2bf(o[2]), f2bf(o[3]),
                f2bf(o[4]), f2bf(o[5]), f2bf(o[6]), f2bf(o[7])};
  *(short8v*)(z + row * DIM_ + lane * 8) = ov;
}

// ---------------- bf16 MFMA GEMM, 128x128 tile, BK=64 ----------------
// C[m,n] = sum_k A[m][k] * Bt[n][k] (+ epilogue)
// A: bf16 [M][lda] k-major. Bt (BTRANS=0): bf16 [N][ldb] k-major.
// Bt (BTRANS=1): bf16 [K][ldb] n-major (transpose-staged).
// OUTBF: 1 -> write bf16, 0 -> fp32.
// epi: 0 none; 1 +bias; 2 +bias+resid[(m%resMod)*ldc+n] (fp32); 3 gelu(+bias)
// dual: if dualThresh && bm >= dualThresh, Bt += dualOff
template <int OUTBF, int BTRANS>
__global__ __launch_bounds__(256) void gemm_bf(
    const short* __restrict__ A, const short* __restrict__ Bsrc,
    const float* __restrict__ bias, const float* __restrict__ resid,
    void* __restrict__ Cv, int M, int N, int K, int lda, int ldb, int ldc,
    long long sAb, long long sBb, long long sCb, int dualThresh,
    long long dualOff, int epi, int resMod) {
  int zz = blockIdx.z;
  A += (long long)zz * sAb;
  Bsrc += (long long)zz * sBb;
  int bm = blockIdx.y * 128, bn = blockIdx.x * 128;
  if (dualThresh && bm >= dualThresh) Bsrc += dualOff;
  int t = threadIdx.x;
  __shared__ __align__(16) short Alds[128][64];
  __shared__ __align__(16) short Blds[128][64];
  int lane = t & 63, wid = t >> 6;
  int lr = lane & 15, q = lane >> 4;
  int wm = (wid >> 1) * 64, wn = (wid & 1) * 64;
  f32x4 acc[4][4] = {};

  for (int k0 = 0; k0 < K; k0 += 64) {
    #pragma unroll
    for (int rep = 0; rep < 4; ++rep) {
      int L = rep * 256 + t;
      int row = L >> 3, c8 = (L & 7) << 3;
      *(short8v*)&Alds[row][c8] =
          *(const short8v*)(A + (long long)(bm + row) * lda + k0 + c8);
    }
    if (BTRANS == 0) {
      #pragma unroll
      for (int rep = 0; rep < 4; ++rep) {
        int L = rep * 256 + t;
        int row = L >> 3, c8 = (L & 7) << 3;
        *(short8v*)&Blds[row][c8] =
            *(const short8v*)(Bsrc + (long long)(bn + row) * ldb + k0 + c8);
      }
    } else {
      #pragma unroll
      for (int rep = 0; rep < 4; ++rep) {
        int L = rep * 256 + t;
        int kk = L >> 4, n8 = (L & 15) << 3;
        short8v v =
            *(const short8v*)(Bsrc + (long long)(k0 + kk) * ldb + bn + n8);
        #pragma unroll
        for (int j = 0; j < 8; ++j) Blds[n8 + j][kk] = v[j];
      }
    }
    __syncthreads();
    #pragma unroll
    for (int kk2 = 0; kk2 < 2; ++kk2) {
      short8v af[4], bfr[4];
      #pragma unroll
      for (int mi = 0; mi < 4; ++mi)
        af[mi] = *(const short8v*)&Alds[wm + mi * 16 + lr][kk2 * 32 + q * 8];
      #pragma unroll
      for (int ni = 0; ni < 4; ++ni)
        bfr[ni] = *(const short8v*)&Blds[wn + ni * 16 + lr][kk2 * 32 + q * 8];
      #pragma unroll
      for (int mi = 0; mi < 4; ++mi)
        #pragma unroll
        for (int ni = 0; ni < 4; ++ni)
          acc[mi][ni] = __builtin_amdgcn_mfma_f32_16x16x32_bf16(
              af[mi], bfr[ni], acc[mi][ni], 0, 0, 0);
    }
    __syncthreads();
  }

  #pragma unroll
  for (int ni = 0; ni < 4; ++ni) {
    int col = bn + wn + ni * 16 + lr;
    float bval = (epi >= 1) ? bias[col] : 0.f;
    #pragma unroll
    for (int mi = 0; mi < 4; ++mi) {
      #pragma unroll
      for (int r = 0; r < 4; ++r) {
        int m = bm + wm + mi * 16 + q * 4 + r;
        float val = acc[mi][ni][r];
        if (epi == 1) {
          val += bval;
        } else if (epi == 2) {
          int rm = resMod ? (m % resMod) : m;
          val += bval + resid[(long long)rm * ldc + col];
        } else if (epi == 3) {
          val = gelu_tanh(val + bval);
        }
        long long idx = (long long)zz * sCb + (long long)m * ldc + col;
        if (OUTBF)
          ((short*)Cv)[idx] = f2bf(val);
        else
          ((float*)Cv)[idx] = val;
      }
    }
  }
}

// ---------------- fused Linformer attention, bf16 MFMA ----------------
// grid (N/64, HEADS, batch). qc bf16 in-place. kvp bf16 [b][2*KLIN][DIM]
// (rows 0..255 kp, 256..511 vp). Scale applied to fp32 S post-MFMA.
__global__ __launch_bounds__(256) void attn_k(short* __restrict__ qc,
                                              const short* __restrict__ kvp,
                                              float scale) {
  int n0 = blockIdx.x * 64, hh = blockIdx.y, b = blockIdx.z;
  int t = threadIdx.x;
  int lane = t & 63, w = t >> 6;
  int lr = lane & 15, qd = lane >> 4;

  __shared__ __align__(16) short Qlds[64][72];
  __shared__ __align__(16) short Kbuf[256 * 72];  // K, then aliased as P
  __shared__ __align__(16) short Vt[64][264];
  auto Klds = (short(*)[72])Kbuf;
  auto Plds = (short(*)[264])Kbuf;

  short* qptr = qc + (long long)b * N_ * DIM_ + hh * DH;
  const short* kptr = kvp + (long long)b * 2 * KLIN * DIM_ + hh * DH;
  const short* vptr = kptr + (long long)KLIN * DIM_;

  #pragma unroll
  for (int rep = 0; rep < 2; ++rep) {
    int L = rep * 256 + t, row = L >> 3, c8 = (L & 7) << 3;
    *(short8v*)&Qlds[row][c8] =
        *(const short8v*)(qptr + (long long)(n0 + row) * DIM_ + c8);
  }
  #pragma unroll
  for (int rep = 0; rep < 8; ++rep) {
    int L = rep * 256 + t, row = L >> 3, c8 = (L & 7) << 3;
    *(short8v*)&Klds[row][c8] =
        *(const short8v*)(kptr + (long long)row * DIM_ + c8);
  }
  #pragma unroll
  for (int rep = 0; rep < 4; ++rep) {
    int key0 = rep * 64 + (t >> 4) * 4, dh0 = (t & 15) * 4;
    short4v a0 = *(const short4v*)(vptr + (long long)(key0 + 0) * DIM_ + dh0);
    short4v a1 = *(const short4v*)(vptr + (long long)(key0 + 1) * DIM_ + dh0);
    short4v a2 = *(const short4v*)(vptr + (long long)(key0 + 2) * DIM_ + dh0);
    short4v a3 = *(const short4v*)(vptr + (long long)(key0 + 3) * DIM_ + dh0);
    short4v w0 = {a0[0], a1[0], a2[0], a3[0]};
    short4v w1 = {a0[1], a1[1], a2[1], a3[1]};
    short4v w2 = {a0[2], a1[2], a2[2], a3[2]};
    short4v w3 = {a0[3], a1[3], a2[3], a3[3]};
    *(short4v*)&Vt[dh0 + 0][key0] = w0;
    *(short4v*)&Vt[dh0 + 1][key0] = w1;
    *(short4v*)&Vt[dh0 + 2][key0] = w2;
    *(short4v*)&Vt[dh0 + 3][key0] = w3;
  }
  __syncthreads();

  short8v qa0 = *(const short8v*)&Qlds[16 * w + lr][qd * 8];
  short8v qa1 = *(const short8v*)&Qlds[16 * w + lr][32 + qd * 8];
  f32x4 sacc[16];
  #pragma unroll
  for (int nt = 0; nt < 16; ++nt) {
    short8v b0 = *(const short8v*)&Klds[nt * 16 + lr][qd * 8];
    short8v b1 = *(const short8v*)&Klds[nt * 16 + lr][32 + qd * 8];
    f32x4 acc = {};
    acc = __builtin_amdgcn_mfma_f32_16x16x32_bf16(qa0, b0, acc, 0, 0, 0);
    acc = __builtin_amdgcn_mfma_f32_16x16x32_bf16(qa1, b1, acc, 0, 0, 0);
    sacc[nt] = acc;
  }

  float l[4];
  #pragma unroll
  for (int r = 0; r < 4; ++r) {
    float m = -1e30f;
    #pragma unroll
    for (int nt = 0; nt < 16; ++nt) {
      sacc[nt][r] *= scale;
      m = fmaxf(m, sacc[nt][r]);
    }
    #pragma unroll
    for (int o = 1; o < 16; o <<= 1) m = fmaxf(m, __shfl_xor(m, o));
    float rs = 0.f;
    #pragma unroll
    for (int nt = 0; nt < 16; ++nt) {
      float e = __expf(sacc[nt][r] - m);
      sacc[nt][r] = e;
      rs += e;
    }
    #pragma unroll
    for (int o = 1; o < 16; o <<= 1) rs += __shfl_xor(rs, o);
    l[r] = rs;
  }

  __syncthreads();  // Klds reads done; reuse as Plds
  #pragma unroll
  for (int nt = 0; nt < 16; ++nt)
    #pragma unroll
    for (int r = 0; r < 4; ++r)
      Plds[16 * w + qd * 4 + r][nt * 16 + lr] = f2bf(sacc[nt][r]);
  __syncthreads();

  f32x4 out[4] = {};
  #pragma unroll
  for (int k0 = 0; k0 < 8; ++k0) {
    short8v ap = *(const short8v*)&Plds[16 * w + lr][k0 * 32 + qd * 8];
    #pragma unroll
    for (int n2 = 0; n2 < 4; ++n2) {
      short8v bv = *(const short8v*)&Vt[n2 * 16 + lr][k0 * 32 + qd * 8];
      out[n2] =
          __builtin_amdgcn_mfma_f32_16x16x32_bf16(ap, bv, out[n2], 0, 0, 0);
    }
  }

  #pragma unroll
  for (int r = 0; r < 4; ++r) {
    float inv = 1.f / l[r];
    long long rowoff = (long long)(n0 + 16 * w + qd * 4 + r) * DIM_;
    #pragma unroll
    for (int n2 = 0; n2 < 4; ++n2)
      qptr[rowoff + n2 * 16 + lr] = f2bf(out[n2][r] * inv);
  }
}

// ---------------- two-stage mean pool ----------------
__global__ __launch_bounds__(256) void pool1_k(const float* __restrict__ h,
                                               float* __restrict__ partial) {
  int stripe = blockIdx.x, b = blockIdx.y;
  int c4 = (threadIdx.x & 127) * 4, half = threadIdx.x >> 7;
  const float* base =
      h + ((long long)b * N_ + stripe * 128 + half * 64) * DIM_ + c4;
  float4 acc = {0.f, 0.f, 0.f, 0.f};
  for (int r = 0; r < 64; ++r) {
    float4 v = *(const float4*)(base + (long long)r * DIM_);
    acc.x += v.x; acc.y += v.y; acc.z += v.z; acc.w += v.w;
  }
  __shared__ float red[512];
  if (half == 1) *(float4*)&red[c4] = acc;
  __syncthreads();
  if (half == 0) {
    float4 o = *(const float4*)&red[c4];
    o.x += acc.x; o.y += acc.y; o.z += acc.z; o.w += acc.w;
    *(float4*)&partial[((long long)b * 16 + stripe) * DIM_ + c4] = o;
  }
}
__global__ __launch_bounds__(256) void pool2_k(const float* __restrict__ partial,
                                               float* __restrict__ pooled) {
  int b = blockIdx.x;
  for (int c = threadIdx.x; c < DIM_; c += 256) {
    float s = 0.f;
    for (int k = 0; k < 16; ++k) s += partial[((long long)b * 16 + k) * DIM_ + c];
    pooled[b * DIM_ + c] = s * (1.f / N_);
  }
}

// ---------------- final FC [16,512]@[512,2] ----------------
__global__ __launch_bounds__(64) void fc_k(const float* __restrict__ pooled,
                                           const float* __restrict__ fc_w,
                                           const float* __restrict__ fc_b,
                                           float* __restrict__ out) {
  int t = threadIdx.x;
  if (t < B_ * NCLS) {
    int b = t >> 1, c = t & 1;
    float s = fc_b[c];
    for (int d = 0; d < DIM_; ++d)
      s += pooled[b * DIM_ + d] * fc_w[d * NCLS + c];
    out[t] = s;
  }
}

extern "C" void kernel_launch(void* const* d_in, const int* in_sizes, int n_in,
                              void* d_out, int out_size, void* d_ws,
                              size_t ws_size, hipStream_t stream) {
  const float* x     = (const float*)d_in[0];
  const float* emb_w = (const float*)d_in[1];
  const float* emb_b = (const float*)d_in[2];
  const float* pos   = (const float*)d_in[3];
  const float* ln1_s = (const float*)d_in[4];
  const float* ln1_b = (const float*)d_in[5];
  const float* wq    = (const float*)d_in[6];
  const float* wk    = (const float*)d_in[7];
  const float* wv    = (const float*)d_in[8];
  const float* pk    = (const float*)d_in[9];
  const float* pv    = (const float*)d_in[10];
  const float* wo    = (const float*)d_in[11];
  const float* wo_b  = (const float*)d_in[12];
  const float* ln2_s = (const float*)d_in[13];
  const float* ln2_b = (const float*)d_in[14];
  const float* w1    = (const float*)d_in[15];
  const float* b1    = (const float*)d_in[16];
  const float* w2    = (const float*)d_in[17];
  const float* b2    = (const float*)d_in[18];
  const float* fc_w  = (const float*)d_in[19];
  const float* fc_b  = (const float*)d_in[20];
  float* out = (float*)d_out;

  // ---- workspace (~148 MB) ----
  char* P = (char*)d_ws;
  float* h = (float*)P;            P += (long long)B_ * N_ * DIM_ * 4;   // 67MB
  short* zc = (short*)P;                                                 // arena
  short* qc = zc + (long long)ACROWS * DIM_;
  short* ffnmid = zc;              P += (long long)2 * ACROWS * DIM_ * 2; // 33.5MB
  short* zp = (short*)P;                                                 // R1
  short* kvp = zp + (long long)ACB * 2 * KLIN * DIM_;
  short* zln = zp;                 P += (long long)2 * ACB * 2 * KLIN * DIM_ * 2; // 8.4MB
  short* wq_t  = (short*)P;  P += (long long)DEPTH * DIM_ * DIM_ * 2;
  short* wkv_t = (short*)P;  P += (long long)DEPTH * 2 * DIM_ * DIM_ * 2;
  short* wo_t  = (short*)P;  P += (long long)DEPTH * DIM_ * DIM_ * 2;
  short* w1_t  = (short*)P;  P += (long long)DEPTH * 4 * DIM_ * DIM_ * 2;
  short* w2_t  = (short*)P;  P += (long long)DEPTH * 4 * DIM_ * DIM_ * 2;
  short* pkv_t = (short*)P;  P += (long long)DEPTH * 2 * KLIN * N_ * 2;
  short* emb_wt = (short*)P; P += (long long)DIM_ * INDIM * 2;
  short* x_bf  = (short*)P;  P += (long long)B_ * N_ * INDIM * 2;
  float* partial = (float*)P; P += (long long)B_ * 16 * DIM_ * 4;
  float* pooled  = (float*)P;

  const float scale = 0.125f;
  const long long WQS = (long long)DIM_ * DIM_;        // 262144
  const long long KVS = (long long)2 * KLIN * DIM_;    // 262144

  // ---- converts ----
  auto tconv = [&](const float* s, short* d, int R, int C, long long ss,
                   long long sd, int b) {
    hipLaunchKernelGGL(tconv_k, dim3(C / 32, R / 32, b), dim3(256), 0, stream,
                       s, d, R, C, ss, sd);
  };
  tconv(wq, wq_t, DIM_, DIM_, WQS, WQS, DEPTH);
  tconv(wk, wkv_t, DIM_, DIM_, WQS, 2 * WQS, DEPTH);
  tconv(wv, wkv_t + WQS, DIM_, DIM_, WQS, 2 * WQS, DEPTH);
  tconv(wo, wo_t, DIM_, DIM_, WQS, WQS, DEPTH);
  tconv(w1, w1_t, DIM_, 4 * DIM_, 4 * WQS, 4 * WQS, DEPTH);
  tconv(w2, w2_t, 4 * DIM_, DIM_, 4 * WQS, 4 * WQS, DEPTH);
  tconv(pk, pkv_t, N_, KLIN, (long long)N_ * KLIN, (long long)2 * KLIN * N_, DEPTH);
  tconv(pv, pkv_t + (long long)KLIN * N_, N_, KLIN, (long long)N_ * KLIN,
        (long long)2 * KLIN * N_, DEPTH);
  tconv(emb_w, emb_wt, INDIM, DIM_, 0, 0, 1);
  hipLaunchKernelGGL(cconv_k, dim3((B_ * N_ * INDIM / 8 + 255) / 256),
                     dim3(256), 0, stream, x, x_bf, B_ * N_ * INDIM / 8);

  // ---- embedding: h = x@emb_w + emb_b + pos ----
  hipLaunchKernelGGL((gemm_bf<0, 0>), dim3(DIM_ / 128, B_ * N_ / 128, 1),
                     dim3(256), 0, stream, x_bf, emb_wt, emb_b, pos, (void*)h,
                     B_ * N_, DIM_, INDIM, INDIM, INDIM, DIM_, 0LL, 0LL, 0LL,
                     0, 0LL, 2, N_);

  for (int i = 0; i < DEPTH; ++i) {
    const short* wq_i  = wq_t + i * WQS;
    const short* wkv_i = wkv_t + i * 2 * WQS;
    const short* wo_i  = wo_t + i * WQS;
    const short* w1_i  = w1_t + (long long)i * 4 * WQS;
    const short* w2_i  = w2_t + (long long)i * 4 * WQS;
    const short* pkv_i = pkv_t + (long long)i * 2 * KLIN * N_;

    // ---- attention, 2 chunks of 8 batches ----
    for (int c = 0; c < B_ / ACB; ++c) {
      float* hc = h + (long long)c * ACROWS * DIM_;
      hipLaunchKernelGGL(ln_k, dim3(ACROWS / 4), dim3(256), 0, stream, hc,
                         ln1_s + i * DIM_, ln1_b + i * DIM_, zc);
      // qc = zc @ wq
      hipLaunchKernelGGL((gemm_bf<1, 0>), dim3(DIM_ / 128, ACROWS / 128, 1),
                         dim3(256), 0, stream, zc, wq_i, nullptr, nullptr,
                         (void*)qc, ACROWS, DIM_, DIM_, DIM_, DIM_, DIM_, 0LL,
                         0LL, 0LL, 0, 0LL, 0, 0);
      // zp[b] = pkv^T @ zc[b]  (BTRANS on zc)
      hipLaunchKernelGGL((gemm_bf<1, 1>), dim3(DIM_ / 128, 512 / 128, ACB),
                         dim3(256), 0, stream, pkv_i, zc, nullptr, nullptr,
                         (void*)zp, 512, DIM_, N_, N_, DIM_, DIM_, 0LL,
                         (long long)N_ * DIM_, KVS, 0, 0LL, 0, 0);
      // kvp[b] = zp[b] @ [wk | wv]  (B dual by output row)
      hipLaunchKernelGGL((gemm_bf<1, 0>), dim3(DIM_ / 128, 512 / 128, ACB),
                         dim3(256), 0, stream, zp, wkv_i, nullptr, nullptr,
                         (void*)kvp, 512, DIM_, DIM_, DIM_, DIM_, DIM_, KVS,
                         0LL, KVS, KLIN, (long long)WQS, 0, 0);
      // fused attention in-place on qc
      hipLaunchKernelGGL(attn_k, dim3(N_ / 64, HEADS, ACB), dim3(256), 0,
                         stream, qc, kvp, scale);
      // h += qc @ wo + wo_b
      hipLaunchKernelGGL((gemm_bf<0, 0>), dim3(DIM_ / 128, ACROWS / 128, 1),
                         dim3(256), 0, stream, qc, wo_i, wo_b + i * DIM_,
                         hc, (void*)hc, ACROWS, DIM_, DIM_, DIM_, DIM_, DIM_,
                         0LL, 0LL, 0LL, 0, 0LL, 2, 0);
    }

    // ---- FFN, 4 chunks of 8192 rows ----
    for (int r0 = 0; r0 < B_ * N_; r0 += FROWS) {
      float* hr = h + (long long)r0 * DIM_;
      hipLaunchKernelGGL(ln_k, dim3(FROWS / 4), dim3(256), 0, stream, hr,
                         ln2_s + i * DIM_, ln2_b + i * DIM_, zln);
      // ffnmid = gelu(zln @ w1 + b1)
      hipLaunchKernelGGL((gemm_bf<1, 0>), dim3(4 * DIM_ / 128, FROWS / 128, 1),
                         dim3(256), 0, stream, zln, w1_i,
                         b1 + (long long)i * 4 * DIM_, nullptr, (void*)ffnmid,
                         FROWS, 4 * DIM_, DIM_, DIM_, DIM_, 4 * DIM_, 0LL, 0LL,
                         0LL, 0, 0LL, 3, 0);
      // h += ffnmid @ w2 + b2
      hipLaunchKernelGGL((gemm_bf<0, 0>), dim3(DIM_ / 128, FROWS / 128, 1),
                         dim3(256), 0, stream, ffnmid, w2_i,
                         b2 + (long long)i * DIM_, hr, (void*)hr, FROWS, DIM_,
                         4 * DIM_, 4 * DIM_, 4 * DIM_, DIM_, 0LL, 0LL, 0LL, 0,
                         0LL, 2, 0);
    }
  }

  hipLaunchKernelGGL(pool1_k, dim3(16, B_), dim3(256), 0, stream, h, partial);
  hipLaunchKernelGGL(pool2_k, dim3(B_), dim3(256), 0, stream, partial, pooled);
  hipLaunchKernelGGL(fc_k, dim3(1), dim3(64), 0, stream, pooled, fc_w, fc_b,
                     out);
}

// Round 7
// 3341.061 us; speedup vs baseline: 6.3661x; 1.2456x over previous
//
#include <hip/hip_runtime.h>
#include <math.h>

// ---------------- constants ----------------
#define B_    16
#define N_    2048
#define INDIM 64
#define DIM_  512
#define HEADS 8
#define DEPTH 4
#define KLIN  256
#define NCLS  2
#define DH    64
#define EPSF  1e-5f
#define ACB   8                    // batches per attention chunk
#define ACROWS (ACB * N_)          // 16384 rows
#define FROWS 8192                 // rows per FFN chunk

typedef __attribute__((ext_vector_type(8))) short short8v;
typedef __attribute__((ext_vector_type(4))) short short4v;
typedef __attribute__((ext_vector_type(4))) float f32x4;

// fp32 -> bf16 round-to-nearest-even (finite inputs)
__device__ __forceinline__ short f2bf(float f) {
  unsigned u = __float_as_uint(f);
  u += 0x7FFFu + ((u >> 16) & 1u);
  return (short)(u >> 16);
}

__device__ __forceinline__ float wave_sum(float v) {
  #pragma unroll
  for (int o = 32; o > 0; o >>= 1) v += __shfl_xor(v, o);
  return v;
}

__device__ __forceinline__ float gelu_tanh(float x) {
  float x3 = x * x * x;
  float t = tanhf(0.7978845608028654f * (x + 0.044715f * x3));
  return 0.5f * x * (1.f + t);
}

// ---------------- converts (once per launch) ----------------
// transpose-convert: src fp32 [R][C] -> dst bf16 [C][R], batched over z
__global__ __launch_bounds__(256) void tconv_k(const float* __restrict__ src,
                                               short* __restrict__ dst, int R,
                                               int C, long long sSrc,
                                               long long sDst) {
  __shared__ float tile[32][33];
  int c0 = blockIdx.x * 32, r0 = blockIdx.y * 32;
  src += (long long)blockIdx.z * sSrc;
  dst += (long long)blockIdx.z * sDst;
  int tx = threadIdx.x & 31, ty = threadIdx.x >> 5;
  #pragma unroll
  for (int rr = 0; rr < 4; ++rr)
    tile[ty + rr * 8][tx] = src[(long long)(r0 + ty + rr * 8) * C + c0 + tx];
  __syncthreads();
  #pragma unroll
  for (int rr = 0; rr < 4; ++rr) {
    int c = ty + rr * 8;
    dst[(long long)(c0 + c) * R + r0 + tx] = f2bf(tile[tx][c]);
  }
}

// straight copy-convert fp32 -> bf16, n8 = elements/8
__global__ __launch_bounds__(256) void cconv_k(const float* __restrict__ src,
                                               short* __restrict__ dst,
                                               int n8) {
  int i = blockIdx.x * 256 + threadIdx.x;
  if (i < n8) {
    const float* s = src + (long long)i * 8;
    float4 a = *(const float4*)s, c = *(const float4*)(s + 4);
    short8v o = {f2bf(a.x), f2bf(a.y), f2bf(a.z), f2bf(a.w),
                 f2bf(c.x), f2bf(c.y), f2bf(c.z), f2bf(c.w)};
    *(short8v*)(dst + (long long)i * 8) = o;
  }
}

// ---------------- bf16 tile transpose: [R][C] -> [C][R], batched ----------
__global__ __launch_bounds__(256) void tpose_k(const short* __restrict__ src,
                                               short* __restrict__ dst, int R,
                                               int C, long long sSrc,
                                               long long sDst) {
  __shared__ __align__(16) short tile[64][72];
  int c0 = blockIdx.x * 64, r0 = blockIdx.y * 64;
  src += (long long)blockIdx.z * sSrc;
  dst += (long long)blockIdx.z * sDst;
  int t = threadIdx.x;
  #pragma unroll
  for (int rep = 0; rep < 2; ++rep) {
    int row = rep * 32 + (t >> 3), c8 = (t & 7) * 8;
    *(short8v*)&tile[row][c8] =
        *(const short8v*)(src + (long long)(r0 + row) * C + c0 + c8);
  }
  __syncthreads();
  #pragma unroll
  for (int rep = 0; rep < 2; ++rep) {
    int c = rep * 32 + (t >> 3), r8 = (t & 7) * 8;
    short8v o;
    #pragma unroll
    for (int j = 0; j < 8; ++j) o[j] = tile[r8 + j][c];
    *(short8v*)(dst + (long long)(c0 + c) * R + r0 + r8) = o;
  }
}

// ---------------- LayerNorm: fp32 in, bf16 out ----------------
__global__ __launch_bounds__(256) void ln_k(const float* __restrict__ h,
                                            const float* __restrict__ s,
                                            const float* __restrict__ b,
                                            short* __restrict__ z) {
  int lane = threadIdx.x & 63;
  long long row = ((long long)blockIdx.x << 2) + (threadIdx.x >> 6);
  const float* hr = h + row * DIM_ + lane * 8;
  float4 a = *(const float4*)hr;
  float4 c = *(const float4*)(hr + 4);
  float sum = a.x + a.y + a.z + a.w + c.x + c.y + c.z + c.w;
  sum = wave_sum(sum);
  float mu = sum * (1.f / DIM_);
  float d[8] = {a.x - mu, a.y - mu, a.z - mu, a.w - mu,
                c.x - mu, c.y - mu, c.z - mu, c.w - mu};
  float vs = 0.f;
  #pragma unroll
  for (int i = 0; i < 8; ++i) vs += d[i] * d[i];
  vs = wave_sum(vs);
  float rstd = rsqrtf(vs * (1.f / DIM_) + EPSF);
  const float* sp = s + lane * 8;
  const float* bp = b + lane * 8;
  float4 s0 = *(const float4*)sp, s1 = *(const float4*)(sp + 4);
  float4 b0 = *(const float4*)bp, b1 = *(const float4*)(bp + 4);
  float o[8];
  o[0] = d[0] * rstd * s0.x + b0.x; o[1] = d[1] * rstd * s0.y + b0.y;
  o[2] = d[2] * rstd * s0.z + b0.z; o[3] = d[3] * rstd * s0.w + b0.w;
  o[4] = d[4] * rstd * s1.x + b1.x; o[5] = d[5] * rstd * s1.y + b1.y;
  o[6] = d[6] * rstd * s1.z + b1.z; o[7] = d[7] * rstd * s1.w + b1.w;
  short8v ov = {f2bf(o[0]), f2bf(o[1]), f2bf(o[2]), f2bf(o[3]),
                f2bf(o[4]), f2bf(o[5]), f2bf(o[6]), f2bf(o[7])};
  *(short8v*)(z + row * DIM_ + lane * 8) = ov;
}

// ---------------- bf16 MFMA GEMM, 128x128 tile, BK=64 ----------------
// C[m,n] = sum_k A[m][k] * Bt[n][k] (+ epilogue). Both operands k-major.
// OUTBF: 1 -> write bf16, 0 -> fp32.
// epi: 0 none; 1 +bias; 2 +bias+resid[(m%resMod)*ldc+n] (fp32); 3 gelu(+bias)
// dual: if dualThresh && bm >= dualThresh, Bt += dualOff
template <int OUTBF>
__global__ __launch_bounds__(256) void gemm_bf(
    const short* __restrict__ A, const short* __restrict__ Bsrc,
    const float* __restrict__ bias, const float* __restrict__ resid,
    void* __restrict__ Cv, int M, int N, int K, int lda, int ldb, int ldc,
    long long sAb, long long sBb, long long sCb, int dualThresh,
    long long dualOff, int epi, int resMod) {
  int zz = blockIdx.z;
  A += (long long)zz * sAb;
  Bsrc += (long long)zz * sBb;
  int bm = blockIdx.y * 128, bn = blockIdx.x * 128;
  if (dualThresh && bm >= dualThresh) Bsrc += dualOff;
  int t = threadIdx.x;
  // rows padded to 72 shorts (144B = 36 banks): frag b128 reads 2-way (free),
  // 16B-aligned rows.
  __shared__ __align__(16) short Alds[128][72];
  __shared__ __align__(16) short Blds[128][72];
  int lane = t & 63, wid = t >> 6;
  int lr = lane & 15, q = lane >> 4;
  int wm = (wid >> 1) * 64, wn = (wid & 1) * 64;
  f32x4 acc[4][4] = {};

  for (int k0 = 0; k0 < K; k0 += 64) {
    #pragma unroll
    for (int rep = 0; rep < 4; ++rep) {
      int L = rep * 256 + t;
      int row = L >> 3, c8 = (L & 7) << 3;
      *(short8v*)&Alds[row][c8] =
          *(const short8v*)(A + (long long)(bm + row) * lda + k0 + c8);
      *(short8v*)&Blds[row][c8] =
          *(const short8v*)(Bsrc + (long long)(bn + row) * ldb + k0 + c8);
    }
    __syncthreads();
    #pragma unroll
    for (int kk2 = 0; kk2 < 2; ++kk2) {
      short8v af[4], bfr[4];
      #pragma unroll
      for (int mi = 0; mi < 4; ++mi)
        af[mi] = *(const short8v*)&Alds[wm + mi * 16 + lr][kk2 * 32 + q * 8];
      #pragma unroll
      for (int ni = 0; ni < 4; ++ni)
        bfr[ni] = *(const short8v*)&Blds[wn + ni * 16 + lr][kk2 * 32 + q * 8];
      #pragma unroll
      for (int mi = 0; mi < 4; ++mi)
        #pragma unroll
        for (int ni = 0; ni < 4; ++ni)
          acc[mi][ni] = __builtin_amdgcn_mfma_f32_16x16x32_bf16(
              af[mi], bfr[ni], acc[mi][ni], 0, 0, 0);
    }
    __syncthreads();
  }

  #pragma unroll
  for (int ni = 0; ni < 4; ++ni) {
    int col = bn + wn + ni * 16 + lr;
    float bval = (epi >= 1) ? bias[col] : 0.f;
    #pragma unroll
    for (int mi = 0; mi < 4; ++mi) {
      #pragma unroll
      for (int r = 0; r < 4; ++r) {
        int m = bm + wm + mi * 16 + q * 4 + r;
        float val = acc[mi][ni][r];
        if (epi == 1) {
          val += bval;
        } else if (epi == 2) {
          int rm = resMod ? (m % resMod) : m;
          val += bval + resid[(long long)rm * ldc + col];
        } else if (epi == 3) {
          val = gelu_tanh(val + bval);
        }
        long long idx = (long long)zz * sCb + (long long)m * ldc + col;
        if (OUTBF)
          ((short*)Cv)[idx] = f2bf(val);
        else
          ((float*)Cv)[idx] = val;
      }
    }
  }
}

// ---------------- fused Linformer attention, bf16 MFMA ----------------
__global__ __launch_bounds__(256) void attn_k(short* __restrict__ qc,
                                              const short* __restrict__ kvp,
                                              float scale) {
  int n0 = blockIdx.x * 64, hh = blockIdx.y, b = blockIdx.z;
  int t = threadIdx.x;
  int lane = t & 63, w = t >> 6;
  int lr = lane & 15, qd = lane >> 4;

  __shared__ __align__(16) short Qlds[64][72];
  __shared__ __align__(16) short Kbuf[256 * 72];  // K, then aliased as P
  __shared__ __align__(16) short Vt[64][264];
  auto Klds = (short(*)[72])Kbuf;
  auto Plds = (short(*)[264])Kbuf;

  short* qptr = qc + (long long)b * N_ * DIM_ + hh * DH;
  const short* kptr = kvp + (long long)b * 2 * KLIN * DIM_ + hh * DH;
  const short* vptr = kptr + (long long)KLIN * DIM_;

  #pragma unroll
  for (int rep = 0; rep < 2; ++rep) {
    int L = rep * 256 + t, row = L >> 3, c8 = (L & 7) << 3;
    *(short8v*)&Qlds[row][c8] =
        *(const short8v*)(qptr + (long long)(n0 + row) * DIM_ + c8);
  }
  #pragma unroll
  for (int rep = 0; rep < 8; ++rep) {
    int L = rep * 256 + t, row = L >> 3, c8 = (L & 7) << 3;
    *(short8v*)&Klds[row][c8] =
        *(const short8v*)(kptr + (long long)row * DIM_ + c8);
  }
  #pragma unroll
  for (int rep = 0; rep < 4; ++rep) {
    int key0 = rep * 64 + (t >> 4) * 4, dh0 = (t & 15) * 4;
    short4v a0 = *(const short4v*)(vptr + (long long)(key0 + 0) * DIM_ + dh0);
    short4v a1 = *(const short4v*)(vptr + (long long)(key0 + 1) * DIM_ + dh0);
    short4v a2 = *(const short4v*)(vptr + (long long)(key0 + 2) * DIM_ + dh0);
    short4v a3 = *(const short4v*)(vptr + (long long)(key0 + 3) * DIM_ + dh0);
    short4v w0 = {a0[0], a1[0], a2[0], a3[0]};
    short4v w1 = {a0[1], a1[1], a2[1], a3[1]};
    short4v w2 = {a0[2], a1[2], a2[2], a3[2]};
    short4v w3 = {a0[3], a1[3], a2[3], a3[3]};
    *(short4v*)&Vt[dh0 + 0][key0] = w0;
    *(short4v*)&Vt[dh0 + 1][key0] = w1;
    *(short4v*)&Vt[dh0 + 2][key0] = w2;
    *(short4v*)&Vt[dh0 + 3][key0] = w3;
  }
  __syncthreads();

  short8v qa0 = *(const short8v*)&Qlds[16 * w + lr][qd * 8];
  short8v qa1 = *(const short8v*)&Qlds[16 * w + lr][32 + qd * 8];
  f32x4 sacc[16];
  #pragma unroll
  for (int nt = 0; nt < 16; ++nt) {
    short8v b0 = *(const short8v*)&Klds[nt * 16 + lr][qd * 8];
    short8v b1 = *(const short8v*)&Klds[nt * 16 + lr][32 + qd * 8];
    f32x4 acc = {};
    acc = __builtin_amdgcn_mfma_f32_16x16x32_bf16(qa0, b0, acc, 0, 0, 0);
    acc = __builtin_amdgcn_mfma_f32_16x16x32_bf16(qa1, b1, acc, 0, 0, 0);
    sacc[nt] = acc;
  }

  float l[4];
  #pragma unroll
  for (int r = 0; r < 4; ++r) {
    float m = -1e30f;
    #pragma unroll
    for (int nt = 0; nt < 16; ++nt) {
      sacc[nt][r] *= scale;
      m = fmaxf(m, sacc[nt][r]);
    }
    #pragma unroll
    for (int o = 1; o < 16; o <<= 1) m = fmaxf(m, __shfl_xor(m, o));
    float rs = 0.f;
    #pragma unroll
    for (int nt = 0; nt < 16; ++nt) {
      float e = __expf(sacc[nt][r] - m);
      sacc[nt][r] = e;
      rs += e;
    }
    #pragma unroll
    for (int o = 1; o < 16; o <<= 1) rs += __shfl_xor(rs, o);
    l[r] = rs;
  }

  __syncthreads();  // Klds reads done; reuse as Plds
  #pragma unroll
  for (int nt = 0; nt < 16; ++nt)
    #pragma unroll
    for (int r = 0; r < 4; ++r)
      Plds[16 * w + qd * 4 + r][nt * 16 + lr] = f2bf(sacc[nt][r]);
  __syncthreads();

  f32x4 out[4] = {};
  #pragma unroll
  for (int k0 = 0; k0 < 8; ++k0) {
    short8v ap = *(const short8v*)&Plds[16 * w + lr][k0 * 32 + qd * 8];
    #pragma unroll
    for (int n2 = 0; n2 < 4; ++n2) {
      short8v bv = *(const short8v*)&Vt[n2 * 16 + lr][k0 * 32 + qd * 8];
      out[n2] =
          __builtin_amdgcn_mfma_f32_16x16x32_bf16(ap, bv, out[n2], 0, 0, 0);
    }
  }

  #pragma unroll
  for (int r = 0; r < 4; ++r) {
    float inv = 1.f / l[r];
    long long rowoff = (long long)(n0 + 16 * w + qd * 4 + r) * DIM_;
    #pragma unroll
    for (int n2 = 0; n2 < 4; ++n2)
      qptr[rowoff + n2 * 16 + lr] = f2bf(out[n2][r] * inv);
  }
}

// ---------------- two-stage mean pool ----------------
__global__ __launch_bounds__(256) void pool1_k(const float* __restrict__ h,
                                               float* __restrict__ partial) {
  int stripe = blockIdx.x, b = blockIdx.y;
  int c4 = (threadIdx.x & 127) * 4, half = threadIdx.x >> 7;
  const float* base =
      h + ((long long)b * N_ + stripe * 128 + half * 64) * DIM_ + c4;
  float4 acc = {0.f, 0.f, 0.f, 0.f};
  for (int r = 0; r < 64; ++r) {
    float4 v = *(const float4*)(base + (long long)r * DIM_);
    acc.x += v.x; acc.y += v.y; acc.z += v.z; acc.w += v.w;
  }
  __shared__ float red[512];
  if (half == 1) *(float4*)&red[c4] = acc;
  __syncthreads();
  if (half == 0) {
    float4 o = *(const float4*)&red[c4];
    o.x += acc.x; o.y += acc.y; o.z += acc.z; o.w += acc.w;
    *(float4*)&partial[((long long)b * 16 + stripe) * DIM_ + c4] = o;
  }
}
__global__ __launch_bounds__(256) void pool2_k(const float* __restrict__ partial,
                                               float* __restrict__ pooled) {
  int b = blockIdx.x;
  for (int c = threadIdx.x; c < DIM_; c += 256) {
    float s = 0.f;
    for (int k = 0; k < 16; ++k) s += partial[((long long)b * 16 + k) * DIM_ + c];
    pooled[b * DIM_ + c] = s * (1.f / N_);
  }
}

// ---------------- final FC [16,512]@[512,2] ----------------
__global__ __launch_bounds__(64) void fc_k(const float* __restrict__ pooled,
                                           const float* __restrict__ fc_w,
                                           const float* __restrict__ fc_b,
                                           float* __restrict__ out) {
  int t = threadIdx.x;
  if (t < B_ * NCLS) {
    int b = t >> 1, c = t & 1;
    float s = fc_b[c];
    for (int d = 0; d < DIM_; ++d)
      s += pooled[b * DIM_ + d] * fc_w[d * NCLS + c];
    out[t] = s;
  }
}

extern "C" void kernel_launch(void* const* d_in, const int* in_sizes, int n_in,
                              void* d_out, int out_size, void* d_ws,
                              size_t ws_size, hipStream_t stream) {
  const float* x     = (const float*)d_in[0];
  const float* emb_w = (const float*)d_in[1];
  const float* emb_b = (const float*)d_in[2];
  const float* pos   = (const float*)d_in[3];
  const float* ln1_s = (const float*)d_in[4];
  const float* ln1_b = (const float*)d_in[5];
  const float* wq    = (const float*)d_in[6];
  const float* wk    = (const float*)d_in[7];
  const float* wv    = (const float*)d_in[8];
  const float* pk    = (const float*)d_in[9];
  const float* pv    = (const float*)d_in[10];
  const float* wo    = (const float*)d_in[11];
  const float* wo_b  = (const float*)d_in[12];
  const float* ln2_s = (const float*)d_in[13];
  const float* ln2_b = (const float*)d_in[14];
  const float* w1    = (const float*)d_in[15];
  const float* b1    = (const float*)d_in[16];
  const float* w2    = (const float*)d_in[17];
  const float* b2    = (const float*)d_in[18];
  const float* fc_w  = (const float*)d_in[19];
  const float* fc_b  = (const float*)d_in[20];
  float* out = (float*)d_out;

  // ---- workspace (~165 MB) ----
  char* P = (char*)d_ws;
  float* h = (float*)P;            P += (long long)B_ * N_ * DIM_ * 4;   // 67MB
  short* zc = (short*)P;                                                 // arena
  short* qc = zc + (long long)ACROWS * DIM_;
  short* ffnmid = zc;              P += (long long)2 * ACROWS * DIM_ * 2; // 33.5MB
  short* zcT = (short*)P;          P += (long long)ACB * DIM_ * N_ * 2;   // 16.8MB
  short* zp = (short*)P;
  short* kvp = zp + (long long)ACB * 2 * KLIN * DIM_;
  short* zln = zp;                 P += (long long)2 * ACB * 2 * KLIN * DIM_ * 2; // 8.4MB
  short* wq_t  = (short*)P;  P += (long long)DEPTH * DIM_ * DIM_ * 2;
  short* wkv_t = (short*)P;  P += (long long)DEPTH * 2 * DIM_ * DIM_ * 2;
  short* wo_t  = (short*)P;  P += (long long)DEPTH * DIM_ * DIM_ * 2;
  short* w1_t  = (short*)P;  P += (long long)DEPTH * 4 * DIM_ * DIM_ * 2;
  short* w2_t  = (short*)P;  P += (long long)DEPTH * 4 * DIM_ * DIM_ * 2;
  short* pkv_t = (short*)P;  P += (long long)DEPTH * 2 * KLIN * N_ * 2;
  short* emb_wt = (short*)P; P += (long long)DIM_ * INDIM * 2;
  short* x_bf  = (short*)P;  P += (long long)B_ * N_ * INDIM * 2;
  float* partial = (float*)P; P += (long long)B_ * 16 * DIM_ * 4;
  float* pooled  = (float*)P;

  const float scale = 0.125f;
  const long long WQS = (long long)DIM_ * DIM_;        // 262144
  const long long KVS = (long long)2 * KLIN * DIM_;    // 262144

  // ---- converts ----
  auto tconv = [&](const float* s, short* d, int R, int C, long long ss,
                   long long sd, int b) {
    hipLaunchKernelGGL(tconv_k, dim3(C / 32, R / 32, b), dim3(256), 0, stream,
                       s, d, R, C, ss, sd);
  };
  tconv(wq, wq_t, DIM_, DIM_, WQS, WQS, DEPTH);
  tconv(wk, wkv_t, DIM_, DIM_, WQS, 2 * WQS, DEPTH);
  tconv(wv, wkv_t + WQS, DIM_, DIM_, WQS, 2 * WQS, DEPTH);
  tconv(wo, wo_t, DIM_, DIM_, WQS, WQS, DEPTH);
  tconv(w1, w1_t, DIM_, 4 * DIM_, 4 * WQS, 4 * WQS, DEPTH);
  tconv(w2, w2_t, 4 * DIM_, DIM_, 4 * WQS, 4 * WQS, DEPTH);
  // pkv stays k-major over n: pk [N][KLIN] -> pkv_t [2KLIN][N] per layer
  tconv(pk, pkv_t, N_, KLIN, (long long)N_ * KLIN, (long long)2 * KLIN * N_, DEPTH);
  tconv(pv, pkv_t + (long long)KLIN * N_, N_, KLIN, (long long)N_ * KLIN,
        (long long)2 * KLIN * N_, DEPTH);
  tconv(emb_w, emb_wt, INDIM, DIM_, 0, 0, 1);
  hipLaunchKernelGGL(cconv_k, dim3((B_ * N_ * INDIM / 8 + 255) / 256),
                     dim3(256), 0, stream, x, x_bf, B_ * N_ * INDIM / 8);

  // ---- embedding: h = x@emb_w + emb_b + pos ----
  hipLaunchKernelGGL((gemm_bf<0>), dim3(DIM_ / 128, B_ * N_ / 128, 1),
                     dim3(256), 0, stream, x_bf, emb_wt, emb_b, pos, (void*)h,
                     B_ * N_, DIM_, INDIM, INDIM, INDIM, DIM_, 0LL, 0LL, 0LL,
                     0, 0LL, 2, N_);

  for (int i = 0; i < DEPTH; ++i) {
    const short* wq_i  = wq_t + i * WQS;
    const short* wkv_i = wkv_t + i * 2 * WQS;
    const short* wo_i  = wo_t + i * WQS;
    const short* w1_i  = w1_t + (long long)i * 4 * WQS;
    const short* w2_i  = w2_t + (long long)i * 4 * WQS;
    const short* pkv_i = pkv_t + (long long)i * 2 * KLIN * N_;

    // ---- attention, 2 chunks of 8 batches ----
    for (int c = 0; c < B_ / ACB; ++c) {
      float* hc = h + (long long)c * ACROWS * DIM_;
      hipLaunchKernelGGL(ln_k, dim3(ACROWS / 4), dim3(256), 0, stream, hc,
                         ln1_s + i * DIM_, ln1_b + i * DIM_, zc);
      // zcT[b] = zc[b]^T  ([N_][DIM] -> [DIM][N_], per batch)
      hipLaunchKernelGGL(tpose_k, dim3(DIM_ / 64, N_ / 64, ACB), dim3(256), 0,
                         stream, zc, zcT, N_, DIM_, (long long)N_ * DIM_,
                         (long long)DIM_ * N_);
      // qc = zc @ wq
      hipLaunchKernelGGL((gemm_bf<1>), dim3(DIM_ / 128, ACROWS / 128, 1),
                         dim3(256), 0, stream, zc, wq_i, nullptr, nullptr,
                         (void*)qc, ACROWS, DIM_, DIM_, DIM_, DIM_, DIM_, 0LL,
                         0LL, 0LL, 0, 0LL, 0, 0);
      // zp[b] = pkv^T @ zc[b]  (Bt = zcT[b], clean k-major)
      hipLaunchKernelGGL((gemm_bf<1>), dim3(DIM_ / 128, 512 / 128, ACB),
                         dim3(256), 0, stream, pkv_i, zcT, nullptr, nullptr,
                         (void*)zp, 512, DIM_, N_, N_, N_, DIM_, 0LL,
                         (long long)DIM_ * N_, KVS, 0, 0LL, 0, 0);
      // kvp[b] = zp[b] @ [wk | wv]  (B dual by output row)
      hipLaunchKernelGGL((gemm_bf<1>), dim3(DIM_ / 128, 512 / 128, ACB),
                         dim3(256), 0, stream, zp, wkv_i, nullptr, nullptr,
                         (void*)kvp, 512, DIM_, DIM_, DIM_, DIM_, DIM_, KVS,
                         0LL, KVS, KLIN, (long long)WQS, 0, 0);
      // fused attention in-place on qc
      hipLaunchKernelGGL(attn_k, dim3(N_ / 64, HEADS, ACB), dim3(256), 0,
                         stream, qc, kvp, scale);
      // h += qc @ wo + wo_b
      hipLaunchKernelGGL((gemm_bf<0>), dim3(DIM_ / 128, ACROWS / 128, 1),
                         dim3(256), 0, stream, qc, wo_i, wo_b + i * DIM_,
                         hc, (void*)hc, ACROWS, DIM_, DIM_, DIM_, DIM_, DIM_,
                         0LL, 0LL, 0LL, 0, 0LL, 2, 0);
    }

    // ---- FFN, 2 chunks of 8192 rows x ... (4 chunks) ----
    for (int r0 = 0; r0 < B_ * N_; r0 += FROWS) {
      float* hr = h + (long long)r0 * DIM_;
      hipLaunchKernelGGL(ln_k, dim3(FROWS / 4), dim3(256), 0, stream, hr,
                         ln2_s + i * DIM_, ln2_b + i * DIM_, zln);
      // ffnmid = gelu(zln @ w1 + b1)
      hipLaunchKernelGGL((gemm_bf<1>), dim3(4 * DIM_ / 128, FROWS / 128, 1),
                         dim3(256), 0, stream, zln, w1_i,
                         b1 + (long long)i * 4 * DIM_, nullptr, (void*)ffnmid,
                         FROWS, 4 * DIM_, DIM_, DIM_, DIM_, 4 * DIM_, 0LL, 0LL,
                         0LL, 0, 0LL, 3, 0);
      // h += ffnmid @ w2 + b2
      hipLaunchKernelGGL((gemm_bf<0>), dim3(DIM_ / 128, FROWS / 128, 1),
                         dim3(256), 0, stream, ffnmid, w2_i,
                         b2 + (long long)i * DIM_, hr, (void*)hr, FROWS, DIM_,
                         4 * DIM_, 4 * DIM_, 4 * DIM_, DIM_, 0LL, 0LL, 0LL, 0,
                         0LL, 2, 0);
    }
  }

  hipLaunchKernelGGL(pool1_k, dim3(16, B_), dim3(256), 0, stream, h, partial);
  hipLaunchKernelGGL(pool2_k, dim3(B_), dim3(256), 0, stream, partial, pooled);
  hipLaunchKernelGGL(fc_k, dim3(1), dim3(64), 0, stream, pooled, fc_w, fc_b,
                     out);
}

// Round 8
// 2900.210 us; speedup vs baseline: 7.3338x; 1.1520x over previous
//
#include <hip/hip_runtime.h>
#include <math.h>

// ---------------- constants ----------------
#define B_    16
#define N_    2048
#define INDIM 64
#define DIM_  512
#define HEADS 8
#define DEPTH 4
#define KLIN  256
#define NCLS  2
#define DH    64
#define EPSF  1e-5f
#define ACB   8                    // batches per attention chunk
#define ACROWS (ACB * N_)          // 16384 rows
#define FROWS 8192                 // rows per FFN chunk

typedef __attribute__((ext_vector_type(8))) short short8v;
typedef __attribute__((ext_vector_type(4))) short short4v;
typedef __attribute__((ext_vector_type(4))) float f32x4;

// fp32 -> bf16 round-to-nearest-even (finite inputs)
__device__ __forceinline__ short f2bf(float f) {
  unsigned u = __float_as_uint(f);
  u += 0x7FFFu + ((u >> 16) & 1u);
  return (short)(u >> 16);
}

__device__ __forceinline__ float wave_sum(float v) {
  #pragma unroll
  for (int o = 32; o > 0; o >>= 1) v += __shfl_xor(v, o);
  return v;
}

__device__ __forceinline__ float gelu_tanh(float x) {
  float x3 = x * x * x;
  float t = tanhf(0.7978845608028654f * (x + 0.044715f * x3));
  return 0.5f * x * (1.f + t);
}

// async global->LDS, 16B per lane; LDS dest = wave-uniform base + lane*16
__device__ __forceinline__ void gl_lds16(const short* g, short* l) {
  __builtin_amdgcn_global_load_lds(
      (const __attribute__((address_space(1))) unsigned int*)g,
      (__attribute__((address_space(3))) unsigned int*)l, 16, 0, 0);
}

// ---------------- converts (once per launch) ----------------
// transpose-convert: src fp32 [R][C] -> dst bf16 [C][R], batched over z
__global__ __launch_bounds__(256) void tconv_k(const float* __restrict__ src,
                                               short* __restrict__ dst, int R,
                                               int C, long long sSrc,
                                               long long sDst) {
  __shared__ float tile[32][33];
  int c0 = blockIdx.x * 32, r0 = blockIdx.y * 32;
  src += (long long)blockIdx.z * sSrc;
  dst += (long long)blockIdx.z * sDst;
  int tx = threadIdx.x & 31, ty = threadIdx.x >> 5;
  #pragma unroll
  for (int rr = 0; rr < 4; ++rr)
    tile[ty + rr * 8][tx] = src[(long long)(r0 + ty + rr * 8) * C + c0 + tx];
  __syncthreads();
  #pragma unroll
  for (int rr = 0; rr < 4; ++rr) {
    int c = ty + rr * 8;
    dst[(long long)(c0 + c) * R + r0 + tx] = f2bf(tile[tx][c]);
  }
}

// straight copy-convert fp32 -> bf16, n8 = elements/8
__global__ __launch_bounds__(256) void cconv_k(const float* __restrict__ src,
                                               short* __restrict__ dst,
                                               int n8) {
  int i = blockIdx.x * 256 + threadIdx.x;
  if (i < n8) {
    const float* s = src + (long long)i * 8;
    float4 a = *(const float4*)s, c = *(const float4*)(s + 4);
    short8v o = {f2bf(a.x), f2bf(a.y), f2bf(a.z), f2bf(a.w),
                 f2bf(c.x), f2bf(c.y), f2bf(c.z), f2bf(c.w)};
    *(short8v*)(dst + (long long)i * 8) = o;
  }
}

// ---------------- bf16 tile transpose: [R][C] -> [C][R], batched ----------
__global__ __launch_bounds__(256) void tpose_k(const short* __restrict__ src,
                                               short* __restrict__ dst, int R,
                                               int C, long long sSrc,
                                               long long sDst) {
  __shared__ __align__(16) short tile[64][72];
  int c0 = blockIdx.x * 64, r0 = blockIdx.y * 64;
  src += (long long)blockIdx.z * sSrc;
  dst += (long long)blockIdx.z * sDst;
  int t = threadIdx.x;
  #pragma unroll
  for (int rep = 0; rep < 2; ++rep) {
    int row = rep * 32 + (t >> 3), c8 = (t & 7) * 8;
    *(short8v*)&tile[row][c8] =
        *(const short8v*)(src + (long long)(r0 + row) * C + c0 + c8);
  }
  __syncthreads();
  #pragma unroll
  for (int rep = 0; rep < 2; ++rep) {
    int c = rep * 32 + (t >> 3), r8 = (t & 7) * 8;
    short8v o;
    #pragma unroll
    for (int j = 0; j < 8; ++j) o[j] = tile[r8 + j][c];
    *(short8v*)(dst + (long long)(c0 + c) * R + r0 + r8) = o;
  }
}

// ---------------- LayerNorm: fp32 in, bf16 out ----------------
__global__ __launch_bounds__(256) void ln_k(const float* __restrict__ h,
                                            const float* __restrict__ s,
                                            const float* __restrict__ b,
                                            short* __restrict__ z) {
  int lane = threadIdx.x & 63;
  long long row = ((long long)blockIdx.x << 2) + (threadIdx.x >> 6);
  const float* hr = h + row * DIM_ + lane * 8;
  float4 a = *(const float4*)hr;
  float4 c = *(const float4*)(hr + 4);
  float sum = a.x + a.y + a.z + a.w + c.x + c.y + c.z + c.w;
  sum = wave_sum(sum);
  float mu = sum * (1.f / DIM_);
  float d[8] = {a.x - mu, a.y - mu, a.z - mu, a.w - mu,
                c.x - mu, c.y - mu, c.z - mu, c.w - mu};
  float vs = 0.f;
  #pragma unroll
  for (int i = 0; i < 8; ++i) vs += d[i] * d[i];
  vs = wave_sum(vs);
  float rstd = rsqrtf(vs * (1.f / DIM_) + EPSF);
  const float* sp = s + lane * 8;
  const float* bp = b + lane * 8;
  float4 s0 = *(const float4*)sp, s1 = *(const float4*)(sp + 4);
  float4 b0 = *(const float4*)bp, b1 = *(const float4*)(bp + 4);
  float o[8];
  o[0] = d[0] * rstd * s0.x + b0.x; o[1] = d[1] * rstd * s0.y + b0.y;
  o[2] = d[2] * rstd * s0.z + b0.z; o[3] = d[3] * rstd * s0.w + b0.w;
  o[4] = d[4] * rstd * s1.x + b1.x; o[5] = d[5] * rstd * s1.y + b1.y;
  o[6] = d[6] * rstd * s1.z + b1.z; o[7] = d[7] * rstd * s1.w + b1.w;
  short8v ov = {f2bf(o[0]), f2bf(o[1]), f2bf(o[2]), f2bf(o[3]),
                f2bf(o[4]), f2bf(o[5]), f2bf(o[6]), f2bf(o[7])};
  *(short8v*)(z + row * DIM_ + lane * 8) = ov;
}

// ---------------- bf16 MFMA GEMM, BMx128 tile, BK=64 ----------------
// C[m,n] = sum_k A[m][k] * Bt[n][k] (+ epilogue). Both operands k-major.
// Staging: global_load_lds 16B/lane, XOR-swizzled source chunks so the
// unpadded [row][64] LDS layout gives 2-way (free) frag-read conflicts.
// MFMA operands swapped => acc regs hold 4 consecutive n-cols per thread
// => fully vectorized epilogue (float4 / short4 stores, float4 bias/resid).
// epi: 0 none; 1 +bias; 2 +bias+resid[(m%resMod)*ldc+n] (fp32); 3 gelu(+bias)
// dual: if dualThresh && bm >= dualThresh, Bt += dualOff
template <int OUTBF, int BM>
__global__ __launch_bounds__(256) void gemm_bf(
    const short* __restrict__ A, const short* __restrict__ Bsrc,
    const float* __restrict__ bias, const float* __restrict__ resid,
    void* __restrict__ Cv, int M, int N, int K, int lda, int ldb, int ldc,
    long long sAb, long long sBb, long long sCb, int dualThresh,
    long long dualOff, int epi, int resMod) {
  constexpr int MT = BM / 32;   // frag rows per wave: 4 (BM=128) or 2 (BM=64)
  constexpr int WMS = BM / 2;   // wave m-stride
  int zz = blockIdx.z;
  A += (long long)zz * sAb;
  Bsrc += (long long)zz * sBb;
  int bm = blockIdx.y * BM, bn = blockIdx.x * 128;
  if (dualThresh && bm >= dualThresh) Bsrc += dualOff;
  int t = threadIdx.x;
  __shared__ __align__(16) short Alds[BM * 64];
  __shared__ __align__(16) short Blds[128 * 64];
  int lane = t & 63, wid = t >> 6;
  int lr = lane & 15, q = lane >> 4;
  int wm = (wid >> 1) * WMS, wn = (wid & 1) * 64;
  int rl = lane >> 3;          // row within 8-row group
  int cs = (lane & 7) ^ rl;    // swizzled source chunk
  f32x4 acc[MT][4] = {};

  for (int k0 = 0; k0 < K; k0 += 64) {
    #pragma unroll
    for (int i = 0; i < BM / 32; ++i) {
      int rb = i * 32 + wid * 8;
      gl_lds16(A + (long long)(bm + rb + rl) * lda + k0 + cs * 8,
               Alds + rb * 64);
    }
    #pragma unroll
    for (int i = 0; i < 4; ++i) {
      int rb = i * 32 + wid * 8;
      gl_lds16(Bsrc + (long long)(bn + rb + rl) * ldb + k0 + cs * 8,
               Blds + rb * 64);
    }
    __syncthreads();
    #pragma unroll
    for (int kk2 = 0; kk2 < 2; ++kk2) {
      short8v af[MT], bfr[4];
      #pragma unroll
      for (int mi = 0; mi < MT; ++mi)
        af[mi] = *(const short8v*)&Alds[(wm + mi * 16 + lr) * 64 +
                                        (((kk2 << 2) | q) ^ (lr & 7)) * 8];
      #pragma unroll
      for (int ni = 0; ni < 4; ++ni)
        bfr[ni] = *(const short8v*)&Blds[(wn + ni * 16 + lr) * 64 +
                                         (((kk2 << 2) | q) ^ (lr & 7)) * 8];
      #pragma unroll
      for (int mi = 0; mi < MT; ++mi)
        #pragma unroll
        for (int ni = 0; ni < 4; ++ni)
          acc[mi][ni] = __builtin_amdgcn_mfma_f32_16x16x32_bf16(
              bfr[ni], af[mi], acc[mi][ni], 0, 0, 0);  // swapped: cols in regs
    }
    __syncthreads();
  }

  // ---- vectorized epilogue: thread owns row m, 4 consecutive cols per acc --
  #pragma unroll
  for (int mi = 0; mi < MT; ++mi) {
    int m = bm + wm + mi * 16 + lr;
    int rm = (epi == 2 && resMod) ? (m % resMod) : m;
    #pragma unroll
    for (int ni = 0; ni < 4; ++ni) {
      int nb = bn + wn + ni * 16 + q * 4;
      f32x4 v = acc[mi][ni];
      if (epi >= 1) {
        float4 bb = *(const float4*)(bias + nb);
        v[0] += bb.x; v[1] += bb.y; v[2] += bb.z; v[3] += bb.w;
      }
      if (epi == 2) {
        float4 rr = *(const float4*)(resid + (long long)rm * ldc + nb);
        v[0] += rr.x; v[1] += rr.y; v[2] += rr.z; v[3] += rr.w;
      } else if (epi == 3) {
        v[0] = gelu_tanh(v[0]); v[1] = gelu_tanh(v[1]);
        v[2] = gelu_tanh(v[2]); v[3] = gelu_tanh(v[3]);
      }
      long long base = (long long)zz * sCb + (long long)m * ldc + nb;
      if (OUTBF) {
        short4v o = {f2bf(v[0]), f2bf(v[1]), f2bf(v[2]), f2bf(v[3])};
        *(short4v*)((short*)Cv + base) = o;
      } else {
        *(float4*)((float*)Cv + base) = make_float4(v[0], v[1], v[2], v[3]);
      }
    }
  }
}

// ---------------- fused Linformer attention, bf16 MFMA ----------------
__global__ __launch_bounds__(256) void attn_k(short* __restrict__ qc,
                                              const short* __restrict__ kvp,
                                              float scale) {
  int n0 = blockIdx.x * 64, hh = blockIdx.y, b = blockIdx.z;
  int t = threadIdx.x;
  int lane = t & 63, w = t >> 6;
  int lr = lane & 15, qd = lane >> 4;

  __shared__ __align__(16) short Qlds[64][72];
  __shared__ __align__(16) short Kbuf[256 * 72];  // K, then aliased as P
  __shared__ __align__(16) short Vt[64][264];
  auto Klds = (short(*)[72])Kbuf;
  auto Plds = (short(*)[264])Kbuf;

  short* qptr = qc + (long long)b * N_ * DIM_ + hh * DH;
  const short* kptr = kvp + (long long)b * 2 * KLIN * DIM_ + hh * DH;
  const short* vptr = kptr + (long long)KLIN * DIM_;

  #pragma unroll
  for (int rep = 0; rep < 2; ++rep) {
    int L = rep * 256 + t, row = L >> 3, c8 = (L & 7) << 3;
    *(short8v*)&Qlds[row][c8] =
        *(const short8v*)(qptr + (long long)(n0 + row) * DIM_ + c8);
  }
  #pragma unroll
  for (int rep = 0; rep < 8; ++rep) {
    int L = rep * 256 + t, row = L >> 3, c8 = (L & 7) << 3;
    *(short8v*)&Klds[row][c8] =
        *(const short8v*)(kptr + (long long)row * DIM_ + c8);
  }
  #pragma unroll
  for (int rep = 0; rep < 4; ++rep) {
    int key0 = rep * 64 + (t >> 4) * 4, dh0 = (t & 15) * 4;
    short4v a0 = *(const short4v*)(vptr + (long long)(key0 + 0) * DIM_ + dh0);
    short4v a1 = *(const short4v*)(vptr + (long long)(key0 + 1) * DIM_ + dh0);
    short4v a2 = *(const short4v*)(vptr + (long long)(key0 + 2) * DIM_ + dh0);
    short4v a3 = *(const short4v*)(vptr + (long long)(key0 + 3) * DIM_ + dh0);
    short4v w0 = {a0[0], a1[0], a2[0], a3[0]};
    short4v w1 = {a0[1], a1[1], a2[1], a3[1]};
    short4v w2 = {a0[2], a1[2], a2[2], a3[2]};
    short4v w3 = {a0[3], a1[3], a2[3], a3[3]};
    *(short4v*)&Vt[dh0 + 0][key0] = w0;
    *(short4v*)&Vt[dh0 + 1][key0] = w1;
    *(short4v*)&Vt[dh0 + 2][key0] = w2;
    *(short4v*)&Vt[dh0 + 3][key0] = w3;
  }
  __syncthreads();

  short8v qa0 = *(const short8v*)&Qlds[16 * w + lr][qd * 8];
  short8v qa1 = *(const short8v*)&Qlds[16 * w + lr][32 + qd * 8];
  f32x4 sacc[16];
  #pragma unroll
  for (int nt = 0; nt < 16; ++nt) {
    short8v b0 = *(const short8v*)&Klds[nt * 16 + lr][qd * 8];
    short8v b1 = *(const short8v*)&Klds[nt * 16 + lr][32 + qd * 8];
    f32x4 acc = {};
    acc = __builtin_amdgcn_mfma_f32_16x16x32_bf16(qa0, b0, acc, 0, 0, 0);
    acc = __builtin_amdgcn_mfma_f32_16x16x32_bf16(qa1, b1, acc, 0, 0, 0);
    sacc[nt] = acc;
  }

  // softmax; normalize P in-place (no epilogue divide needed)
  #pragma unroll
  for (int r = 0; r < 4; ++r) {
    float m = -1e30f;
    #pragma unroll
    for (int nt = 0; nt < 16; ++nt) {
      sacc[nt][r] *= scale;
      m = fmaxf(m, sacc[nt][r]);
    }
    #pragma unroll
    for (int o = 1; o < 16; o <<= 1) m = fmaxf(m, __shfl_xor(m, o));
    float rs = 0.f;
    #pragma unroll
    for (int nt = 0; nt < 16; ++nt) {
      float e = __expf(sacc[nt][r] - m);
      sacc[nt][r] = e;
      rs += e;
    }
    #pragma unroll
    for (int o = 1; o < 16; o <<= 1) rs += __shfl_xor(rs, o);
    float inv = 1.f / rs;
    #pragma unroll
    for (int nt = 0; nt < 16; ++nt) sacc[nt][r] *= inv;
  }

  __syncthreads();  // Klds reads done; reuse as Plds
  #pragma unroll
  for (int nt = 0; nt < 16; ++nt)
    #pragma unroll
    for (int r = 0; r < 4; ++r)
      Plds[16 * w + qd * 4 + r][nt * 16 + lr] = f2bf(sacc[nt][r]);
  __syncthreads();

  // out = P @ V, swapped operands: thread owns query row 16w+lr,
  // dh cols n2*16 + qd*4 + 0..3 -> vectorized 8B stores
  f32x4 out[4] = {};
  #pragma unroll
  for (int k0 = 0; k0 < 8; ++k0) {
    short8v ap = *(const short8v*)&Plds[16 * w + lr][k0 * 32 + qd * 8];
    #pragma unroll
    for (int n2 = 0; n2 < 4; ++n2) {
      short8v bv = *(const short8v*)&Vt[n2 * 16 + lr][k0 * 32 + qd * 8];
      out[n2] =
          __builtin_amdgcn_mfma_f32_16x16x32_bf16(bv, ap, out[n2], 0, 0, 0);
    }
  }

  long long rowoff = (long long)(n0 + 16 * w + lr) * DIM_;
  #pragma unroll
  for (int n2 = 0; n2 < 4; ++n2) {
    short4v o = {f2bf(out[n2][0]), f2bf(out[n2][1]), f2bf(out[n2][2]),
                 f2bf(out[n2][3])};
    *(short4v*)(qptr + rowoff + n2 * 16 + qd * 4) = o;
  }
}

// ---------------- two-stage mean pool ----------------
__global__ __launch_bounds__(256) void pool1_k(const float* __restrict__ h,
                                               float* __restrict__ partial) {
  int stripe = blockIdx.x, b = blockIdx.y;
  int c4 = (threadIdx.x & 127) * 4, half = threadIdx.x >> 7;
  const float* base =
      h + ((long long)b * N_ + stripe * 128 + half * 64) * DIM_ + c4;
  float4 acc = {0.f, 0.f, 0.f, 0.f};
  for (int r = 0; r < 64; ++r) {
    float4 v = *(const float4*)(base + (long long)r * DIM_);
    acc.x += v.x; acc.y += v.y; acc.z += v.z; acc.w += v.w;
  }
  __shared__ float red[512];
  if (half == 1) *(float4*)&red[c4] = acc;
  __syncthreads();
  if (half == 0) {
    float4 o = *(const float4*)&red[c4];
    o.x += acc.x; o.y += acc.y; o.z += acc.z; o.w += acc.w;
    *(float4*)&partial[((long long)b * 16 + stripe) * DIM_ + c4] = o;
  }
}
__global__ __launch_bounds__(256) void pool2_k(const float* __restrict__ partial,
                                               float* __restrict__ pooled) {
  int b = blockIdx.x;
  for (int c = threadIdx.x; c < DIM_; c += 256) {
    float s = 0.f;
    for (int k = 0; k < 16; ++k) s += partial[((long long)b * 16 + k) * DIM_ + c];
    pooled[b * DIM_ + c] = s * (1.f / N_);
  }
}

// ---------------- final FC [16,512]@[512,2] ----------------
__global__ __launch_bounds__(64) void fc_k(const float* __restrict__ pooled,
                                           const float* __restrict__ fc_w,
                                           const float* __restrict__ fc_b,
                                           float* __restrict__ out) {
  int t = threadIdx.x;
  if (t < B_ * NCLS) {
    int b = t >> 1, c = t & 1;
    float s = fc_b[c];
    for (int d = 0; d < DIM_; ++d)
      s += pooled[b * DIM_ + d] * fc_w[d * NCLS + c];
    out[t] = s;
  }
}

extern "C" void kernel_launch(void* const* d_in, const int* in_sizes, int n_in,
                              void* d_out, int out_size, void* d_ws,
                              size_t ws_size, hipStream_t stream) {
  const float* x     = (const float*)d_in[0];
  const float* emb_w = (const float*)d_in[1];
  const float* emb_b = (const float*)d_in[2];
  const float* pos   = (const float*)d_in[3];
  const float* ln1_s = (const float*)d_in[4];
  const float* ln1_b = (const float*)d_in[5];
  const float* wq    = (const float*)d_in[6];
  const float* wk    = (const float*)d_in[7];
  const float* wv    = (const float*)d_in[8];
  const float* pk    = (const float*)d_in[9];
  const float* pv    = (const float*)d_in[10];
  const float* wo    = (const float*)d_in[11];
  const float* wo_b  = (const float*)d_in[12];
  const float* ln2_s = (const float*)d_in[13];
  const float* ln2_b = (const float*)d_in[14];
  const float* w1    = (const float*)d_in[15];
  const float* b1    = (const float*)d_in[16];
  const float* w2    = (const float*)d_in[17];
  const float* b2    = (const float*)d_in[18];
  const float* fc_w  = (const float*)d_in[19];
  const float* fc_b  = (const float*)d_in[20];
  float* out = (float*)d_out;

  // ---- workspace (~165 MB) ----
  char* P = (char*)d_ws;
  float* h = (float*)P;            P += (long long)B_ * N_ * DIM_ * 4;   // 67MB
  short* zc = (short*)P;                                                 // arena
  short* qc = zc + (long long)ACROWS * DIM_;
  short* ffnmid = zc;              P += (long long)2 * ACROWS * DIM_ * 2; // 33.5MB
  short* zcT = (short*)P;          P += (long long)ACB * DIM_ * N_ * 2;   // 16.8MB
  short* zp = (short*)P;
  short* kvp = zp + (long long)ACB * 2 * KLIN * DIM_;
  short* zln = zp;                 P += (long long)2 * ACB * 2 * KLIN * DIM_ * 2; // 8.4MB
  short* wq_t  = (short*)P;  P += (long long)DEPTH * DIM_ * DIM_ * 2;
  short* wkv_t = (short*)P;  P += (long long)DEPTH * 2 * DIM_ * DIM_ * 2;
  short* wo_t  = (short*)P;  P += (long long)DEPTH * DIM_ * DIM_ * 2;
  short* w1_t  = (short*)P;  P += (long long)DEPTH * 4 * DIM_ * DIM_ * 2;
  short* w2_t  = (short*)P;  P += (long long)DEPTH * 4 * DIM_ * DIM_ * 2;
  short* pkv_t = (short*)P;  P += (long long)DEPTH * 2 * KLIN * N_ * 2;
  short* emb_wt = (short*)P; P += (long long)DIM_ * INDIM * 2;
  short* x_bf  = (short*)P;  P += (long long)B_ * N_ * INDIM * 2;
  float* partial = (float*)P; P += (long long)B_ * 16 * DIM_ * 4;
  float* pooled  = (float*)P;

  const float scale = 0.125f;
  const long long WQS = (long long)DIM_ * DIM_;        // 262144
  const long long KVS = (long long)2 * KLIN * DIM_;    // 262144

  // ---- converts ----
  auto tconv = [&](const float* s, short* d, int R, int C, long long ss,
                   long long sd, int b) {
    hipLaunchKernelGGL(tconv_k, dim3(C / 32, R / 32, b), dim3(256), 0, stream,
                       s, d, R, C, ss, sd);
  };
  tconv(wq, wq_t, DIM_, DIM_, WQS, WQS, DEPTH);
  tconv(wk, wkv_t, DIM_, DIM_, WQS, 2 * WQS, DEPTH);
  tconv(wv, wkv_t + WQS, DIM_, DIM_, WQS, 2 * WQS, DEPTH);
  tconv(wo, wo_t, DIM_, DIM_, WQS, WQS, DEPTH);
  tconv(w1, w1_t, DIM_, 4 * DIM_, 4 * WQS, 4 * WQS, DEPTH);
  tconv(w2, w2_t, 4 * DIM_, DIM_, 4 * WQS, 4 * WQS, DEPTH);
  tconv(pk, pkv_t, N_, KLIN, (long long)N_ * KLIN, (long long)2 * KLIN * N_, DEPTH);
  tconv(pv, pkv_t + (long long)KLIN * N_, N_, KLIN, (long long)N_ * KLIN,
        (long long)2 * KLIN * N_, DEPTH);
  tconv(emb_w, emb_wt, INDIM, DIM_, 0, 0, 1);
  hipLaunchKernelGGL(cconv_k, dim3((B_ * N_ * INDIM / 8 + 255) / 256),
                     dim3(256), 0, stream, x, x_bf, B_ * N_ * INDIM / 8);

  // ---- embedding: h = x@emb_w + emb_b + pos ----
  hipLaunchKernelGGL((gemm_bf<0, 128>), dim3(DIM_ / 128, B_ * N_ / 128, 1),
                     dim3(256), 0, stream, x_bf, emb_wt, emb_b, pos, (void*)h,
                     B_ * N_, DIM_, INDIM, INDIM, INDIM, DIM_, 0LL, 0LL, 0LL,
                     0, 0LL, 2, N_);

  for (int i = 0; i < DEPTH; ++i) {
    const short* wq_i  = wq_t + i * WQS;
    const short* wkv_i = wkv_t + i * 2 * WQS;
    const short* wo_i  = wo_t + i * WQS;
    const short* w1_i  = w1_t + (long long)i * 4 * WQS;
    const short* w2_i  = w2_t + (long long)i * 4 * WQS;
    const short* pkv_i = pkv_t + (long long)i * 2 * KLIN * N_;

    // ---- attention, 2 chunks of 8 batches ----
    for (int c = 0; c < B_ / ACB; ++c) {
      float* hc = h + (long long)c * ACROWS * DIM_;
      hipLaunchKernelGGL(ln_k, dim3(ACROWS / 4), dim3(256), 0, stream, hc,
                         ln1_s + i * DIM_, ln1_b + i * DIM_, zc);
      // zcT[b] = zc[b]^T
      hipLaunchKernelGGL(tpose_k, dim3(DIM_ / 64, N_ / 64, ACB), dim3(256), 0,
                         stream, zc, zcT, N_, DIM_, (long long)N_ * DIM_,
                         (long long)DIM_ * N_);
      // qc = zc @ wq
      hipLaunchKernelGGL((gemm_bf<1, 128>), dim3(DIM_ / 128, ACROWS / 128, 1),
                         dim3(256), 0, stream, zc, wq_i, nullptr, nullptr,
                         (void*)qc, ACROWS, DIM_, DIM_, DIM_, DIM_, DIM_, 0LL,
                         0LL, 0LL, 0, 0LL, 0, 0);
      // zp[b] = pkv^T @ zc[b]  (Bt = zcT[b])
      hipLaunchKernelGGL((gemm_bf<1, 64>), dim3(DIM_ / 128, 512 / 64, ACB),
                         dim3(256), 0, stream, pkv_i, zcT, nullptr, nullptr,
                         (void*)zp, 512, DIM_, N_, N_, N_, DIM_, 0LL,
                         (long long)DIM_ * N_, KVS, 0, 0LL, 0, 0);
      // kvp[b] = zp[b] @ [wk | wv]  (B dual by output row)
      hipLaunchKernelGGL((gemm_bf<1, 64>), dim3(DIM_ / 128, 512 / 64, ACB),
                         dim3(256), 0, stream, zp, wkv_i, nullptr, nullptr,
                         (void*)kvp, 512, DIM_, DIM_, DIM_, DIM_, DIM_, KVS,
                         0LL, KVS, KLIN, (long long)WQS, 0, 0);
      // fused attention in-place on qc
      hipLaunchKernelGGL(attn_k, dim3(N_ / 64, HEADS, ACB), dim3(256), 0,
                         stream, qc, kvp, scale);
      // h += qc @ wo + wo_b
      hipLaunchKernelGGL((gemm_bf<0, 128>), dim3(DIM_ / 128, ACROWS / 128, 1),
                         dim3(256), 0, stream, qc, wo_i, wo_b + i * DIM_,
                         hc, (void*)hc, ACROWS, DIM_, DIM_, DIM_, DIM_, DIM_,
                         0LL, 0LL, 0LL, 0, 0LL, 2, 0);
    }

    // ---- FFN, 4 chunks of 8192 rows ----
    for (int r0 = 0; r0 < B_ * N_; r0 += FROWS) {
      float* hr = h + (long long)r0 * DIM_;
      hipLaunchKernelGGL(ln_k, dim3(FROWS / 4), dim3(256), 0, stream, hr,
                         ln2_s + i * DIM_, ln2_b + i * DIM_, zln);
      // ffnmid = gelu(zln @ w1 + b1)
      hipLaunchKernelGGL((gemm_bf<1, 128>), dim3(4 * DIM_ / 128, FROWS / 128, 1),
                         dim3(256), 0, stream, zln, w1_i,
                         b1 + (long long)i * 4 * DIM_, nullptr, (void*)ffnmid,
                         FROWS, 4 * DIM_, DIM_, DIM_, DIM_, 4 * DIM_, 0LL, 0LL,
                         0LL, 0, 0LL, 3, 0);
      // h += ffnmid @ w2 + b2   (BM=64 -> 512 blocks)
      hipLaunchKernelGGL((gemm_bf<0, 64>), dim3(DIM_ / 128, FROWS / 64, 1),
                         dim3(256), 0, stream, ffnmid, w2_i,
                         b2 + (long long)i * DIM_, hr, (void*)hr, FROWS, DIM_,
                         4 * DIM_, 4 * DIM_, 4 * DIM_, DIM_, 0LL, 0LL, 0LL, 0,
                         0LL, 2, 0);
    }
  }

  hipLaunchKernelGGL(pool1_k, dim3(16, B_), dim3(256), 0, stream, h, partial);
  hipLaunchKernelGGL(pool2_k, dim3(B_), dim3(256), 0, stream, partial, pooled);
  hipLaunchKernelGGL(fc_k, dim3(1), dim3(64), 0, stream, pooled, fc_w, fc_b,
                     out);
}

// Round 9
// 2734.554 us; speedup vs baseline: 7.7781x; 1.0606x over previous
//
#include <hip/hip_runtime.h>
#include <math.h>

// ---------------- constants ----------------
#define B_    16
#define N_    2048
#define INDIM 64
#define DIM_  512
#define HEADS 8
#define DEPTH 4
#define KLIN  256
#define NCLS  2
#define DH    64
#define EPSF  1e-5f
#define ACB   8                    // batches per attention chunk
#define ACROWS (ACB * N_)          // 16384 rows
#define FROWS 8192                 // rows per FFN chunk

typedef __attribute__((ext_vector_type(8))) short short8v;
typedef __attribute__((ext_vector_type(4))) short short4v;
typedef __attribute__((ext_vector_type(4))) float f32x4;

// fp32 -> bf16 round-to-nearest-even (finite inputs)
__device__ __forceinline__ short f2bf(float f) {
  unsigned u = __float_as_uint(f);
  u += 0x7FFFu + ((u >> 16) & 1u);
  return (short)(u >> 16);
}

__device__ __forceinline__ float wave_sum(float v) {
  #pragma unroll
  for (int o = 32; o > 0; o >>= 1) v += __shfl_xor(v, o);
  return v;
}

// tanh-GELU via sigmoid identity: 0.5x(1+tanh(c(x+a x^3))) = x*sigmoid(2c x + 2ca x^3)
// ~7 VALU (v_exp_f32 + v_rcp) vs ~45+ for libm tanhf. Same formula, fp32-exact
// to ~1e-7 (under bf16 rounding noise).
__device__ __forceinline__ float gelu_tanh(float x) {
  float u = x * (1.5957691216057308f + 0.07135481627f * x * x);
  return x / (1.f + __expf(-u));
}

// async global->LDS, 16B per lane; LDS dest = wave-uniform base + lane*16
__device__ __forceinline__ void gl_lds16(const short* g, short* l) {
  __builtin_amdgcn_global_load_lds(
      (const __attribute__((address_space(1))) unsigned int*)g,
      (__attribute__((address_space(3))) unsigned int*)l, 16, 0, 0);
}

// ---------------- converts (once per launch) ----------------
// transpose-convert: src fp32 [R][C] -> dst bf16 [C][R], batched over z
__global__ __launch_bounds__(256) void tconv_k(const float* __restrict__ src,
                                               short* __restrict__ dst, int R,
                                               int C, long long sSrc,
                                               long long sDst) {
  __shared__ float tile[32][33];
  int c0 = blockIdx.x * 32, r0 = blockIdx.y * 32;
  src += (long long)blockIdx.z * sSrc;
  dst += (long long)blockIdx.z * sDst;
  int tx = threadIdx.x & 31, ty = threadIdx.x >> 5;
  #pragma unroll
  for (int rr = 0; rr < 4; ++rr)
    tile[ty + rr * 8][tx] = src[(long long)(r0 + ty + rr * 8) * C + c0 + tx];
  __syncthreads();
  #pragma unroll
  for (int rr = 0; rr < 4; ++rr) {
    int c = ty + rr * 8;
    dst[(long long)(c0 + c) * R + r0 + tx] = f2bf(tile[tx][c]);
  }
}

// straight copy-convert fp32 -> bf16, n8 = elements/8
__global__ __launch_bounds__(256) void cconv_k(const float* __restrict__ src,
                                               short* __restrict__ dst,
                                               int n8) {
  int i = blockIdx.x * 256 + threadIdx.x;
  if (i < n8) {
    const float* s = src + (long long)i * 8;
    float4 a = *(const float4*)s, c = *(const float4*)(s + 4);
    short8v o = {f2bf(a.x), f2bf(a.y), f2bf(a.z), f2bf(a.w),
                 f2bf(c.x), f2bf(c.y), f2bf(c.z), f2bf(c.w)};
    *(short8v*)(dst + (long long)i * 8) = o;
  }
}

// ---------------- bf16 tile transpose: [R][C] -> [C][R], batched ----------
__global__ __launch_bounds__(256) void tpose_k(const short* __restrict__ src,
                                               short* __restrict__ dst, int R,
                                               int C, long long sSrc,
                                               long long sDst) {
  __shared__ __align__(16) short tile[64][72];
  int c0 = blockIdx.x * 64, r0 = blockIdx.y * 64;
  src += (long long)blockIdx.z * sSrc;
  dst += (long long)blockIdx.z * sDst;
  int t = threadIdx.x;
  #pragma unroll
  for (int rep = 0; rep < 2; ++rep) {
    int row = rep * 32 + (t >> 3), c8 = (t & 7) * 8;
    *(short8v*)&tile[row][c8] =
        *(const short8v*)(src + (long long)(r0 + row) * C + c0 + c8);
  }
  __syncthreads();
  #pragma unroll
  for (int rep = 0; rep < 2; ++rep) {
    int c = rep * 32 + (t >> 3), r8 = (t & 7) * 8;
    short8v o;
    #pragma unroll
    for (int j = 0; j < 8; ++j) o[j] = tile[r8 + j][c];
    *(short8v*)(dst + (long long)(c0 + c) * R + r0 + r8) = o;
  }
}

// ---------------- LayerNorm: fp32 in, bf16 out ----------------
__global__ __launch_bounds__(256) void ln_k(const float* __restrict__ h,
                                            const float* __restrict__ s,
                                            const float* __restrict__ b,
                                            short* __restrict__ z) {
  int lane = threadIdx.x & 63;
  long long row = ((long long)blockIdx.x << 2) + (threadIdx.x >> 6);
  const float* hr = h + row * DIM_ + lane * 8;
  float4 a = *(const float4*)hr;
  float4 c = *(const float4*)(hr + 4);
  float sum = a.x + a.y + a.z + a.w + c.x + c.y + c.z + c.w;
  sum = wave_sum(sum);
  float mu = sum * (1.f / DIM_);
  float d[8] = {a.x - mu, a.y - mu, a.z - mu, a.w - mu,
                c.x - mu, c.y - mu, c.z - mu, c.w - mu};
  float vs = 0.f;
  #pragma unroll
  for (int i = 0; i < 8; ++i) vs += d[i] * d[i];
  vs = wave_sum(vs);
  float rstd = rsqrtf(vs * (1.f / DIM_) + EPSF);
  const float* sp = s + lane * 8;
  const float* bp = b + lane * 8;
  float4 s0 = *(const float4*)sp, s1 = *(const float4*)(sp + 4);
  float4 b0 = *(const float4*)bp, b1 = *(const float4*)(bp + 4);
  float o[8];
  o[0] = d[0] * rstd * s0.x + b0.x; o[1] = d[1] * rstd * s0.y + b0.y;
  o[2] = d[2] * rstd * s0.z + b0.z; o[3] = d[3] * rstd * s0.w + b0.w;
  o[4] = d[4] * rstd * s1.x + b1.x; o[5] = d[5] * rstd * s1.y + b1.y;
  o[6] = d[6] * rstd * s1.z + b1.z; o[7] = d[7] * rstd * s1.w + b1.w;
  short8v ov = {f2bf(o[0]), f2bf(o[1]), f2bf(o[2]), f2bf(o[3]),
                f2bf(o[4]), f2bf(o[5]), f2bf(o[6]), f2bf(o[7])};
  *(short8v*)(z + row * DIM_ + lane * 8) = ov;
}

// ---------------- bf16 MFMA GEMM, BMx128 tile, BK=64 ----------------
// C[m,n] = sum_k A[m][k] * Bt[n][k] (+ epilogue). Both operands k-major.
// Staging: global_load_lds 16B/lane, XOR-swizzled source chunks so the
// unpadded [row][64] LDS layout gives 2-way (free) frag-read conflicts.
// MFMA operands swapped => acc regs hold 4 consecutive n-cols per thread
// => fully vectorized epilogue (float4 / short4 stores, float4 bias/resid).
// epi: 0 none; 1 +bias; 2 +bias+resid[(m%resMod)*ldc+n] (fp32); 3 gelu(+bias)
// dual: if dualThresh && bm >= dualThresh, Bt += dualOff
template <int OUTBF, int BM>
__global__ __launch_bounds__(256) void gemm_bf(
    const short* __restrict__ A, const short* __restrict__ Bsrc,
    const float* __restrict__ bias, const float* __restrict__ resid,
    void* __restrict__ Cv, int M, int N, int K, int lda, int ldb, int ldc,
    long long sAb, long long sBb, long long sCb, int dualThresh,
    long long dualOff, int epi, int resMod) {
  constexpr int MT = BM / 32;   // frag rows per wave: 4 (BM=128) or 2 (BM=64)
  constexpr int WMS = BM / 2;   // wave m-stride
  int zz = blockIdx.z;
  A += (long long)zz * sAb;
  Bsrc += (long long)zz * sBb;
  int bm = blockIdx.y * BM, bn = blockIdx.x * 128;
  if (dualThresh && bm >= dualThresh) Bsrc += dualOff;
  int t = threadIdx.x;
  __shared__ __align__(16) short Alds[BM * 64];
  __shared__ __align__(16) short Blds[128 * 64];
  int lane = t & 63, wid = t >> 6;
  int lr = lane & 15, q = lane >> 4;
  int wm = (wid >> 1) * WMS, wn = (wid & 1) * 64;
  int rl = lane >> 3;          // row within 8-row group
  int cs = (lane & 7) ^ rl;    // swizzled source chunk
  f32x4 acc[MT][4] = {};

  for (int k0 = 0; k0 < K; k0 += 64) {
    #pragma unroll
    for (int i = 0; i < BM / 32; ++i) {
      int rb = i * 32 + wid * 8;
      gl_lds16(A + (long long)(bm + rb + rl) * lda + k0 + cs * 8,
               Alds + rb * 64);
    }
    #pragma unroll
    for (int i = 0; i < 4; ++i) {
      int rb = i * 32 + wid * 8;
      gl_lds16(Bsrc + (long long)(bn + rb + rl) * ldb + k0 + cs * 8,
               Blds + rb * 64);
    }
    __syncthreads();
    #pragma unroll
    for (int kk2 = 0; kk2 < 2; ++kk2) {
      short8v af[MT], bfr[4];
      #pragma unroll
      for (int mi = 0; mi < MT; ++mi)
        af[mi] = *(const short8v*)&Alds[(wm + mi * 16 + lr) * 64 +
                                        (((kk2 << 2) | q) ^ (lr & 7)) * 8];
      #pragma unroll
      for (int ni = 0; ni < 4; ++ni)
        bfr[ni] = *(const short8v*)&Blds[(wn + ni * 16 + lr) * 64 +
                                         (((kk2 << 2) | q) ^ (lr & 7)) * 8];
      #pragma unroll
      for (int mi = 0; mi < MT; ++mi)
        #pragma unroll
        for (int ni = 0; ni < 4; ++ni)
          acc[mi][ni] = __builtin_amdgcn_mfma_f32_16x16x32_bf16(
              bfr[ni], af[mi], acc[mi][ni], 0, 0, 0);  // swapped: cols in regs
    }
    __syncthreads();
  }

  // ---- vectorized epilogue: thread owns row m, 4 consecutive cols per acc --
  #pragma unroll
  for (int mi = 0; mi < MT; ++mi) {
    int m = bm + wm + mi * 16 + lr;
    int rm = (epi == 2 && resMod) ? (m % resMod) : m;
    #pragma unroll
    for (int ni = 0; ni < 4; ++ni) {
      int nb = bn + wn + ni * 16 + q * 4;
      f32x4 v = acc[mi][ni];
      if (epi >= 1) {
        float4 bb = *(const float4*)(bias + nb);
        v[0] += bb.x; v[1] += bb.y; v[2] += bb.z; v[3] += bb.w;
      }
      if (epi == 2) {
        float4 rr = *(const float4*)(resid + (long long)rm * ldc + nb);
        v[0] += rr.x; v[1] += rr.y; v[2] += rr.z; v[3] += rr.w;
      } else if (epi == 3) {
        v[0] = gelu_tanh(v[0]); v[1] = gelu_tanh(v[1]);
        v[2] = gelu_tanh(v[2]); v[3] = gelu_tanh(v[3]);
      }
      long long base = (long long)zz * sCb + (long long)m * ldc + nb;
      if (OUTBF) {
        short4v o = {f2bf(v[0]), f2bf(v[1]), f2bf(v[2]), f2bf(v[3])};
        *(short4v*)((short*)Cv + base) = o;
      } else {
        *(float4*)((float*)Cv + base) = make_float4(v[0], v[1], v[2], v[3]);
      }
    }
  }
}

// ---------------- fused Linformer attention, bf16 MFMA ----------------
__global__ __launch_bounds__(256) void attn_k(short* __restrict__ qc,
                                              const short* __restrict__ kvp,
                                              float scale) {
  int n0 = blockIdx.x * 64, hh = blockIdx.y, b = blockIdx.z;
  int t = threadIdx.x;
  int lane = t & 63, w = t >> 6;
  int lr = lane & 15, qd = lane >> 4;

  __shared__ __align__(16) short Qlds[64][72];
  __shared__ __align__(16) short Kbuf[256 * 72];  // K, then aliased as P
  __shared__ __align__(16) short Vt[64][264];
  auto Klds = (short(*)[72])Kbuf;
  auto Plds = (short(*)[264])Kbuf;

  short* qptr = qc + (long long)b * N_ * DIM_ + hh * DH;
  const short* kptr = kvp + (long long)b * 2 * KLIN * DIM_ + hh * DH;
  const short* vptr = kptr + (long long)KLIN * DIM_;

  #pragma unroll
  for (int rep = 0; rep < 2; ++rep) {
    int L = rep * 256 + t, row = L >> 3, c8 = (L & 7) << 3;
    *(short8v*)&Qlds[row][c8] =
        *(const short8v*)(qptr + (long long)(n0 + row) * DIM_ + c8);
  }
  #pragma unroll
  for (int rep = 0; rep < 8; ++rep) {
    int L = rep * 256 + t, row = L >> 3, c8 = (L & 7) << 3;
    *(short8v*)&Klds[row][c8] =
        *(const short8v*)(kptr + (long long)row * DIM_ + c8);
  }
  #pragma unroll
  for (int rep = 0; rep < 4; ++rep) {
    int key0 = rep * 64 + (t >> 4) * 4, dh0 = (t & 15) * 4;
    short4v a0 = *(const short4v*)(vptr + (long long)(key0 + 0) * DIM_ + dh0);
    short4v a1 = *(const short4v*)(vptr + (long long)(key0 + 1) * DIM_ + dh0);
    short4v a2 = *(const short4v*)(vptr + (long long)(key0 + 2) * DIM_ + dh0);
    short4v a3 = *(const short4v*)(vptr + (long long)(key0 + 3) * DIM_ + dh0);
    short4v w0 = {a0[0], a1[0], a2[0], a3[0]};
    short4v w1 = {a0[1], a1[1], a2[1], a3[1]};
    short4v w2 = {a0[2], a1[2], a2[2], a3[2]};
    short4v w3 = {a0[3], a1[3], a2[3], a3[3]};
    *(short4v*)&Vt[dh0 + 0][key0] = w0;
    *(short4v*)&Vt[dh0 + 1][key0] = w1;
    *(short4v*)&Vt[dh0 + 2][key0] = w2;
    *(short4v*)&Vt[dh0 + 3][key0] = w3;
  }
  __syncthreads();

  short8v qa0 = *(const short8v*)&Qlds[16 * w + lr][qd * 8];
  short8v qa1 = *(const short8v*)&Qlds[16 * w + lr][32 + qd * 8];
  f32x4 sacc[16];
  #pragma unroll
  for (int nt = 0; nt < 16; ++nt) {
    short8v b0 = *(const short8v*)&Klds[nt * 16 + lr][qd * 8];
    short8v b1 = *(const short8v*)&Klds[nt * 16 + lr][32 + qd * 8];
    f32x4 acc = {};
    acc = __builtin_amdgcn_mfma_f32_16x16x32_bf16(qa0, b0, acc, 0, 0, 0);
    acc = __builtin_amdgcn_mfma_f32_16x16x32_bf16(qa1, b1, acc, 0, 0, 0);
    sacc[nt] = acc;
  }

  // softmax; normalize P in-place (no epilogue divide needed)
  #pragma unroll
  for (int r = 0; r < 4; ++r) {
    float m = -1e30f;
    #pragma unroll
    for (int nt = 0; nt < 16; ++nt) {
      sacc[nt][r] *= scale;
      m = fmaxf(m, sacc[nt][r]);
    }
    #pragma unroll
    for (int o = 1; o < 16; o <<= 1) m = fmaxf(m, __shfl_xor(m, o));
    float rs = 0.f;
    #pragma unroll
    for (int nt = 0; nt < 16; ++nt) {
      float e = __expf(sacc[nt][r] - m);
      sacc[nt][r] = e;
      rs += e;
    }
    #pragma unroll
    for (int o = 1; o < 16; o <<= 1) rs += __shfl_xor(rs, o);
    float inv = 1.f / rs;
    #pragma unroll
    for (int nt = 0; nt < 16; ++nt) sacc[nt][r] *= inv;
  }

  __syncthreads();  // Klds reads done; reuse as Plds
  #pragma unroll
  for (int nt = 0; nt < 16; ++nt)
    #pragma unroll
    for (int r = 0; r < 4; ++r)
      Plds[16 * w + qd * 4 + r][nt * 16 + lr] = f2bf(sacc[nt][r]);
  __syncthreads();

  // out = P @ V, swapped operands: thread owns query row 16w+lr,
  // dh cols n2*16 + qd*4 + 0..3 -> vectorized 8B stores
  f32x4 out[4] = {};
  #pragma unroll
  for (int k0 = 0; k0 < 8; ++k0) {
    short8v ap = *(const short8v*)&Plds[16 * w + lr][k0 * 32 + qd * 8];
    #pragma unroll
    for (int n2 = 0; n2 < 4; ++n2) {
      short8v bv = *(const short8v*)&Vt[n2 * 16 + lr][k0 * 32 + qd * 8];
      out[n2] =
          __builtin_amdgcn_mfma_f32_16x16x32_bf16(bv, ap, out[n2], 0, 0, 0);
    }
  }

  long long rowoff = (long long)(n0 + 16 * w + lr) * DIM_;
  #pragma unroll
  for (int n2 = 0; n2 < 4; ++n2) {
    short4v o = {f2bf(out[n2][0]), f2bf(out[n2][1]), f2bf(out[n2][2]),
                 f2bf(out[n2][3])};
    *(short4v*)(qptr + rowoff + n2 * 16 + qd * 4) = o;
  }
}

// ---------------- two-stage mean pool ----------------
__global__ __launch_bounds__(256) void pool1_k(const float* __restrict__ h,
                                               float* __restrict__ partial) {
  int stripe = blockIdx.x, b = blockIdx.y;
  int c4 = (threadIdx.x & 127) * 4, half = threadIdx.x >> 7;
  const float* base =
      h + ((long long)b * N_ + stripe * 128 + half * 64) * DIM_ + c4;
  float4 acc = {0.f, 0.f, 0.f, 0.f};
  for (int r = 0; r < 64; ++r) {
    float4 v = *(const float4*)(base + (long long)r * DIM_);
    acc.x += v.x; acc.y += v.y; acc.z += v.z; acc.w += v.w;
  }
  __shared__ float red[512];
  if (half == 1) *(float4*)&red[c4] = acc;
  __syncthreads();
  if (half == 0) {
    float4 o = *(const float4*)&red[c4];
    o.x += acc.x; o.y += acc.y; o.z += acc.z; o.w += acc.w;
    *(float4*)&partial[((long long)b * 16 + stripe) * DIM_ + c4] = o;
  }
}
__global__ __launch_bounds__(256) void pool2_k(const float* __restrict__ partial,
                                               float* __restrict__ pooled) {
  int b = blockIdx.x;
  for (int c = threadIdx.x; c < DIM_; c += 256) {
    float s = 0.f;
    for (int k = 0; k < 16; ++k) s += partial[((long long)b * 16 + k) * DIM_ + c];
    pooled[b * DIM_ + c] = s * (1.f / N_);
  }
}

// ---------------- final FC [16,512]@[512,2] ----------------
__global__ __launch_bounds__(64) void fc_k(const float* __restrict__ pooled,
                                           const float* __restrict__ fc_w,
                                           const float* __restrict__ fc_b,
                                           float* __restrict__ out) {
  int t = threadIdx.x;
  if (t < B_ * NCLS) {
    int b = t >> 1, c = t & 1;
    float s = fc_b[c];
    for (int d = 0; d < DIM_; ++d)
      s += pooled[b * DIM_ + d] * fc_w[d * NCLS + c];
    out[t] = s;
  }
}

extern "C" void kernel_launch(void* const* d_in, const int* in_sizes, int n_in,
                              void* d_out, int out_size, void* d_ws,
                              size_t ws_size, hipStream_t stream) {
  const float* x     = (const float*)d_in[0];
  const float* emb_w = (const float*)d_in[1];
  const float* emb_b = (const float*)d_in[2];
  const float* pos   = (const float*)d_in[3];
  const float* ln1_s = (const float*)d_in[4];
  const float* ln1_b = (const float*)d_in[5];
  const float* wq    = (const float*)d_in[6];
  const float* wk    = (const float*)d_in[7];
  const float* wv    = (const float*)d_in[8];
  const float* pk    = (const float*)d_in[9];
  const float* pv    = (const float*)d_in[10];
  const float* wo    = (const float*)d_in[11];
  const float* wo_b  = (const float*)d_in[12];
  const float* ln2_s = (const float*)d_in[13];
  const float* ln2_b = (const float*)d_in[14];
  const float* w1    = (const float*)d_in[15];
  const float* b1    = (const float*)d_in[16];
  const float* w2    = (const float*)d_in[17];
  const float* b2    = (const float*)d_in[18];
  const float* fc_w  = (const float*)d_in[19];
  const float* fc_b  = (const float*)d_in[20];
  float* out = (float*)d_out;

  // ---- workspace (~165 MB) ----
  char* P = (char*)d_ws;
  float* h = (float*)P;            P += (long long)B_ * N_ * DIM_ * 4;   // 67MB
  short* zc = (short*)P;                                                 // arena
  short* qc = zc + (long long)ACROWS * DIM_;
  short* ffnmid = zc;              P += (long long)2 * ACROWS * DIM_ * 2; // 33.5MB
  short* zcT = (short*)P;          P += (long long)ACB * DIM_ * N_ * 2;   // 16.8MB
  short* zp = (short*)P;
  short* kvp = zp + (long long)ACB * 2 * KLIN * DIM_;
  short* zln = zp;                 P += (long long)2 * ACB * 2 * KLIN * DIM_ * 2; // 8.4MB
  short* wq_t  = (short*)P;  P += (long long)DEPTH * DIM_ * DIM_ * 2;
  short* wkv_t = (short*)P;  P += (long long)DEPTH * 2 * DIM_ * DIM_ * 2;
  short* wo_t  = (short*)P;  P += (long long)DEPTH * DIM_ * DIM_ * 2;
  short* w1_t  = (short*)P;  P += (long long)DEPTH * 4 * DIM_ * DIM_ * 2;
  short* w2_t  = (short*)P;  P += (long long)DEPTH * 4 * DIM_ * DIM_ * 2;
  short* pkv_t = (short*)P;  P += (long long)DEPTH * 2 * KLIN * N_ * 2;
  short* emb_wt = (short*)P; P += (long long)DIM_ * INDIM * 2;
  short* x_bf  = (short*)P;  P += (long long)B_ * N_ * INDIM * 2;
  float* partial = (float*)P; P += (long long)B_ * 16 * DIM_ * 4;
  float* pooled  = (float*)P;

  const float scale = 0.125f;
  const long long WQS = (long long)DIM_ * DIM_;        // 262144
  const long long KVS = (long long)2 * KLIN * DIM_;    // 262144

  // ---- converts ----
  auto tconv = [&](const float* s, short* d, int R, int C, long long ss,
                   long long sd, int b) {
    hipLaunchKernelGGL(tconv_k, dim3(C / 32, R / 32, b), dim3(256), 0, stream,
                       s, d, R, C, ss, sd);
  };
  tconv(wq, wq_t, DIM_, DIM_, WQS, WQS, DEPTH);
  tconv(wk, wkv_t, DIM_, DIM_, WQS, 2 * WQS, DEPTH);
  tconv(wv, wkv_t + WQS, DIM_, DIM_, WQS, 2 * WQS, DEPTH);
  tconv(wo, wo_t, DIM_, DIM_, WQS, WQS, DEPTH);
  tconv(w1, w1_t, DIM_, 4 * DIM_, 4 * WQS, 4 * WQS, DEPTH);
  tconv(w2, w2_t, 4 * DIM_, DIM_, 4 * WQS, 4 * WQS, DEPTH);
  tconv(pk, pkv_t, N_, KLIN, (long long)N_ * KLIN, (long long)2 * KLIN * N_, DEPTH);
  tconv(pv, pkv_t + (long long)KLIN * N_, N_, KLIN, (long long)N_ * KLIN,
        (long long)2 * KLIN * N_, DEPTH);
  tconv(emb_w, emb_wt, INDIM, DIM_, 0, 0, 1);
  hipLaunchKernelGGL(cconv_k, dim3((B_ * N_ * INDIM / 8 + 255) / 256),
                     dim3(256), 0, stream, x, x_bf, B_ * N_ * INDIM / 8);

  // ---- embedding: h = x@emb_w + emb_b + pos ----
  hipLaunchKernelGGL((gemm_bf<0, 128>), dim3(DIM_ / 128, B_ * N_ / 128, 1),
                     dim3(256), 0, stream, x_bf, emb_wt, emb_b, pos, (void*)h,
                     B_ * N_, DIM_, INDIM, INDIM, INDIM, DIM_, 0LL, 0LL, 0LL,
                     0, 0LL, 2, N_);

  for (int i = 0; i < DEPTH; ++i) {
    const short* wq_i  = wq_t + i * WQS;
    const short* wkv_i = wkv_t + i * 2 * WQS;
    const short* wo_i  = wo_t + i * WQS;
    const short* w1_i  = w1_t + (long long)i * 4 * WQS;
    const short* w2_i  = w2_t + (long long)i * 4 * WQS;
    const short* pkv_i = pkv_t + (long long)i * 2 * KLIN * N_;

    // ---- attention, 2 chunks of 8 batches ----
    for (int c = 0; c < B_ / ACB; ++c) {
      float* hc = h + (long long)c * ACROWS * DIM_;
      hipLaunchKernelGGL(ln_k, dim3(ACROWS / 4), dim3(256), 0, stream, hc,
                         ln1_s + i * DIM_, ln1_b + i * DIM_, zc);
      // zcT[b] = zc[b]^T
      hipLaunchKernelGGL(tpose_k, dim3(DIM_ / 64, N_ / 64, ACB), dim3(256), 0,
                         stream, zc, zcT, N_, DIM_, (long long)N_ * DIM_,
                         (long long)DIM_ * N_);
      // qc = zc @ wq
      hipLaunchKernelGGL((gemm_bf<1, 128>), dim3(DIM_ / 128, ACROWS / 128, 1),
                         dim3(256), 0, stream, zc, wq_i, nullptr, nullptr,
                         (void*)qc, ACROWS, DIM_, DIM_, DIM_, DIM_, DIM_, 0LL,
                         0LL, 0LL, 0, 0LL, 0, 0);
      // zp[b] = pkv^T @ zc[b]  (Bt = zcT[b])
      hipLaunchKernelGGL((gemm_bf<1, 64>), dim3(DIM_ / 128, 512 / 64, ACB),
                         dim3(256), 0, stream, pkv_i, zcT, nullptr, nullptr,
                         (void*)zp, 512, DIM_, N_, N_, N_, DIM_, 0LL,
                         (long long)DIM_ * N_, KVS, 0, 0LL, 0, 0);
      // kvp[b] = zp[b] @ [wk | wv]  (B dual by output row)
      hipLaunchKernelGGL((gemm_bf<1, 64>), dim3(DIM_ / 128, 512 / 64, ACB),
                         dim3(256), 0, stream, zp, wkv_i, nullptr, nullptr,
                         (void*)kvp, 512, DIM_, DIM_, DIM_, DIM_, DIM_, KVS,
                         0LL, KVS, KLIN, (long long)WQS, 0, 0);
      // fused attention in-place on qc
      hipLaunchKernelGGL(attn_k, dim3(N_ / 64, HEADS, ACB), dim3(256), 0,
                         stream, qc, kvp, scale);
      // h += qc @ wo + wo_b
      hipLaunchKernelGGL((gemm_bf<0, 128>), dim3(DIM_ / 128, ACROWS / 128, 1),
                         dim3(256), 0, stream, qc, wo_i, wo_b + i * DIM_,
                         hc, (void*)hc, ACROWS, DIM_, DIM_, DIM_, DIM_, DIM_,
                         0LL, 0LL, 0LL, 0, 0LL, 2, 0);
    }

    // ---- FFN, 4 chunks of 8192 rows ----
    for (int r0 = 0; r0 < B_ * N_; r0 += FROWS) {
      float* hr = h + (long long)r0 * DIM_;
      hipLaunchKernelGGL(ln_k, dim3(FROWS / 4), dim3(256), 0, stream, hr,
                         ln2_s + i * DIM_, ln2_b + i * DIM_, zln);
      // ffnmid = gelu(zln @ w1 + b1)
      hipLaunchKernelGGL((gemm_bf<1, 128>), dim3(4 * DIM_ / 128, FROWS / 128, 1),
                         dim3(256), 0, stream, zln, w1_i,
                         b1 + (long long)i * 4 * DIM_, nullptr, (void*)ffnmid,
                         FROWS, 4 * DIM_, DIM_, DIM_, DIM_, 4 * DIM_, 0LL, 0LL,
                         0LL, 0, 0LL, 3, 0);
      // h += ffnmid @ w2 + b2   (BM=64 -> 512 blocks)
      hipLaunchKernelGGL((gemm_bf<0, 64>), dim3(DIM_ / 128, FROWS / 64, 1),
                         dim3(256), 0, stream, ffnmid, w2_i,
                         b2 + (long long)i * DIM_, hr, (void*)hr, FROWS, DIM_,
                         4 * DIM_, 4 * DIM_, 4 * DIM_, DIM_, 0LL, 0LL, 0LL, 0,
                         0LL, 2, 0);
    }
  }

  hipLaunchKernelGGL(pool1_k, dim3(16, B_), dim3(256), 0, stream, h, partial);
  hipLaunchKernelGGL(pool2_k, dim3(B_), dim3(256), 0, stream, partial, pooled);
  hipLaunchKernelGGL(fc_k, dim3(1), dim3(64), 0, stream, pooled, fc_w, fc_b,
                     out);
}

// Round 10
// 2245.607 us; speedup vs baseline: 9.4717x; 1.2177x over previous
//
#include <hip/hip_runtime.h>
#include <math.h>

// ---------------- constants ----------------
#define B_    16
#define N_    2048
#define INDIM 64
#define DIM_  512
#define HEADS 8
#define DEPTH 4
#define KLIN  256
#define NCLS  2
#define DH    64
#define EPSF  1e-5f

typedef __attribute__((ext_vector_type(8))) short short8v;
typedef __attribute__((ext_vector_type(4))) short short4v;
typedef __attribute__((ext_vector_type(4))) float f32x4;

// fp32 -> bf16 round-to-nearest-even (finite inputs)
__device__ __forceinline__ short f2bf(float f) {
  unsigned u = __float_as_uint(f);
  u += 0x7FFFu + ((u >> 16) & 1u);
  return (short)(u >> 16);
}

__device__ __forceinline__ float wave_sum(float v) {
  #pragma unroll
  for (int o = 32; o > 0; o >>= 1) v += __shfl_xor(v, o);
  return v;
}

// tanh-GELU via sigmoid identity (~7 VALU vs ~45+ libm tanhf)
__device__ __forceinline__ float gelu_tanh(float x) {
  float u = x * (1.5957691216057308f + 0.07135481627f * x * x);
  return x / (1.f + __expf(-u));
}

// async global->LDS, 16B per lane; LDS dest = wave-uniform base + lane*16
__device__ __forceinline__ void gl_lds16(const short* g, short* l) {
  __builtin_amdgcn_global_load_lds(
      (const __attribute__((address_space(1))) unsigned int*)g,
      (__attribute__((address_space(3))) unsigned int*)l, 16, 0, 0);
}

// ---------------- converts (once per launch) ----------------
__global__ __launch_bounds__(256) void tconv_k(const float* __restrict__ src,
                                               short* __restrict__ dst, int R,
                                               int C, long long sSrc,
                                               long long sDst) {
  __shared__ float tile[32][33];
  int c0 = blockIdx.x * 32, r0 = blockIdx.y * 32;
  src += (long long)blockIdx.z * sSrc;
  dst += (long long)blockIdx.z * sDst;
  int tx = threadIdx.x & 31, ty = threadIdx.x >> 5;
  #pragma unroll
  for (int rr = 0; rr < 4; ++rr)
    tile[ty + rr * 8][tx] = src[(long long)(r0 + ty + rr * 8) * C + c0 + tx];
  __syncthreads();
  #pragma unroll
  for (int rr = 0; rr < 4; ++rr) {
    int c = ty + rr * 8;
    dst[(long long)(c0 + c) * R + r0 + tx] = f2bf(tile[tx][c]);
  }
}

__global__ __launch_bounds__(256) void cconv_k(const float* __restrict__ src,
                                               short* __restrict__ dst,
                                               int n8) {
  int i = blockIdx.x * 256 + threadIdx.x;
  if (i < n8) {
    const float* s = src + (long long)i * 8;
    float4 a = *(const float4*)s, c = *(const float4*)(s + 4);
    short8v o = {f2bf(a.x), f2bf(a.y), f2bf(a.z), f2bf(a.w),
                 f2bf(c.x), f2bf(c.y), f2bf(c.z), f2bf(c.w)};
    *(short8v*)(dst + (long long)i * 8) = o;
  }
}

// ---------------- bf16 tile transpose: [R][C] -> [C][R], batched ----------
__global__ __launch_bounds__(256) void tpose_k(const short* __restrict__ src,
                                               short* __restrict__ dst, int R,
                                               int C, long long sSrc,
                                               long long sDst) {
  __shared__ __align__(16) short tile[64][72];
  int c0 = blockIdx.x * 64, r0 = blockIdx.y * 64;
  src += (long long)blockIdx.z * sSrc;
  dst += (long long)blockIdx.z * sDst;
  int t = threadIdx.x;
  #pragma unroll
  for (int rep = 0; rep < 2; ++rep) {
    int row = rep * 32 + (t >> 3), c8 = (t & 7) * 8;
    *(short8v*)&tile[row][c8] =
        *(const short8v*)(src + (long long)(r0 + row) * C + c0 + c8);
  }
  __syncthreads();
  #pragma unroll
  for (int rep = 0; rep < 2; ++rep) {
    int c = rep * 32 + (t >> 3), r8 = (t & 7) * 8;
    short8v o;
    #pragma unroll
    for (int j = 0; j < 8; ++j) o[j] = tile[r8 + j][c];
    *(short8v*)(dst + (long long)(c0 + c) * R + r0 + r8) = o;
  }
}

// ---------------- LayerNorm: fp32 in, bf16 out ----------------
__global__ __launch_bounds__(256) void ln_k(const float* __restrict__ h,
                                            const float* __restrict__ s,
                                            const float* __restrict__ b,
                                            short* __restrict__ z) {
  int lane = threadIdx.x & 63;
  long long row = ((long long)blockIdx.x << 2) + (threadIdx.x >> 6);
  const float* hr = h + row * DIM_ + lane * 8;
  float4 a = *(const float4*)hr;
  float4 c = *(const float4*)(hr + 4);
  float sum = a.x + a.y + a.z + a.w + c.x + c.y + c.z + c.w;
  sum = wave_sum(sum);
  float mu = sum * (1.f / DIM_);
  float d[8] = {a.x - mu, a.y - mu, a.z - mu, a.w - mu,
                c.x - mu, c.y - mu, c.z - mu, c.w - mu};
  float vs = 0.f;
  #pragma unroll
  for (int i = 0; i < 8; ++i) vs += d[i] * d[i];
  vs = wave_sum(vs);
  float rstd = rsqrtf(vs * (1.f / DIM_) + EPSF);
  const float* sp = s + lane * 8;
  const float* bp = b + lane * 8;
  float4 s0 = *(const float4*)sp, s1 = *(const float4*)(sp + 4);
  float4 b0 = *(const float4*)bp, b1 = *(const float4*)(bp + 4);
  float o[8];
  o[0] = d[0] * rstd * s0.x + b0.x; o[1] = d[1] * rstd * s0.y + b0.y;
  o[2] = d[2] * rstd * s0.z + b0.z; o[3] = d[3] * rstd * s0.w + b0.w;
  o[4] = d[4] * rstd * s1.x + b1.x; o[5] = d[5] * rstd * s1.y + b1.y;
  o[6] = d[6] * rstd * s1.z + b1.z; o[7] = d[7] * rstd * s1.w + b1.w;
  short8v ov = {f2bf(o[0]), f2bf(o[1]), f2bf(o[2]), f2bf(o[3]),
                f2bf(o[4]), f2bf(o[5]), f2bf(o[6]), f2bf(o[7])};
  *(short8v*)(z + row * DIM_ + lane * 8) = ov;
}

// ---------------- bf16 MFMA GEMM, BMxBN tile, BK=64 ----------------
// C[m,n] = sum_k A[m][k] * Bt[n][k] (+ epilogue). Both operands k-major.
// 4 waves in 2x2; wave tile = (BM/2) x (BN/2). Staging via global_load_lds
// 16B/lane with XOR-swizzled source chunks (conflict-free unpadded LDS).
// Swapped MFMA operands: acc regs hold 4 consecutive n-cols -> vector epilogue.
// epi: 0 none; 1 +bias; 2 +bias+resid[(m%resMod)*ldc+n] (fp32); 3 gelu(+bias)
template <int OUTBF, int BM, int BN>
__global__ __launch_bounds__(256) void gemm_bf(
    const short* __restrict__ A, const short* __restrict__ Bsrc,
    const float* __restrict__ bias, const float* __restrict__ resid,
    void* __restrict__ Cv, int M, int N, int K, int lda, int ldb, int ldc,
    long long sAb, long long sBb, long long sCb, int dualThresh,
    long long dualOff, int epi, int resMod) {
  constexpr int MT = BM / 32;   // frag rows per wave
  constexpr int NT = BN / 32;   // frag cols per wave
  int zz = blockIdx.z;
  A += (long long)zz * sAb;
  Bsrc += (long long)zz * sBb;
  int bm = blockIdx.y * BM, bn = blockIdx.x * BN;
  if (dualThresh && bm >= dualThresh) Bsrc += dualOff;
  int t = threadIdx.x;
  __shared__ __align__(16) short Alds[BM * 64];
  __shared__ __align__(16) short Blds[BN * 64];
  int lane = t & 63, wid = t >> 6;
  int lr = lane & 15, q = lane >> 4;
  int wm = (wid >> 1) * (BM / 2), wn = (wid & 1) * (BN / 2);
  int rl = lane >> 3;          // row within 8-row group
  int cs = (lane & 7) ^ rl;    // swizzled source chunk
  f32x4 acc[MT][NT] = {};

  for (int k0 = 0; k0 < K; k0 += 64) {
    #pragma unroll
    for (int i = 0; i < BM / 32; ++i) {
      int rb = i * 32 + wid * 8;
      gl_lds16(A + (long long)(bm + rb + rl) * lda + k0 + cs * 8,
               Alds + rb * 64);
    }
    #pragma unroll
    for (int i = 0; i < BN / 32; ++i) {
      int rb = i * 32 + wid * 8;
      gl_lds16(Bsrc + (long long)(bn + rb + rl) * ldb + k0 + cs * 8,
               Blds + rb * 64);
    }
    __syncthreads();
    #pragma unroll
    for (int kk2 = 0; kk2 < 2; ++kk2) {
      short8v af[MT], bfr[NT];
      #pragma unroll
      for (int mi = 0; mi < MT; ++mi)
        af[mi] = *(const short8v*)&Alds[(wm + mi * 16 + lr) * 64 +
                                        (((kk2 << 2) | q) ^ (lr & 7)) * 8];
      #pragma unroll
      for (int ni = 0; ni < NT; ++ni)
        bfr[ni] = *(const short8v*)&Blds[(wn + ni * 16 + lr) * 64 +
                                         (((kk2 << 2) | q) ^ (lr & 7)) * 8];
      #pragma unroll
      for (int mi = 0; mi < MT; ++mi)
        #pragma unroll
        for (int ni = 0; ni < NT; ++ni)
          acc[mi][ni] = __builtin_amdgcn_mfma_f32_16x16x32_bf16(
              bfr[ni], af[mi], acc[mi][ni], 0, 0, 0);  // swapped: cols in regs
    }
    __syncthreads();
  }

  #pragma unroll
  for (int mi = 0; mi < MT; ++mi) {
    int m = bm + wm + mi * 16 + lr;
    int rm = (epi == 2 && resMod) ? (m % resMod) : m;
    #pragma unroll
    for (int ni = 0; ni < NT; ++ni) {
      int nb = bn + wn + ni * 16 + q * 4;
      f32x4 v = acc[mi][ni];
      if (epi >= 1) {
        float4 bb = *(const float4*)(bias + nb);
        v[0] += bb.x; v[1] += bb.y; v[2] += bb.z; v[3] += bb.w;
      }
      if (epi == 2) {
        float4 rr = *(const float4*)(resid + (long long)rm * ldc + nb);
        v[0] += rr.x; v[1] += rr.y; v[2] += rr.z; v[3] += rr.w;
      } else if (epi == 3) {
        v[0] = gelu_tanh(v[0]); v[1] = gelu_tanh(v[1]);
        v[2] = gelu_tanh(v[2]); v[3] = gelu_tanh(v[3]);
      }
      long long base = (long long)zz * sCb + (long long)m * ldc + nb;
      if (OUTBF) {
        short4v o = {f2bf(v[0]), f2bf(v[1]), f2bf(v[2]), f2bf(v[3])};
        *(short4v*)((short*)Cv + base) = o;
      } else {
        *(float4*)((float*)Cv + base) = make_float4(v[0], v[1], v[2], v[3]);
      }
    }
  }
}

// ---------------- fused Linformer attention, bf16 MFMA ----------------
__global__ __launch_bounds__(256) void attn_k(short* __restrict__ qc,
                                              const short* __restrict__ kvp,
                                              float scale) {
  int n0 = blockIdx.x * 64, hh = blockIdx.y, b = blockIdx.z;
  int t = threadIdx.x;
  int lane = t & 63, w = t >> 6;
  int lr = lane & 15, qd = lane >> 4;

  __shared__ __align__(16) short Qlds[64][72];
  __shared__ __align__(16) short Kbuf[256 * 72];  // K, then aliased as P
  __shared__ __align__(16) short Vt[64][264];
  auto Klds = (short(*)[72])Kbuf;
  auto Plds = (short(*)[264])Kbuf;

  short* qptr = qc + (long long)b * N_ * DIM_ + hh * DH;
  const short* kptr = kvp + (long long)b * 2 * KLIN * DIM_ + hh * DH;
  const short* vptr = kptr + (long long)KLIN * DIM_;

  #pragma unroll
  for (int rep = 0; rep < 2; ++rep) {
    int L = rep * 256 + t, row = L >> 3, c8 = (L & 7) << 3;
    *(short8v*)&Qlds[row][c8] =
        *(const short8v*)(qptr + (long long)(n0 + row) * DIM_ + c8);
  }
  #pragma unroll
  for (int rep = 0; rep < 8; ++rep) {
    int L = rep * 256 + t, row = L >> 3, c8 = (L & 7) << 3;
    *(short8v*)&Klds[row][c8] =
        *(const short8v*)(kptr + (long long)row * DIM_ + c8);
  }
  #pragma unroll
  for (int rep = 0; rep < 4; ++rep) {
    int key0 = rep * 64 + (t >> 4) * 4, dh0 = (t & 15) * 4;
    short4v a0 = *(const short4v*)(vptr + (long long)(key0 + 0) * DIM_ + dh0);
    short4v a1 = *(const short4v*)(vptr + (long long)(key0 + 1) * DIM_ + dh0);
    short4v a2 = *(const short4v*)(vptr + (long long)(key0 + 2) * DIM_ + dh0);
    short4v a3 = *(const short4v*)(vptr + (long long)(key0 + 3) * DIM_ + dh0);
    short4v w0 = {a0[0], a1[0], a2[0], a3[0]};
    short4v w1 = {a0[1], a1[1], a2[1], a3[1]};
    short4v w2 = {a0[2], a1[2], a2[2], a3[2]};
    short4v w3 = {a0[3], a1[3], a2[3], a3[3]};
    *(short4v*)&Vt[dh0 + 0][key0] = w0;
    *(short4v*)&Vt[dh0 + 1][key0] = w1;
    *(short4v*)&Vt[dh0 + 2][key0] = w2;
    *(short4v*)&Vt[dh0 + 3][key0] = w3;
  }
  __syncthreads();

  short8v qa0 = *(const short8v*)&Qlds[16 * w + lr][qd * 8];
  short8v qa1 = *(const short8v*)&Qlds[16 * w + lr][32 + qd * 8];
  f32x4 sacc[16];
  #pragma unroll
  for (int nt = 0; nt < 16; ++nt) {
    short8v b0 = *(const short8v*)&Klds[nt * 16 + lr][qd * 8];
    short8v b1 = *(const short8v*)&Klds[nt * 16 + lr][32 + qd * 8];
    f32x4 acc = {};
    acc = __builtin_amdgcn_mfma_f32_16x16x32_bf16(qa0, b0, acc, 0, 0, 0);
    acc = __builtin_amdgcn_mfma_f32_16x16x32_bf16(qa1, b1, acc, 0, 0, 0);
    sacc[nt] = acc;
  }

  // softmax; normalize P in-place
  #pragma unroll
  for (int r = 0; r < 4; ++r) {
    float m = -1e30f;
    #pragma unroll
    for (int nt = 0; nt < 16; ++nt) {
      sacc[nt][r] *= scale;
      m = fmaxf(m, sacc[nt][r]);
    }
    #pragma unroll
    for (int o = 1; o < 16; o <<= 1) m = fmaxf(m, __shfl_xor(m, o));
    float rs = 0.f;
    #pragma unroll
    for (int nt = 0; nt < 16; ++nt) {
      float e = __expf(sacc[nt][r] - m);
      sacc[nt][r] = e;
      rs += e;
    }
    #pragma unroll
    for (int o = 1; o < 16; o <<= 1) rs += __shfl_xor(rs, o);
    float inv = 1.f / rs;
    #pragma unroll
    for (int nt = 0; nt < 16; ++nt) sacc[nt][r] *= inv;
  }

  __syncthreads();  // Klds reads done; reuse as Plds
  #pragma unroll
  for (int nt = 0; nt < 16; ++nt)
    #pragma unroll
    for (int r = 0; r < 4; ++r)
      Plds[16 * w + qd * 4 + r][nt * 16 + lr] = f2bf(sacc[nt][r]);
  __syncthreads();

  f32x4 out[4] = {};
  #pragma unroll
  for (int k0 = 0; k0 < 8; ++k0) {
    short8v ap = *(const short8v*)&Plds[16 * w + lr][k0 * 32 + qd * 8];
    #pragma unroll
    for (int n2 = 0; n2 < 4; ++n2) {
      short8v bv = *(const short8v*)&Vt[n2 * 16 + lr][k0 * 32 + qd * 8];
      out[n2] =
          __builtin_amdgcn_mfma_f32_16x16x32_bf16(bv, ap, out[n2], 0, 0, 0);
    }
  }

  long long rowoff = (long long)(n0 + 16 * w + lr) * DIM_;
  #pragma unroll
  for (int n2 = 0; n2 < 4; ++n2) {
    short4v o = {f2bf(out[n2][0]), f2bf(out[n2][1]), f2bf(out[n2][2]),
                 f2bf(out[n2][3])};
    *(short4v*)(qptr + rowoff + n2 * 16 + qd * 4) = o;
  }
}

// ---------------- two-stage mean pool ----------------
__global__ __launch_bounds__(256) void pool1_k(const float* __restrict__ h,
                                               float* __restrict__ partial) {
  int stripe = blockIdx.x, b = blockIdx.y;
  int c4 = (threadIdx.x & 127) * 4, half = threadIdx.x >> 7;
  const float* base =
      h + ((long long)b * N_ + stripe * 128 + half * 64) * DIM_ + c4;
  float4 acc = {0.f, 0.f, 0.f, 0.f};
  for (int r = 0; r < 64; ++r) {
    float4 v = *(const float4*)(base + (long long)r * DIM_);
    acc.x += v.x; acc.y += v.y; acc.z += v.z; acc.w += v.w;
  }
  __shared__ float red[512];
  if (half == 1) *(float4*)&red[c4] = acc;
  __syncthreads();
  if (half == 0) {
    float4 o = *(const float4*)&red[c4];
    o.x += acc.x; o.y += acc.y; o.z += acc.z; o.w += acc.w;
    *(float4*)&partial[((long long)b * 16 + stripe) * DIM_ + c4] = o;
  }
}
__global__ __launch_bounds__(256) void pool2_k(const float* __restrict__ partial,
                                               float* __restrict__ pooled) {
  int b = blockIdx.x;
  for (int c = threadIdx.x; c < DIM_; c += 256) {
    float s = 0.f;
    for (int k = 0; k < 16; ++k) s += partial[((long long)b * 16 + k) * DIM_ + c];
    pooled[b * DIM_ + c] = s * (1.f / N_);
  }
}

// ---------------- final FC [16,512]@[512,2] ----------------
__global__ __launch_bounds__(64) void fc_k(const float* __restrict__ pooled,
                                           const float* __restrict__ fc_w,
                                           const float* __restrict__ fc_b,
                                           float* __restrict__ out) {
  int t = threadIdx.x;
  if (t < B_ * NCLS) {
    int b = t >> 1, c = t & 1;
    float s = fc_b[c];
    for (int d = 0; d < DIM_; ++d)
      s += pooled[b * DIM_ + d] * fc_w[d * NCLS + c];
    out[t] = s;
  }
}

extern "C" void kernel_launch(void* const* d_in, const int* in_sizes, int n_in,
                              void* d_out, int out_size, void* d_ws,
                              size_t ws_size, hipStream_t stream) {
  const float* x     = (const float*)d_in[0];
  const float* emb_w = (const float*)d_in[1];
  const float* emb_b = (const float*)d_in[2];
  const float* pos   = (const float*)d_in[3];
  const float* ln1_s = (const float*)d_in[4];
  const float* ln1_b = (const float*)d_in[5];
  const float* wq    = (const float*)d_in[6];
  const float* wk    = (const float*)d_in[7];
  const float* wv    = (const float*)d_in[8];
  const float* pk    = (const float*)d_in[9];
  const float* pv    = (const float*)d_in[10];
  const float* wo    = (const float*)d_in[11];
  const float* wo_b  = (const float*)d_in[12];
  const float* ln2_s = (const float*)d_in[13];
  const float* ln2_b = (const float*)d_in[14];
  const float* w1    = (const float*)d_in[15];
  const float* b1    = (const float*)d_in[16];
  const float* w2    = (const float*)d_in[17];
  const float* b2    = (const float*)d_in[18];
  const float* fc_w  = (const float*)d_in[19];
  const float* fc_b  = (const float*)d_in[20];
  float* out = (float*)d_out;

  // ---- adaptive chunking: big path if workspace allows (~221MB), else the
  // proven ~162MB layout. Branch depends only on ws_size (constant) ----
  const bool big = ws_size >= (size_t)230 * 1024 * 1024;
  const int acb = big ? 16 : 8;          // batches per attention chunk
  const long long acrows = (long long)acb * N_;
  const int frows = big ? 16384 : 8192;  // rows per FFN chunk

  char* P = (char*)d_ws;
  float* h = (float*)P;            P += (long long)B_ * N_ * DIM_ * 4;   // 67MB
  short* zc = (short*)P;           P += acrows * DIM_ * 2;
  short* qc = (short*)P;           P += acrows * DIM_ * 2;
  short* ffnmid = zc;              // frows*4*DIM == 2*acrows*DIM exactly
  short* zcT = (short*)P;          P += acrows * DIM_ * 2;   // also zln (FFN)
  short* zln = zcT;
  short* zp = (short*)P;           P += (long long)acb * 2 * KLIN * DIM_ * 2;
  short* kvp = (short*)P;          P += (long long)acb * 2 * KLIN * DIM_ * 2;
  short* wq_t  = (short*)P;  P += (long long)DEPTH * DIM_ * DIM_ * 2;
  short* wkv_t = (short*)P;  P += (long long)DEPTH * 2 * DIM_ * DIM_ * 2;
  short* wo_t  = (short*)P;  P += (long long)DEPTH * DIM_ * DIM_ * 2;
  short* w1_t  = (short*)P;  P += (long long)DEPTH * 4 * DIM_ * DIM_ * 2;
  short* w2_t  = (short*)P;  P += (long long)DEPTH * 4 * DIM_ * DIM_ * 2;
  short* pkv_t = (short*)P;  P += (long long)DEPTH * 2 * KLIN * N_ * 2;
  short* emb_wt = (short*)P; P += (long long)DIM_ * INDIM * 2;
  short* x_bf  = (short*)P;  P += (long long)B_ * N_ * INDIM * 2;
  float* partial = (float*)P; P += (long long)B_ * 16 * DIM_ * 4;
  float* pooled  = (float*)P;

  const float scale = 0.125f;
  const long long WQS = (long long)DIM_ * DIM_;        // 262144
  const long long KVS = (long long)2 * KLIN * DIM_;    // 262144

  // ---- converts ----
  auto tconv = [&](const float* s, short* d, int R, int C, long long ss,
                   long long sd, int b) {
    hipLaunchKernelGGL(tconv_k, dim3(C / 32, R / 32, b), dim3(256), 0, stream,
                       s, d, R, C, ss, sd);
  };
  tconv(wq, wq_t, DIM_, DIM_, WQS, WQS, DEPTH);
  tconv(wk, wkv_t, DIM_, DIM_, WQS, 2 * WQS, DEPTH);
  tconv(wv, wkv_t + WQS, DIM_, DIM_, WQS, 2 * WQS, DEPTH);
  tconv(wo, wo_t, DIM_, DIM_, WQS, WQS, DEPTH);
  tconv(w1, w1_t, DIM_, 4 * DIM_, 4 * WQS, 4 * WQS, DEPTH);
  tconv(w2, w2_t, 4 * DIM_, DIM_, 4 * WQS, 4 * WQS, DEPTH);
  tconv(pk, pkv_t, N_, KLIN, (long long)N_ * KLIN, (long long)2 * KLIN * N_, DEPTH);
  tconv(pv, pkv_t + (long long)KLIN * N_, N_, KLIN, (long long)N_ * KLIN,
        (long long)2 * KLIN * N_, DEPTH);
  tconv(emb_w, emb_wt, INDIM, DIM_, 0, 0, 1);
  hipLaunchKernelGGL(cconv_k, dim3((B_ * N_ * INDIM / 8 + 255) / 256),
                     dim3(256), 0, stream, x, x_bf, B_ * N_ * INDIM / 8);

  // ---- embedding: h = x@emb_w + emb_b + pos ----
  hipLaunchKernelGGL((gemm_bf<0, 128, 128>), dim3(DIM_ / 128, B_ * N_ / 128, 1),
                     dim3(256), 0, stream, x_bf, emb_wt, emb_b, pos, (void*)h,
                     B_ * N_, DIM_, INDIM, INDIM, INDIM, DIM_, 0LL, 0LL, 0LL,
                     0, 0LL, 2, N_);

  for (int i = 0; i < DEPTH; ++i) {
    const short* wq_i  = wq_t + i * WQS;
    const short* wkv_i = wkv_t + i * 2 * WQS;
    const short* wo_i  = wo_t + i * WQS;
    const short* w1_i  = w1_t + (long long)i * 4 * WQS;
    const short* w2_i  = w2_t + (long long)i * 4 * WQS;
    const short* pkv_i = pkv_t + (long long)i * 2 * KLIN * N_;

    // ---- attention, B_/acb chunks ----
    for (int c = 0; c < B_ / acb; ++c) {
      float* hc = h + (long long)c * acrows * DIM_;
      hipLaunchKernelGGL(ln_k, dim3(acrows / 4), dim3(256), 0, stream, hc,
                         ln1_s + i * DIM_, ln1_b + i * DIM_, zc);
      // zcT[b] = zc[b]^T
      hipLaunchKernelGGL(tpose_k, dim3(DIM_ / 64, N_ / 64, acb), dim3(256), 0,
                         stream, zc, zcT, N_, DIM_, (long long)N_ * DIM_,
                         (long long)DIM_ * N_);
      // qc = zc @ wq  (BN=256: 2 col-tiles, halves A overfetch)
      hipLaunchKernelGGL((gemm_bf<1, 64, 256>), dim3(DIM_ / 256, acrows / 64, 1),
                         dim3(256), 0, stream, zc, wq_i, nullptr, nullptr,
                         (void*)qc, (int)acrows, DIM_, DIM_, DIM_, DIM_, DIM_,
                         0LL, 0LL, 0LL, 0, 0LL, 0, 0);
      // zp[b] = pkv^T @ zc[b]  (Bt = zcT[b])
      hipLaunchKernelGGL((gemm_bf<1, 64, 128>), dim3(DIM_ / 128, 512 / 64, acb),
                         dim3(256), 0, stream, pkv_i, zcT, nullptr, nullptr,
                         (void*)zp, 512, DIM_, N_, N_, N_, DIM_, 0LL,
                         (long long)DIM_ * N_, KVS, 0, 0LL, 0, 0);
      // kvp[b] = zp[b] @ [wk | wv]  (B dual by output row)
      hipLaunchKernelGGL((gemm_bf<1, 64, 128>), dim3(DIM_ / 128, 512 / 64, acb),
                         dim3(256), 0, stream, zp, wkv_i, nullptr, nullptr,
                         (void*)kvp, 512, DIM_, DIM_, DIM_, DIM_, DIM_, KVS,
                         0LL, KVS, KLIN, (long long)WQS, 0, 0);
      // fused attention in-place on qc
      hipLaunchKernelGGL(attn_k, dim3(N_ / 64, HEADS, acb), dim3(256), 0,
                         stream, qc, kvp, scale);
      // h += qc @ wo + wo_b  (BN=256)
      hipLaunchKernelGGL((gemm_bf<0, 64, 256>), dim3(DIM_ / 256, acrows / 64, 1),
                         dim3(256), 0, stream, qc, wo_i, wo_b + i * DIM_,
                         hc, (void*)hc, (int)acrows, DIM_, DIM_, DIM_, DIM_,
                         DIM_, 0LL, 0LL, 0LL, 0, 0LL, 2, 0);
    }

    // ---- FFN, (B_*N_)/frows chunks ----
    for (int r0 = 0; r0 < B_ * N_; r0 += frows) {
      float* hr = h + (long long)r0 * DIM_;
      hipLaunchKernelGGL(ln_k, dim3(frows / 4), dim3(256), 0, stream, hr,
                         ln2_s + i * DIM_, ln2_b + i * DIM_, zln);
      // ffnmid = gelu(zln @ w1 + b1)
      hipLaunchKernelGGL((gemm_bf<1, 128, 128>),
                         dim3(4 * DIM_ / 128, frows / 128, 1), dim3(256), 0,
                         stream, zln, w1_i, b1 + (long long)i * 4 * DIM_,
                         nullptr, (void*)ffnmid, frows, 4 * DIM_, DIM_, DIM_,
                         DIM_, 4 * DIM_, 0LL, 0LL, 0LL, 0, 0LL, 3, 0);
      // h += ffnmid @ w2 + b2  (BN=256: halves ffnmid overfetch)
      hipLaunchKernelGGL((gemm_bf<0, 64, 256>), dim3(DIM_ / 256, frows / 64, 1),
                         dim3(256), 0, stream, ffnmid, w2_i,
                         b2 + (long long)i * DIM_, hr, (void*)hr, frows, DIM_,
                         4 * DIM_, 4 * DIM_, 4 * DIM_, DIM_, 0LL, 0LL, 0LL, 0,
                         0LL, 2, 0);
    }
  }

  hipLaunchKernelGGL(pool1_k, dim3(16, B_), dim3(256), 0, stream, h, partial);
  hipLaunchKernelGGL(pool2_k, dim3(B_), dim3(256), 0, stream, partial, pooled);
  hipLaunchKernelGGL(fc_k, dim3(1), dim3(64), 0, stream, pooled, fc_w, fc_b,
                     out);
}